// Round 9
// baseline (1395.078 us; speedup 1.0000x reference)
//
#include <hip/hip_runtime.h>

#define NV 32000
#define NT 64
#define NBLK 160u

typedef unsigned long long ull;
typedef unsigned short ushort;
typedef __attribute__((ext_vector_type(8))) short v8s;
typedef __attribute__((ext_vector_type(4))) float v4f;

// persistent ws layout (float offsets; ushort regions = count/2 floats)
#define WS_WBF     0          // ushort [32000][512]           -> 8192000
#define WS_H2BF    8192000    // ushort [2048][512]  (524288)  -> 8716288
#define WS_IMGEM   8716288    // f32 [1664][512]     (851968)  -> 9568256
#define WS_PROJ    9568256    // f32 [1664][128]     (212992)  -> 9781248
#define WS_EMBM    9781248    // f32 [2048][512]     (1048576) -> 10829824
#define WS_WHHBF   10829824   // ushort [2048][512]  (524288)  -> 11354112
#define WS_WIHBF   11354112   // ushort [2048][512]  (524288)  -> 11878400
#define WS_WHIDBF  11878400   // ushort [128][512]   (32768)   -> 11911168
#define WS_H       11911168   // f32 [2][32][512]    (32768)   -> 11943936
#define WS_XN      11943936   // f32 [32][512]       (16384)   -> 11960320
#define WS_C       11960320   // f32 [32][512]       (16384)   -> 11976704
#define WS_FLAGS   11976704   // 160 slots x 16 u32  (2560)    -> 11979264
#define WS_G       11979264   // f32 [32][2048]      (65536)   -> 12044800
// prep scratch (inside Wbf slot [0,8192000); dead before W_head cast)
#define PS_IMGBF   0          // ushort [1664][2048] (1703936) -> 1703936
#define PS_WCTXBF  1703936    // ushort [512][2048]  (524288)  -> 2228224
#define PS_WIMGBF  2228224    // ushort [128][2048]  (131072)  -> 2359296
#define PS_WMIXRBF 2359296    // ushort [512][512]   (131072)  -> 2490368
#define PS_IMGE    2490368    // f32 [1664][512]     (851968)  -> 3342336
#define PS_IMGEBF  3342336    // ushort [1664][512]  (425984)  -> 3768320
#define PS_EMBG    3768320    // ushort [2048][512]  (524288)  -> 4292608
#define PS_WMIXLBF 4292608    // ushort [512][512]   (131072)  -> 4423680

__device__ __forceinline__ float fsig(float x) {
    x = fminf(fmaxf(x, -30.f), 30.f);
    return 1.f / (1.f + __expf(-x));
}
__device__ __forceinline__ float ftanh(float x) {
    x = fminf(fmaxf(x, -15.f), 15.f);
    float e = __expf(2.f * x);
    return (e - 1.f) / (e + 1.f);
}
__device__ __forceinline__ unsigned short f2bf(float f) {
    union { float f; unsigned int u; } v; v.f = f;
    unsigned int u = v.u;
    return (unsigned short)((u + 0x7FFFu + ((u >> 16) & 1u)) >> 16);
}
__device__ __forceinline__ float bf_lo(unsigned u) { return __uint_as_float(u << 16); }
__device__ __forceinline__ float bf_hi(unsigned u) { return __uint_as_float(u & 0xffff0000u); }
__device__ __forceinline__ ull agld(const ull* p) {
    return __hip_atomic_load(p, __ATOMIC_RELAXED, __HIP_MEMORY_SCOPE_AGENT);
}
__device__ __forceinline__ unsigned pk2(ull v) {
    return (unsigned)f2bf(__uint_as_float((unsigned)v)) |
           ((unsigned)f2bf(__uint_as_float((unsigned)(v >> 32))) << 16);
}

// ---------------- prep kernels ----------------

__global__ __launch_bounds__(256) void k_castpad(const float* __restrict__ in,
        ushort* __restrict__ out, int R, int Rpad, int K, int ldi, int off) {
    size_t i = ((size_t)blockIdx.x * 256 + threadIdx.x) * 8;
    if (i >= (size_t)Rpad * K) return;
    int r = (int)(i / K), k = (int)(i % K);
    uint4 o = {0, 0, 0, 0};
    if (r < R) {
        const float* p = in + (size_t)r * ldi + off + k;
        float4 a = *(const float4*)(p);
        float4 b = *(const float4*)(p + 4);
        o.x = (unsigned)f2bf(a.x) | ((unsigned)f2bf(a.y) << 16);
        o.y = (unsigned)f2bf(a.z) | ((unsigned)f2bf(a.w) << 16);
        o.z = (unsigned)f2bf(b.x) | ((unsigned)f2bf(b.y) << 16);
        o.w = (unsigned)f2bf(b.z) | ((unsigned)f2bf(b.w) << 16);
    }
    *(uint4*)(out + i) = o;
}

// gather token embeddings: embG[(t*32+b)][k] = bf16(embed[tok]*(tok!=0))
__global__ __launch_bounds__(128) void k_embg(const int* __restrict__ toks,
        const float* __restrict__ embed, ushort* __restrict__ embG) {
    int row = blockIdx.x;
    int t = row >> 5, b = row & 31;
    int tok = toks[b * 64 + t];
    int e = threadIdx.x * 4;
    uint2 o = {0, 0};
    if (tok != 0) {
        float4 a = *(const float4*)&embed[(size_t)tok * 512 + e];
        o.x = (unsigned)f2bf(a.x) | ((unsigned)f2bf(a.y) << 16);
        o.y = (unsigned)f2bf(a.z) | ((unsigned)f2bf(a.w) << 16);
    }
    *(uint2*)&embG[(size_t)row * 512 + e] = o;
}

// C[m][n] = sum_k A[m][k]*B[n][k]
__global__ __launch_bounds__(256) void k_gemm(const ushort* __restrict__ A,
        const ushort* __restrict__ B, float* __restrict__ C, int N, int K) {
    __shared__ ushort Al[128][72];
    __shared__ ushort Bl[128][72];
    int n0 = blockIdx.x * 128, m0 = blockIdx.y * 128;
    int tid = threadIdx.x, lane = tid & 63, wid = tid >> 6;
    int wm = wid >> 1, wn = wid & 1;
    v4f acc[4][4] = {};
    for (int kt = 0; kt < K; kt += 64) {
        __syncthreads();
        #pragma unroll
        for (int i = 0; i < 4; i++) {
            int idx = i * 256 + tid;
            int row = idx >> 3, c8 = (idx & 7) * 8;
            *(uint4*)&Al[row][c8] = *(const uint4*)&A[(size_t)(m0 + row) * K + kt + c8];
            *(uint4*)&Bl[row][c8] = *(const uint4*)&B[(size_t)(n0 + row) * K + kt + c8];
        }
        __syncthreads();
        #pragma unroll
        for (int kk = 0; kk < 2; kk++) {
            v8s a[4], bfr[4];
            int ko = kk * 32 + (lane >> 4) * 8;
            #pragma unroll
            for (int mi = 0; mi < 4; mi++)
                a[mi] = *(const v8s*)&Al[wm * 64 + mi * 16 + (lane & 15)][ko];
            #pragma unroll
            for (int ni = 0; ni < 4; ni++)
                bfr[ni] = *(const v8s*)&Bl[wn * 64 + ni * 16 + (lane & 15)][ko];
            #pragma unroll
            for (int mi = 0; mi < 4; mi++)
                #pragma unroll
                for (int ni = 0; ni < 4; ni++)
                    acc[mi][ni] = __builtin_amdgcn_mfma_f32_16x16x32_bf16(a[mi], bfr[ni], acc[mi][ni], 0, 0, 0);
        }
    }
    int col = lane & 15, rbase = (lane >> 4) * 4;
    #pragma unroll
    for (int mi = 0; mi < 4; mi++)
        #pragma unroll
        for (int ni = 0; ni < 4; ni++)
            #pragma unroll
            for (int r = 0; r < 4; r++) {
                int m = m0 + wm * 64 + mi * 16 + rbase + r;
                int v = n0 + wn * 64 + ni * 16 + col;
                C[(size_t)m * N + v] = acc[mi][ni][r];
            }
}

__global__ __launch_bounds__(256) void k_gmean(const float* __restrict__ img,
                                               float* __restrict__ g) {
    int b = blockIdx.x;
    for (int d = threadIdx.x; d < 2048; d += 256) {
        float s = 0.f;
        for (int ss = 0; ss < 49; ss++) s += img[((size_t)(b * 49 + ss)) * 2048 + d];
        g[b * 2048 + d] = s * (1.f / 49.f);
    }
}

__global__ __launch_bounds__(256) void k_h0c0(const float* __restrict__ g,
        const float* __restrict__ Wh0, const float* __restrict__ bh0,
        const float* __restrict__ Wc0, const float* __restrict__ bc0,
        float* __restrict__ h0, float* __restrict__ c0) {
    int b = blockIdx.x >> 1, m = blockIdx.x & 1;
    __shared__ float gs[2048];
    for (int d = threadIdx.x; d < 2048; d += 256) gs[d] = g[b * 2048 + d];
    __syncthreads();
    const float* W = m ? Wc0 : Wh0;
    const float* bb = m ? bc0 : bh0;
    float* out = m ? c0 : h0;
    for (int r = threadIdx.x; r < 512; r += 256) {
        float acc = 0.f;
        const float* wr = W + (size_t)r * 2048;
        for (int d = 0; d < 2048; d += 4) {
            float4 w = *(const float4*)(wr + d);
            acc += w.x * gs[d] + w.y * gs[d + 1] + w.z * gs[d + 2] + w.w * gs[d + 3];
        }
        out[b * 512 + r] = ftanh(acc + bb[r]) * 0.5f;
    }
}

// ---------------- persistent recurrence ----------------
// 128 gates blocks (jc x bg): LDS-pinned weights, MFMA gates GEMM.
// 32 attn blocks: per-batch attention with imgEM/proj pinned in LDS.
// Sync via per-producer epoch flags (64B-padded slots), no global barrier.

__device__ __forceinline__ void waitflags(unsigned* FLG, int base, int stride,
                                          int n, unsigned tgt) {
    if (threadIdx.x < 64) {
        bool done;
        do {
            unsigned v = tgt;
            if ((int)threadIdx.x < n)
                v = __hip_atomic_load(FLG + (base + (int)threadIdx.x * stride) * 16,
                                      __ATOMIC_RELAXED, __HIP_MEMORY_SCOPE_AGENT);
            done = __all((int)(v >= tgt));
            if (!done) __builtin_amdgcn_s_sleep(1);
        } while (!done);
    }
    __syncthreads();
}

union SMem {
    struct {                       // gates role (blocks 0..127)
        ushort wh[64][520];        // W_hh rows (64 = 4 gates x 16 j), bf16
        ushort wi[64][520];        // W_ih rows
        ushort hsb[16][520];       // h / xn staged bf16 (rows 8..15 zero)
        float gtmp[4][16][16];     // [gate][jl][m]
    } g;                           // 153856 B
    struct {                       // attention role (blocks 128..159)
        float imgem[49][512];      // pinned imgEM[b]            100352 B
        float projl[49][129];      // pinned proj[b] (pad 129)    25284 B
        float hb[512];
        float ph[128];
        float scp[49][17];
        float wsm[64];
        float wred[8][2];
        float bc[2];
        float wscl[128];
    } a;                           // ~132 KB
};

__global__ __launch_bounds__(1024, 1) void k_persist(
        const int* __restrict__ toks, const float* __restrict__ embed,
        const float* __restrict__ lng, const float* __restrict__ lnb,
        const float* __restrict__ bih, const float* __restrict__ bhh,
        const float* __restrict__ wsc, const ushort* __restrict__ whidbf,
        const ushort* __restrict__ whhbf, const ushort* __restrict__ wihbf,
        const float* __restrict__ proj, const float* __restrict__ imgEM,
        const float* __restrict__ embM, float* __restrict__ H,
        const float* __restrict__ C0, float* __restrict__ XN,
        unsigned* __restrict__ FLG, ushort* __restrict__ h2bf) {
    __shared__ SMem sm;
    int blk = blockIdx.x, tid = threadIdx.x;

    if (blk < 128) {
        // ---------------- gates role ----------------
        int jc = blk >> 2, bg = blk & 3, b0 = bg * 8;
        int wid = tid >> 6, lane = tid & 63;
        int gate = wid & 3;
        for (int i = tid; i < 4096; i += 1024) {
            int rr = i >> 6, c8 = (i & 63) * 8;
            size_t R = (size_t)((rr >> 4) * 512 + jc * 16 + (rr & 15)) * 512 + c8;
            *(uint4*)&sm.g.wh[rr][c8] = *(const uint4*)&whhbf[R];
            *(uint4*)&sm.g.wi[rr][c8] = *(const uint4*)&wihbf[R];
        }
        for (int i = tid; i < 2080; i += 1024) ((ull*)sm.g.hsb)[i] = 0;
        float c_reg = 0.f, bs0 = 0.f, bs1 = 0.f, bs2 = 0.f, bs3 = 0.f;
        if (tid < 128) {
            int jl = tid >> 3, bb = tid & 7;
            int j = jc * 16 + jl;
            c_reg = C0[(b0 + bb) * 512 + j];
            bs0 = bih[j] + bhh[j];
            bs1 = bih[512 + j] + bhh[512 + j];
            bs2 = bih[1024 + j] + bhh[1024 + j];
            bs3 = bih[1536 + j] + bhh[1536 + j];
        }
        __syncthreads();

        for (int t = 0; t < NT; t++) {
            waitflags(FLG, bg, 4, 32, (unsigned)t);
            {   // stage h -> hsb bf16 (rows 0..7)
                const float* Hb = H + (t & 1) * 16384 + b0 * 512;
                if (tid < 512) {
                    int bb = tid >> 6, c8 = (tid & 63) * 8;
                    const ull* p = (const ull*)(Hb + bb * 512 + c8);
                    uint4 o = { pk2(agld(p)), pk2(agld(p + 1)),
                                pk2(agld(p + 2)), pk2(agld(p + 3)) };
                    *(uint4*)&sm.g.hsb[bb][c8] = o;
                }
            }
            __syncthreads();
            v4f acc = {};
            if (wid < 4) {
                #pragma unroll
                for (int ks = 0; ks < 16; ks++) {
                    int ko = ks * 32 + (lane >> 4) * 8;
                    v8s a = *(const v8s*)&sm.g.hsb[lane & 15][ko];
                    v8s b = *(const v8s*)&sm.g.wh[gate * 16 + (lane & 15)][ko];
                    acc = __builtin_amdgcn_mfma_f32_16x16x32_bf16(a, b, acc, 0, 0, 0);
                }
            }
            waitflags(FLG, 128 + b0, 1, 8, (unsigned)(t + 1));
            {   // stage xn -> hsb bf16
                const float* Xb = XN + b0 * 512;
                if (tid < 512) {
                    int bb = tid >> 6, c8 = (tid & 63) * 8;
                    const ull* p = (const ull*)(Xb + bb * 512 + c8);
                    uint4 o = { pk2(agld(p)), pk2(agld(p + 1)),
                                pk2(agld(p + 2)), pk2(agld(p + 3)) };
                    *(uint4*)&sm.g.hsb[bb][c8] = o;
                }
            }
            __syncthreads();
            if (wid < 4) {
                #pragma unroll
                for (int ks = 0; ks < 16; ks++) {
                    int ko = ks * 32 + (lane >> 4) * 8;
                    v8s a = *(const v8s*)&sm.g.hsb[lane & 15][ko];
                    v8s b = *(const v8s*)&sm.g.wi[gate * 16 + (lane & 15)][ko];
                    acc = __builtin_amdgcn_mfma_f32_16x16x32_bf16(a, b, acc, 0, 0, 0);
                }
                #pragma unroll
                for (int q = 0; q < 4; q++)
                    sm.g.gtmp[gate][lane & 15][(lane >> 4) * 4 + q] = acc[q];
            }
            __syncthreads();
            if (tid < 128) {
                int jl = tid >> 3, bb = tid & 7;
                float vi = sm.g.gtmp[0][jl][bb] + bs0;
                float vf = sm.g.gtmp[1][jl][bb] + bs1;
                float vg = sm.g.gtmp[2][jl][bb] + bs2;
                float vo = sm.g.gtmp[3][jl][bb] + bs3;
                float c2 = fsig(vf) * c_reg + fsig(vi) * ftanh(vg);
                float h2 = fsig(vo) * ftanh(c2);
                c_reg = c2;
                int bglob = b0 + bb, j = jc * 16 + jl;
                __hip_atomic_store((unsigned*)&H[((t + 1) & 1) * 16384 + bglob * 512 + j],
                                   __float_as_uint(h2), __ATOMIC_RELAXED, __HIP_MEMORY_SCOPE_AGENT);
                h2bf[(size_t)(t * 32 + bglob) * 512 + j] = f2bf(h2);
            }
            __syncthreads();
            if (tid == 0)
                __hip_atomic_store(FLG + blk * 16, (unsigned)(t + 1),
                                   __ATOMIC_RELAXED, __HIP_MEMORY_SCOPE_AGENT);
        }
    } else {
        // ---------------- attention role ----------------
        int b = blk - 128, bgb = b >> 3;
        // pin imgEM[b], proj[b], wsc in LDS; lng/lnb in registers
        for (int i = tid; i < 49 * 512; i += 1024)
            sm.a.imgem[i >> 9][i & 511] = imgEM[(size_t)b * 49 * 512 + i];
        for (int i = tid; i < 49 * 128; i += 1024)
            sm.a.projl[i >> 7][i & 127] = proj[(size_t)b * 49 * 128 + i];
        if (tid < 128) sm.a.wscl[tid] = wsc[tid];
        float lngr = 0.f, lnbr = 0.f;
        if (tid < 512) { lngr = lng[tid]; lnbr = lnb[tid]; }
        __syncthreads();

        for (int t = 0; t < NT; t++) {
            // prefetch step-independent data before the flag wait
            int tok = toks[b * 64 + t];
            float emv = 0.f, ebr = 0.f;
            if (tid < 512) {
                emv = embM[(size_t)(t * 32 + b) * 512 + tid];
                ebr = (tok == 0) ? 0.f : embed[(size_t)tok * 512 + tid];
            }
            waitflags(FLG, bgb, 4, 32, (unsigned)t);
            if (tid < 256) {
                ull v = agld((const ull*)(H + (t & 1) * 16384) + b * 256 + tid);
                *(ull*)&sm.a.hb[tid * 2] = v;
            }
            __syncthreads();
            {   // ph: 8 waves x 16 a, 4 lanes per a (k quarters), in-wave reduce
                int w = tid >> 6, l = tid & 63;
                if (w < 8) {
                    int a = w * 16 + (l & 15), q = l >> 4;
                    const ushort* wr2 = whidbf + (size_t)a * 512 + q * 128;
                    const float* hp = sm.a.hb + q * 128;
                    float p = 0.f;
                    #pragma unroll
                    for (int k = 0; k < 128; k += 8) {
                        uint4 qd = *(const uint4*)(wr2 + k);
                        float4 ha = *(const float4*)(hp + k);
                        float4 hb4 = *(const float4*)(hp + k + 4);
                        p += bf_lo(qd.x)*ha.x + bf_hi(qd.x)*ha.y + bf_lo(qd.y)*ha.z + bf_hi(qd.y)*ha.w
                           + bf_lo(qd.z)*hb4.x + bf_hi(qd.z)*hb4.y + bf_lo(qd.w)*hb4.z + bf_hi(qd.w)*hb4.w;
                    }
                    p += __shfl_xor(p, 16);
                    p += __shfl_xor(p, 32);
                    if (l < 16) sm.a.ph[a] = p;
                }
            }
            __syncthreads();
            if (tid < 784) {   // score partials (proj from LDS)
                int s = tid >> 4, aq = tid & 15;
                float p = 0.f;
                #pragma unroll
                for (int i = 0; i < 8; i++) {
                    int a = aq * 8 + i;
                    p += ftanh(sm.a.projl[s][a] + sm.a.ph[a]) * sm.a.wscl[a];
                }
                sm.a.scp[s][aq] = p;
            }
            __syncthreads();
            if (tid < 64) {   // softmax over 49
                float v = 0.f;
                #pragma unroll
                for (int q = 0; q < 16; q++) v += sm.a.scp[tid][q];
                if (tid >= 49) v = -1e30f;
                float m = v;
                for (int o = 32; o > 0; o >>= 1) m = fmaxf(m, __shfl_xor(m, o));
                float e = (tid < 49) ? __expf(v - m) : 0.f;
                float su = e;
                for (int o = 32; o > 0; o >>= 1) su += __shfl_xor(su, o);
                sm.a.wsm[tid] = e / su;
            }
            __syncthreads();
            float x = 0.f;
            if (tid < 512) {   // combine (imgem from LDS) + LN stats, x in register
                x = emv;
                for (int s = 0; s < 49; s++)
                    x += sm.a.wsm[s] * sm.a.imgem[s][tid];
                x = fmaxf(x, 0.f);
                float s1 = x, s2 = x * x;
                for (int o = 32; o > 0; o >>= 1) { s1 += __shfl_xor(s1, o); s2 += __shfl_xor(s2, o); }
                if ((tid & 63) == 0) { sm.a.wred[tid >> 6][0] = s1; sm.a.wred[tid >> 6][1] = s2; }
            }
            __syncthreads();
            if (tid == 0) {
                float s1 = 0.f, s2 = 0.f;
                #pragma unroll
                for (int w = 0; w < 8; w++) { s1 += sm.a.wred[w][0]; s2 += sm.a.wred[w][1]; }
                float mu = s1 * (1.f / 512.f);
                float var = s2 * (1.f / 512.f) - mu * mu;
                sm.a.bc[0] = mu; sm.a.bc[1] = rsqrtf(var + 1e-5f);
            }
            __syncthreads();
            if (tid < 512) {
                float xn = (x - sm.a.bc[0]) * sm.a.bc[1] * lngr + lnbr + ebr;
                __hip_atomic_store((unsigned*)&XN[b * 512 + tid], __float_as_uint(xn),
                                   __ATOMIC_RELAXED, __HIP_MEMORY_SCOPE_AGENT);
            }
            __syncthreads();
            if (tid == 0)
                __hip_atomic_store(FLG + (128 + b) * 16, (unsigned)(t + 1),
                                   __ATOMIC_RELAXED, __HIP_MEMORY_SCOPE_AGENT);
        }
    }
}

// ---------------- deferred head GEMM ----------------
__global__ __launch_bounds__(256) void k_head(const ushort* __restrict__ h2bf,
        const ushort* __restrict__ Wbf, float* __restrict__ out) {
    __shared__ ushort Al[128][72];
    __shared__ ushort Bl[128][72];
    int n0 = blockIdx.x * 128, m0 = blockIdx.y * 128;
    int tid = threadIdx.x, lane = tid & 63, wid = tid >> 6;
    int wm = wid >> 1, wn = wid & 1;
    v4f acc[4][4] = {};
    for (int kt = 0; kt < 512; kt += 64) {
        __syncthreads();
        #pragma unroll
        for (int i = 0; i < 4; i++) {
            int idx = i * 256 + tid;
            int row = idx >> 3, c8 = (idx & 7) * 8;
            *(uint4*)&Al[row][c8] = *(const uint4*)&h2bf[(size_t)(m0 + row) * 512 + kt + c8];
            *(uint4*)&Bl[row][c8] = *(const uint4*)&Wbf[(size_t)(n0 + row) * 512 + kt + c8];
        }
        __syncthreads();
        #pragma unroll
        for (int kk = 0; kk < 2; kk++) {
            v8s a[4], bfr[4];
            int ko = kk * 32 + (lane >> 4) * 8;
            #pragma unroll
            for (int mi = 0; mi < 4; mi++)
                a[mi] = *(const v8s*)&Al[wm * 64 + mi * 16 + (lane & 15)][ko];
            #pragma unroll
            for (int ni = 0; ni < 4; ni++)
                bfr[ni] = *(const v8s*)&Bl[wn * 64 + ni * 16 + (lane & 15)][ko];
            #pragma unroll
            for (int mi = 0; mi < 4; mi++)
                #pragma unroll
                for (int ni = 0; ni < 4; ni++)
                    acc[mi][ni] = __builtin_amdgcn_mfma_f32_16x16x32_bf16(a[mi], bfr[ni], acc[mi][ni], 0, 0, 0);
        }
    }
    int col = lane & 15, rbase = (lane >> 4) * 4;
    #pragma unroll
    for (int mi = 0; mi < 4; mi++)
        #pragma unroll
        for (int ni = 0; ni < 4; ni++)
            #pragma unroll
            for (int r = 0; r < 4; r++) {
                int m = m0 + wm * 64 + mi * 16 + rbase + r;
                int v = n0 + wn * 64 + ni * 16 + col;
                int b = m & 31, t = m >> 5;
                out[((size_t)(b * 64 + t)) * 32000 + v] = acc[mi][ni][r];
            }
}

// ---------------- launch ----------------
extern "C" void kernel_launch(void* const* d_in, const int* in_sizes, int n_in,
                              void* d_out, int out_size, void* d_ws, size_t ws_size,
                              hipStream_t stream) {
    const float* img    = (const float*)d_in[0];
    const int*   toks   = (const int*)d_in[1];
    const float* embed  = (const float*)d_in[2];
    const float* W_ctx  = (const float*)d_in[3];
    const float* W_mix  = (const float*)d_in[4];
    const float* ln_g   = (const float*)d_in[5];
    const float* ln_b   = (const float*)d_in[6];
    const float* W_ih   = (const float*)d_in[7];
    const float* W_hh   = (const float*)d_in[8];
    const float* b_ih   = (const float*)d_in[9];
    const float* b_hh   = (const float*)d_in[10];
    const float* W_head = (const float*)d_in[11];
    const float* W_img  = (const float*)d_in[12];
    const float* W_hid  = (const float*)d_in[13];
    const float* w_sc   = (const float*)d_in[14];
    const float* W_h0   = (const float*)d_in[15];
    const float* b_h0   = (const float*)d_in[16];
    const float* W_c0   = (const float*)d_in[17];
    const float* b_c0   = (const float*)d_in[18];

    float* out = (float*)d_out;
    float* ws  = (float*)d_ws;
    ushort* Wbf    = (ushort*)(ws + WS_WBF);
    ushort* h2bf   = (ushort*)(ws + WS_H2BF);
    float*  imgEM  = ws + WS_IMGEM;
    float*  proj   = ws + WS_PROJ;
    float*  embM   = ws + WS_EMBM;
    ushort* whhbf  = (ushort*)(ws + WS_WHHBF);
    ushort* wihbf  = (ushort*)(ws + WS_WIHBF);
    ushort* whidbf = (ushort*)(ws + WS_WHIDBF);
    float*  H      = ws + WS_H;
    float*  XN     = ws + WS_XN;
    float*  C      = ws + WS_C;
    unsigned* flg  = (unsigned*)(ws + WS_FLAGS);
    float*  g      = ws + WS_G;
    // prep scratch (inside Wbf slot)
    ushort* imgbf   = (ushort*)(ws + PS_IMGBF);
    ushort* wctxbf  = (ushort*)(ws + PS_WCTXBF);
    ushort* wimgbf  = (ushort*)(ws + PS_WIMGBF);
    ushort* wmixRbf = (ushort*)(ws + PS_WMIXRBF);
    float*  imgE    = ws + PS_IMGE;
    ushort* imgEbf  = (ushort*)(ws + PS_IMGEBF);
    ushort* embG    = (ushort*)(ws + PS_EMBG);
    ushort* wmixLbf = (ushort*)(ws + PS_WMIXLBF);

    // prep A: casts into scratch
    k_castpad<<<1664, 256, 0, stream>>>(img,   imgbf,   1568, 1664, 2048, 2048, 0);
    k_castpad<<<512,  256, 0, stream>>>(W_ctx, wctxbf,  512,  512,  2048, 2048, 0);
    k_castpad<<<128,  256, 0, stream>>>(W_img, wimgbf,  128,  128,  2048, 2048, 0);
    k_castpad<<<128,  256, 0, stream>>>(W_mix, wmixRbf, 512,  512,  512,  1024, 512);
    k_castpad<<<128,  256, 0, stream>>>(W_mix, wmixLbf, 512,  512,  512,  1024, 0);
    k_embg<<<2048, 128, 0, stream>>>(toks, embed, embG);
    // prep B: MFMA GEMMs
    k_gemm<<<dim3(4, 13), 256, 0, stream>>>(imgbf, wctxbf, imgE, 512, 2048);
    k_gemm<<<dim3(1, 13), 256, 0, stream>>>(imgbf, wimgbf, proj, 128, 2048);
    k_gemm<<<dim3(4, 16), 256, 0, stream>>>(embG, wmixLbf, embM, 512, 512);
    k_castpad<<<416, 256, 0, stream>>>(imgE, imgEbf, 1664, 1664, 512, 512, 0);
    k_gemm<<<dim3(4, 13), 256, 0, stream>>>(imgEbf, wmixRbf, imgEM, 512, 512);
    // prep C: persistent bf16 weights
    k_castpad<<<512, 256, 0, stream>>>(W_hh,  whhbf,  2048, 2048, 512, 512, 0);
    k_castpad<<<512, 256, 0, stream>>>(W_ih,  wihbf,  2048, 2048, 512, 512, 0);
    k_castpad<<<32,  256, 0, stream>>>(W_hid, whidbf, 128,  128,  512, 512, 0);
    // prep D: head weights (overwrites scratch region)
    k_castpad<<<8000, 256, 0, stream>>>(W_head, Wbf, 32000, 32000, 512, 512, 0);
    // prep E: init state (h0 into H parity-0 buffer)
    k_gmean<<<32, 256, 0, stream>>>(img, g);
    k_h0c0<<<64, 256, 0, stream>>>(g, W_h0, b_h0, W_c0, b_c0, H, C);
    hipMemsetAsync(flg, 0, 10240, stream);   // 160 flag slots (64B each)

    // recurrence: flag-synced, MFMA gates, LDS-pinned weights + attn data
    k_persist<<<NBLK, 1024, 0, stream>>>(toks, embed, ln_g, ln_b, b_ih, b_hh, w_sc,
                                         whidbf, whhbf, wihbf, proj, imgEM, embM,
                                         H, C, XN, flg, h2bf);

    // deferred batched head GEMM
    k_head<<<dim3(250, 16), 256, 0, stream>>>(h2bf, Wbf, out);
}

// Round 10
// 1291.583 us; speedup vs baseline: 1.0801x; 1.0801x over previous
//
#include <hip/hip_runtime.h>

#define NV 32000
#define NT 64
#define NBLK 160u

typedef unsigned long long ull;
typedef unsigned short ushort;
typedef __attribute__((ext_vector_type(8))) short v8s;
typedef __attribute__((ext_vector_type(4))) float v4f;

// persistent ws layout (float offsets; ushort regions = count/2 floats)
#define WS_WBF     0          // ushort [32000][512]           -> 8192000
#define WS_H2BF    8192000    // ushort [2048][512]  (524288)  -> 8716288
#define WS_IMGEM   8716288    // f32 [1664][512]     (851968)  -> 9568256
#define WS_PROJ    9568256    // f32 [1664][128]     (212992)  -> 9781248
#define WS_EMBM    9781248    // f32 [2048][512]     (1048576) -> 10829824
#define WS_WHHBF   10829824   // ushort [2048][512]  (524288)  -> 11354112
#define WS_WIHBF   11354112   // ushort [2048][512]  (524288)  -> 11878400
#define WS_WHIDBF  11878400   // ushort [128][512]   (32768)   -> 11911168
#define WS_H       11911168   // f32 [2][32][512]    (32768)   -> 11943936
#define WS_XN      11943936   // f32 [32][512]       (16384)   -> 11960320
#define WS_C       11960320   // f32 [32][512]       (16384)   -> 11976704
#define WS_FLAGS   11976704   // 160 slots x 16 u32  (2560)    -> 11979264
#define WS_G       11979264   // f32 [32][2048]      (65536)   -> 12044800
// prep scratch (inside Wbf slot [0,8192000); dead before W_head cast)
#define PS_IMGE    0          // f32 [1664][512]     (851968)  -> 851968
#define PS_EMBG    851968     // f32 [2048][512]     (1048576) -> 1900544

__device__ __forceinline__ float fsig(float x) {
    x = fminf(fmaxf(x, -30.f), 30.f);
    return 1.f / (1.f + __expf(-x));
}
__device__ __forceinline__ float ftanh(float x) {
    x = fminf(fmaxf(x, -15.f), 15.f);
    float e = __expf(2.f * x);
    return (e - 1.f) / (e + 1.f);
}
__device__ __forceinline__ unsigned short f2bf(float f) {
    union { float f; unsigned int u; } v; v.f = f;
    unsigned int u = v.u;
    return (unsigned short)((u + 0x7FFFu + ((u >> 16) & 1u)) >> 16);
}
__device__ __forceinline__ unsigned pkf(float x, float y) {
    return (unsigned)f2bf(x) | ((unsigned)f2bf(y) << 16);
}
__device__ __forceinline__ float bf_lo(unsigned u) { return __uint_as_float(u << 16); }
__device__ __forceinline__ float bf_hi(unsigned u) { return __uint_as_float(u & 0xffff0000u); }
__device__ __forceinline__ ull agld(const ull* p) {
    return __hip_atomic_load(p, __ATOMIC_RELAXED, __HIP_MEMORY_SCOPE_AGENT);
}
__device__ __forceinline__ unsigned pk2(ull v) {
    return (unsigned)f2bf(__uint_as_float((unsigned)v)) |
           ((unsigned)f2bf(__uint_as_float((unsigned)(v >> 32))) << 16);
}

// ---------------- prep kernels ----------------

// plain fp32->bf16 cast (W_head only)
__global__ __launch_bounds__(256) void k_castpad(const float* __restrict__ in,
        ushort* __restrict__ out, int R, int Rpad, int K, int ldi, int off) {
    size_t i = ((size_t)blockIdx.x * 256 + threadIdx.x) * 8;
    if (i >= (size_t)Rpad * K) return;
    int r = (int)(i / K), k = (int)(i % K);
    uint4 o = {0, 0, 0, 0};
    if (r < R) {
        const float* p = in + (size_t)r * ldi + off + k;
        float4 a = *(const float4*)(p);
        float4 b = *(const float4*)(p + 4);
        o.x = pkf(a.x, a.y); o.y = pkf(a.z, a.w);
        o.z = pkf(b.x, b.y); o.w = pkf(b.z, b.w);
    }
    *(uint4*)(out + i) = o;
}

// fused cast of the three persist weights: whh(512) | wih(512) | whid(32)
__global__ __launch_bounds__(256) void k_cast3(const float* __restrict__ Whh,
        const float* __restrict__ Wih, const float* __restrict__ Whid,
        ushort* __restrict__ whhbf, ushort* __restrict__ wihbf,
        ushort* __restrict__ whidbf) {
    int blk = blockIdx.x;
    const float* in; ushort* out;
    if (blk < 512)      { in = Whh;  out = whhbf;  }
    else if (blk < 1024){ in = Wih;  out = wihbf;  blk -= 512; }
    else                { in = Whid; out = whidbf; blk -= 1024; }
    size_t i = ((size_t)blk * 256 + threadIdx.x) * 8;
    const float* p = in + i;
    float4 a = *(const float4*)(p);
    float4 b = *(const float4*)(p + 4);
    uint4 o;
    o.x = pkf(a.x, a.y); o.y = pkf(a.z, a.w);
    o.z = pkf(b.x, b.y); o.w = pkf(b.z, b.w);
    *(uint4*)(out + i) = o;
}

// gather token embeddings fp32: embG[(t*32+b)][k] = embed[tok]*(tok!=0)
__global__ __launch_bounds__(128) void k_embg32(const int* __restrict__ toks,
        const float* __restrict__ embed, float* __restrict__ embG) {
    int row = blockIdx.x;
    int t = row >> 5, b = row & 31;
    int tok = toks[b * 64 + t];
    int e = threadIdx.x * 4;
    float4 o = {0.f, 0.f, 0.f, 0.f};
    if (tok != 0) o = *(const float4*)&embed[(size_t)tok * 512 + e];
    *(float4*)&embG[(size_t)row * 512 + e] = o;
}

// fp32-input GEMM, converts to bf16 during LDS staging (identical rounding
// to the old cast+bf16-GEMM path). C[m][n] = sum_k A[m][k+?]*B[n][offb+k]
__global__ __launch_bounds__(256) void k_gemmF(const float* __restrict__ A,
        const float* __restrict__ B, float* __restrict__ C,
        int N, int K, int aR, int lda, int ldb, int offb) {
    __shared__ ushort Al[128][72];
    __shared__ ushort Bl[128][72];
    int n0 = blockIdx.x * 128, m0 = blockIdx.y * 128;
    int tid = threadIdx.x, lane = tid & 63, wid = tid >> 6;
    int wm = wid >> 1, wn = wid & 1;
    v4f acc[4][4] = {};
    for (int kt = 0; kt < K; kt += 64) {
        __syncthreads();
        #pragma unroll
        for (int i = 0; i < 4; i++) {
            int idx = i * 256 + tid;
            int row = idx >> 3, c8 = (idx & 7) * 8;
            uint4 oa = {0, 0, 0, 0};
            if (m0 + row < aR) {
                const float* pa = A + (size_t)(m0 + row) * lda + kt + c8;
                float4 a0 = *(const float4*)pa, a1 = *(const float4*)(pa + 4);
                oa.x = pkf(a0.x, a0.y); oa.y = pkf(a0.z, a0.w);
                oa.z = pkf(a1.x, a1.y); oa.w = pkf(a1.z, a1.w);
            }
            *(uint4*)&Al[row][c8] = oa;
            const float* pb = B + (size_t)(n0 + row) * ldb + offb + kt + c8;
            float4 b0 = *(const float4*)pb, b1 = *(const float4*)(pb + 4);
            uint4 ob;
            ob.x = pkf(b0.x, b0.y); ob.y = pkf(b0.z, b0.w);
            ob.z = pkf(b1.x, b1.y); ob.w = pkf(b1.z, b1.w);
            *(uint4*)&Bl[row][c8] = ob;
        }
        __syncthreads();
        #pragma unroll
        for (int kk = 0; kk < 2; kk++) {
            v8s a[4], bfr[4];
            int ko = kk * 32 + (lane >> 4) * 8;
            #pragma unroll
            for (int mi = 0; mi < 4; mi++)
                a[mi] = *(const v8s*)&Al[wm * 64 + mi * 16 + (lane & 15)][ko];
            #pragma unroll
            for (int ni = 0; ni < 4; ni++)
                bfr[ni] = *(const v8s*)&Bl[wn * 64 + ni * 16 + (lane & 15)][ko];
            #pragma unroll
            for (int mi = 0; mi < 4; mi++)
                #pragma unroll
                for (int ni = 0; ni < 4; ni++)
                    acc[mi][ni] = __builtin_amdgcn_mfma_f32_16x16x32_bf16(a[mi], bfr[ni], acc[mi][ni], 0, 0, 0);
        }
    }
    int col = lane & 15, rbase = (lane >> 4) * 4;
    #pragma unroll
    for (int mi = 0; mi < 4; mi++)
        #pragma unroll
        for (int ni = 0; ni < 4; ni++)
            #pragma unroll
            for (int r = 0; r < 4; r++) {
                int m = m0 + wm * 64 + mi * 16 + rbase + r;
                int v = n0 + wn * 64 + ni * 16 + col;
                C[(size_t)m * N + v] = acc[mi][ni][r];
            }
}

__global__ __launch_bounds__(256) void k_gmean(const float* __restrict__ img,
                                               float* __restrict__ g) {
    int b = blockIdx.x;
    for (int d = threadIdx.x; d < 2048; d += 256) {
        float s = 0.f;
        for (int ss = 0; ss < 49; ss++) s += img[((size_t)(b * 49 + ss)) * 2048 + d];
        g[b * 2048 + d] = s * (1.f / 49.f);
    }
}

// grid 128: (b, m, rhalf) — 1 output row per thread (halved serial chain)
__global__ __launch_bounds__(256) void k_h0c0(const float* __restrict__ g,
        const float* __restrict__ Wh0, const float* __restrict__ bh0,
        const float* __restrict__ Wc0, const float* __restrict__ bc0,
        float* __restrict__ h0, float* __restrict__ c0) {
    int b = blockIdx.x >> 2, m = (blockIdx.x >> 1) & 1, rh = blockIdx.x & 1;
    __shared__ float gs[2048];
    for (int d = threadIdx.x; d < 2048; d += 256) gs[d] = g[b * 2048 + d];
    __syncthreads();
    const float* W = m ? Wc0 : Wh0;
    const float* bb = m ? bc0 : bh0;
    float* out = m ? c0 : h0;
    int r = rh * 256 + threadIdx.x;
    float acc = 0.f;
    const float* wr = W + (size_t)r * 2048;
    for (int d = 0; d < 2048; d += 4) {
        float4 w = *(const float4*)(wr + d);
        acc += w.x * gs[d] + w.y * gs[d + 1] + w.z * gs[d + 2] + w.w * gs[d + 3];
    }
    out[b * 512 + r] = ftanh(acc + bb[r]) * 0.5f;
}

// ---------------- persistent recurrence (exact R8 structure) ----------------
// 128 gates blocks (jc x bg): LDS-pinned weights, MFMA gates GEMM.
// 32 attn blocks: per-batch attention + LN.
// Sync via per-producer epoch flags (64B-padded slots), no global barrier.

__device__ __forceinline__ void waitflags(unsigned* FLG, int base, int stride,
                                          int n, unsigned tgt) {
    if (threadIdx.x < 64) {
        bool done;
        do {
            unsigned v = tgt;
            if ((int)threadIdx.x < n)
                v = __hip_atomic_load(FLG + (base + (int)threadIdx.x * stride) * 16,
                                      __ATOMIC_RELAXED, __HIP_MEMORY_SCOPE_AGENT);
            done = __all((int)(v >= tgt));
            if (!done) __builtin_amdgcn_s_sleep(1);
        } while (!done);
    }
    __syncthreads();
}

union SMem {
    struct {                       // gates role (blocks 0..127)
        ushort wh[64][520];        // W_hh rows (64 = 4 gates x 16 j), bf16
        ushort wi[64][520];        // W_ih rows
        ushort hsb[16][520];       // h / xn staged bf16 (rows 8..15 zero)
        float gtmp[4][16][16];     // [gate][jl][m]
    } g;                           // 153856 B
    struct {                       // attention role (blocks 128..159)
        float hb[512];
        float ebs[512];
        float php[8][128];
        float ph[128];
        float scp[64][16];
        float wsm[64];
        float xps[2][512];
        float wred[8][2];
        float bc[2];
    } a;
};

__global__ __launch_bounds__(1024, 1) void k_persist(
        const int* __restrict__ toks, const float* __restrict__ embed,
        const float* __restrict__ lng, const float* __restrict__ lnb,
        const float* __restrict__ bih, const float* __restrict__ bhh,
        const float* __restrict__ wsc, const ushort* __restrict__ whidbf,
        const ushort* __restrict__ whhbf, const ushort* __restrict__ wihbf,
        const float* __restrict__ proj, const float* __restrict__ imgEM,
        const float* __restrict__ embM, float* __restrict__ H,
        const float* __restrict__ C0, float* __restrict__ XN,
        unsigned* __restrict__ FLG, ushort* __restrict__ h2bf) {
    __shared__ SMem sm;
    int blk = blockIdx.x, tid = threadIdx.x;

    if (blk < 128) {
        // ---------------- gates role ----------------
        int jc = blk >> 2, bg = blk & 3, b0 = bg * 8;
        int wid = tid >> 6, lane = tid & 63;
        int gate = wid & 3;
        for (int i = tid; i < 4096; i += 1024) {
            int rr = i >> 6, c8 = (i & 63) * 8;
            size_t R = (size_t)((rr >> 4) * 512 + jc * 16 + (rr & 15)) * 512 + c8;
            *(uint4*)&sm.g.wh[rr][c8] = *(const uint4*)&whhbf[R];
            *(uint4*)&sm.g.wi[rr][c8] = *(const uint4*)&wihbf[R];
        }
        for (int i = tid; i < 2080; i += 1024) ((ull*)sm.g.hsb)[i] = 0;
        float c_reg = 0.f, bs0 = 0.f, bs1 = 0.f, bs2 = 0.f, bs3 = 0.f;
        if (tid < 128) {
            int jl = tid >> 3, bb = tid & 7;
            int j = jc * 16 + jl;
            c_reg = C0[(b0 + bb) * 512 + j];
            bs0 = bih[j] + bhh[j];
            bs1 = bih[512 + j] + bhh[512 + j];
            bs2 = bih[1024 + j] + bhh[1024 + j];
            bs3 = bih[1536 + j] + bhh[1536 + j];
        }
        __syncthreads();

        for (int t = 0; t < NT; t++) {
            waitflags(FLG, bg, 4, 32, (unsigned)t);
            {   // stage h -> hsb bf16 (rows 0..7)
                const float* Hb = H + (t & 1) * 16384 + b0 * 512;
                if (tid < 512) {
                    int bb = tid >> 6, c8 = (tid & 63) * 8;
                    const ull* p = (const ull*)(Hb + bb * 512 + c8);
                    uint4 o = { pk2(agld(p)), pk2(agld(p + 1)),
                                pk2(agld(p + 2)), pk2(agld(p + 3)) };
                    *(uint4*)&sm.g.hsb[bb][c8] = o;
                }
            }
            __syncthreads();
            v4f acc = {};
            if (wid < 4) {
                #pragma unroll
                for (int ks = 0; ks < 16; ks++) {
                    int ko = ks * 32 + (lane >> 4) * 8;
                    v8s a = *(const v8s*)&sm.g.hsb[lane & 15][ko];
                    v8s b = *(const v8s*)&sm.g.wh[gate * 16 + (lane & 15)][ko];
                    acc = __builtin_amdgcn_mfma_f32_16x16x32_bf16(a, b, acc, 0, 0, 0);
                }
            }
            waitflags(FLG, 128 + b0, 1, 8, (unsigned)(t + 1));
            {   // stage xn -> hsb bf16
                const float* Xb = XN + b0 * 512;
                if (tid < 512) {
                    int bb = tid >> 6, c8 = (tid & 63) * 8;
                    const ull* p = (const ull*)(Xb + bb * 512 + c8);
                    uint4 o = { pk2(agld(p)), pk2(agld(p + 1)),
                                pk2(agld(p + 2)), pk2(agld(p + 3)) };
                    *(uint4*)&sm.g.hsb[bb][c8] = o;
                }
            }
            __syncthreads();
            if (wid < 4) {
                #pragma unroll
                for (int ks = 0; ks < 16; ks++) {
                    int ko = ks * 32 + (lane >> 4) * 8;
                    v8s a = *(const v8s*)&sm.g.hsb[lane & 15][ko];
                    v8s b = *(const v8s*)&sm.g.wi[gate * 16 + (lane & 15)][ko];
                    acc = __builtin_amdgcn_mfma_f32_16x16x32_bf16(a, b, acc, 0, 0, 0);
                }
                #pragma unroll
                for (int q = 0; q < 4; q++)
                    sm.g.gtmp[gate][lane & 15][(lane >> 4) * 4 + q] = acc[q];
            }
            __syncthreads();
            if (tid < 128) {
                int jl = tid >> 3, bb = tid & 7;
                float vi = sm.g.gtmp[0][jl][bb] + bs0;
                float vf = sm.g.gtmp[1][jl][bb] + bs1;
                float vg = sm.g.gtmp[2][jl][bb] + bs2;
                float vo = sm.g.gtmp[3][jl][bb] + bs3;
                float c2 = fsig(vf) * c_reg + fsig(vi) * ftanh(vg);
                float h2 = fsig(vo) * ftanh(c2);
                c_reg = c2;
                int bglob = b0 + bb, j = jc * 16 + jl;
                __hip_atomic_store((unsigned*)&H[((t + 1) & 1) * 16384 + bglob * 512 + j],
                                   __float_as_uint(h2), __ATOMIC_RELAXED, __HIP_MEMORY_SCOPE_AGENT);
                h2bf[(size_t)(t * 32 + bglob) * 512 + j] = f2bf(h2);
            }
            __syncthreads();
            if (tid == 0)
                __hip_atomic_store(FLG + blk * 16, (unsigned)(t + 1),
                                   __ATOMIC_RELAXED, __HIP_MEMORY_SCOPE_AGENT);
        }
    } else {
        // ---------------- attention role ----------------
        int b = blk - 128, bgb = b >> 3;
        for (int t = 0; t < NT; t++) {
            waitflags(FLG, bgb, 4, 32, (unsigned)t);
            int tok = toks[b * 64 + t];
            if (tid < 256) {
                ull v = agld((const ull*)(H + (t & 1) * 16384) + b * 256 + tid);
                *(ull*)&sm.a.hb[tid * 2] = v;
            } else if (tid < 768) {
                int k = tid - 256;
                sm.a.ebs[k] = (tok == 0) ? 0.f : embed[(size_t)tok * 512 + k];
            }
            __syncthreads();
            {   // ph partials (whid from L2, bf16)
                int a = tid & 127, kq = tid >> 7;
                const ushort* wr2 = whidbf + (size_t)a * 512 + kq * 64;
                const float* hp = sm.a.hb + kq * 64;
                float p = 0.f;
                #pragma unroll
                for (int k = 0; k < 64; k += 8) {
                    uint4 q = *(const uint4*)(wr2 + k);
                    float4 ha = *(const float4*)(hp + k);
                    float4 hb4 = *(const float4*)(hp + k + 4);
                    p += bf_lo(q.x)*ha.x + bf_hi(q.x)*ha.y + bf_lo(q.y)*ha.z + bf_hi(q.y)*ha.w
                       + bf_lo(q.z)*hb4.x + bf_hi(q.z)*hb4.y + bf_lo(q.w)*hb4.z + bf_hi(q.w)*hb4.w;
                }
                sm.a.php[kq][a] = p;
            }
            __syncthreads();
            if (tid < 128) {
                float p = 0.f;
                #pragma unroll
                for (int kq = 0; kq < 8; kq++) p += sm.a.php[kq][tid];
                sm.a.ph[tid] = p;
            }
            __syncthreads();
            {   // score partials
                int s = tid >> 4, aq = tid & 15;
                float p = 0.f;
                if (s < 49) {
                    const float* pr = proj + (size_t)(b * 49 + s) * 128 + aq * 8;
                    #pragma unroll
                    for (int a = 0; a < 8; a++)
                        p += ftanh(pr[a] + sm.a.ph[aq * 8 + a]) * wsc[aq * 8 + a];
                }
                sm.a.scp[s][aq] = p;
            }
            __syncthreads();
            if (tid < 64) {
                float v = 0.f;
                #pragma unroll
                for (int q = 0; q < 16; q++) v += sm.a.scp[tid][q];
                if (tid >= 49) v = -1e30f;
                float m = v;
                for (int o = 32; o > 0; o >>= 1) m = fmaxf(m, __shfl_xor(m, o));
                float e = (tid < 49) ? __expf(v - m) : 0.f;
                float su = e;
                for (int o = 32; o > 0; o >>= 1) su += __shfl_xor(su, o);
                sm.a.wsm[tid] = e / su;
            }
            __syncthreads();
            {   // x = embM + sum_s w_s imgEM   (split s over 2 halves)
                int e = tid & 511, sh = tid >> 9;
                float xp = 0.f;
                if (sh == 0) xp = embM[(size_t)(t * 32 + b) * 512 + e];
                int s0 = sh * 25, s1 = sh ? 49 : 25;
                for (int s = s0; s < s1; s++)
                    xp += sm.a.wsm[s] * imgEM[(size_t)(b * 49 + s) * 512 + e];
                sm.a.xps[sh][e] = xp;
            }
            __syncthreads();
            if (tid < 512) {
                float x = fmaxf(sm.a.xps[0][tid] + sm.a.xps[1][tid], 0.f);
                float s = x, s2 = x * x;
                for (int o = 32; o > 0; o >>= 1) { s += __shfl_xor(s, o); s2 += __shfl_xor(s2, o); }
                if ((tid & 63) == 0) { sm.a.wred[tid >> 6][0] = s; sm.a.wred[tid >> 6][1] = s2; }
            }
            __syncthreads();
            if (tid == 0) {
                float s = 0.f, s2 = 0.f;
                #pragma unroll
                for (int w = 0; w < 8; w++) { s += sm.a.wred[w][0]; s2 += sm.a.wred[w][1]; }
                float mu = s * (1.f / 512.f);
                float var = s2 * (1.f / 512.f) - mu * mu;
                sm.a.bc[0] = mu; sm.a.bc[1] = rsqrtf(var + 1e-5f);
            }
            __syncthreads();
            if (tid < 512) {
                float x = fmaxf(sm.a.xps[0][tid] + sm.a.xps[1][tid], 0.f);
                float xn = (x - sm.a.bc[0]) * sm.a.bc[1] * lng[tid] + lnb[tid] + sm.a.ebs[tid];
                __hip_atomic_store((unsigned*)&XN[b * 512 + tid], __float_as_uint(xn),
                                   __ATOMIC_RELAXED, __HIP_MEMORY_SCOPE_AGENT);
            }
            __syncthreads();
            if (tid == 0)
                __hip_atomic_store(FLG + (128 + b) * 16, (unsigned)(t + 1),
                                   __ATOMIC_RELAXED, __HIP_MEMORY_SCOPE_AGENT);
        }
    }
}

// ---------------- deferred head GEMM ----------------
__global__ __launch_bounds__(256) void k_head(const ushort* __restrict__ h2bf,
        const ushort* __restrict__ Wbf, float* __restrict__ out) {
    __shared__ ushort Al[128][72];
    __shared__ ushort Bl[128][72];
    int n0 = blockIdx.x * 128, m0 = blockIdx.y * 128;
    int tid = threadIdx.x, lane = tid & 63, wid = tid >> 6;
    int wm = wid >> 1, wn = wid & 1;
    v4f acc[4][4] = {};
    for (int kt = 0; kt < 512; kt += 64) {
        __syncthreads();
        #pragma unroll
        for (int i = 0; i < 4; i++) {
            int idx = i * 256 + tid;
            int row = idx >> 3, c8 = (idx & 7) * 8;
            *(uint4*)&Al[row][c8] = *(const uint4*)&h2bf[(size_t)(m0 + row) * 512 + kt + c8];
            *(uint4*)&Bl[row][c8] = *(const uint4*)&Wbf[(size_t)(n0 + row) * 512 + kt + c8];
        }
        __syncthreads();
        #pragma unroll
        for (int kk = 0; kk < 2; kk++) {
            v8s a[4], bfr[4];
            int ko = kk * 32 + (lane >> 4) * 8;
            #pragma unroll
            for (int mi = 0; mi < 4; mi++)
                a[mi] = *(const v8s*)&Al[wm * 64 + mi * 16 + (lane & 15)][ko];
            #pragma unroll
            for (int ni = 0; ni < 4; ni++)
                bfr[ni] = *(const v8s*)&Bl[wn * 64 + ni * 16 + (lane & 15)][ko];
            #pragma unroll
            for (int mi = 0; mi < 4; mi++)
                #pragma unroll
                for (int ni = 0; ni < 4; ni++)
                    acc[mi][ni] = __builtin_amdgcn_mfma_f32_16x16x32_bf16(a[mi], bfr[ni], acc[mi][ni], 0, 0, 0);
        }
    }
    int col = lane & 15, rbase = (lane >> 4) * 4;
    #pragma unroll
    for (int mi = 0; mi < 4; mi++)
        #pragma unroll
        for (int ni = 0; ni < 4; ni++)
            #pragma unroll
            for (int r = 0; r < 4; r++) {
                int m = m0 + wm * 64 + mi * 16 + rbase + r;
                int v = n0 + wn * 64 + ni * 16 + col;
                int b = m & 31, t = m >> 5;
                out[((size_t)(b * 64 + t)) * 32000 + v] = acc[mi][ni][r];
            }
}

// ---------------- launch ----------------
extern "C" void kernel_launch(void* const* d_in, const int* in_sizes, int n_in,
                              void* d_out, int out_size, void* d_ws, size_t ws_size,
                              hipStream_t stream) {
    const float* img    = (const float*)d_in[0];
    const int*   toks   = (const int*)d_in[1];
    const float* embed  = (const float*)d_in[2];
    const float* W_ctx  = (const float*)d_in[3];
    const float* W_mix  = (const float*)d_in[4];
    const float* ln_g   = (const float*)d_in[5];
    const float* ln_b   = (const float*)d_in[6];
    const float* W_ih   = (const float*)d_in[7];
    const float* W_hh   = (const float*)d_in[8];
    const float* b_ih   = (const float*)d_in[9];
    const float* b_hh   = (const float*)d_in[10];
    const float* W_head = (const float*)d_in[11];
    const float* W_img  = (const float*)d_in[12];
    const float* W_hid  = (const float*)d_in[13];
    const float* w_sc   = (const float*)d_in[14];
    const float* W_h0   = (const float*)d_in[15];
    const float* b_h0   = (const float*)d_in[16];
    const float* W_c0   = (const float*)d_in[17];
    const float* b_c0   = (const float*)d_in[18];

    float* out = (float*)d_out;
    float* ws  = (float*)d_ws;
    ushort* Wbf    = (ushort*)(ws + WS_WBF);
    ushort* h2bf   = (ushort*)(ws + WS_H2BF);
    float*  imgEM  = ws + WS_IMGEM;
    float*  proj   = ws + WS_PROJ;
    float*  embM   = ws + WS_EMBM;
    ushort* whhbf  = (ushort*)(ws + WS_WHHBF);
    ushort* wihbf  = (ushort*)(ws + WS_WIHBF);
    ushort* whidbf = (ushort*)(ws + WS_WHIDBF);
    float*  H      = ws + WS_H;
    float*  XN     = ws + WS_XN;
    float*  C      = ws + WS_C;
    unsigned* flg  = (unsigned*)(ws + WS_FLAGS);
    float*  g      = ws + WS_G;
    float*  imgE   = ws + PS_IMGE;   // scratch inside Wbf slot
    float*  embG   = ws + PS_EMBG;   // scratch inside Wbf slot

    // prep A: gathers + fused persist-weight casts
    k_embg32<<<2048, 128, 0, stream>>>(toks, embed, embG);
    k_cast3<<<1056, 256, 0, stream>>>(W_hh, W_ih, W_hid, whhbf, wihbf, whidbf);
    // prep B: fp32-input MFMA GEMMs (convert in staging; same rounding as before)
    k_gemmF<<<dim3(4, 13), 256, 0, stream>>>(img,  W_ctx, imgE, 512, 2048, 1568, 2048, 2048, 0);
    k_gemmF<<<dim3(1, 13), 256, 0, stream>>>(img,  W_img, proj, 128, 2048, 1568, 2048, 2048, 0);
    k_gemmF<<<dim3(4, 16), 256, 0, stream>>>(embG, W_mix, embM, 512, 512, 2048, 512, 1024, 0);
    k_gemmF<<<dim3(4, 13), 256, 0, stream>>>(imgE, W_mix, imgEM, 512, 512, 1664, 512, 1024, 512);
    // prep C: init state
    k_gmean<<<32, 256, 0, stream>>>(img, g);
    k_h0c0<<<128, 256, 0, stream>>>(g, W_h0, b_h0, W_c0, b_c0, H, C);
    // prep D: head weights (overwrites scratch region — after all GEMMs)
    k_castpad<<<8000, 256, 0, stream>>>(W_head, Wbf, 32000, 32000, 512, 512, 0);
    hipMemsetAsync(flg, 0, 10240, stream);   // 160 flag slots (64B each)

    // recurrence: flag-synced, MFMA gates, LDS-pinned weights (R8-proven)
    k_persist<<<NBLK, 1024, 0, stream>>>(toks, embed, ln_g, ln_b, b_ih, b_hh, w_sc,
                                         whidbf, whhbf, wihbf, proj, imgEM, embM,
                                         H, C, XN, flg, h2bf);

    // deferred batched head GEMM
    k_head<<<dim3(250, 16), 256, 0, stream>>>(h2bf, Wbf, out);
}

// Round 11
// 1157.041 us; speedup vs baseline: 1.2057x; 1.1163x over previous
//
#include <hip/hip_runtime.h>

#define NV 32000
#define NT 64
#define NBLK 160u

typedef unsigned long long ull;
typedef unsigned short ushort;
typedef __attribute__((ext_vector_type(8))) short v8s;
typedef __attribute__((ext_vector_type(4))) float v4f;

// persistent ws layout (float offsets; ushort regions = count/2 floats)
#define WS_WBF     0          // ushort [32000][512]           -> 8192000
#define WS_H2BF    8192000    // ushort [2048][512]  (524288)  -> 8716288
#define WS_IMGEM   8716288    // f32 [1664][512]     (851968)  -> 9568256
#define WS_PROJ    9568256    // f32 [1664][128]     (212992)  -> 9781248
#define WS_EMBM    9781248    // f32 [2048][512]     (1048576) -> 10829824
#define WS_WHHBF   10829824   // ushort [2048][512]  (524288)  -> 11354112
#define WS_WIHBF   11354112   // ushort [2048][512]  (524288)  -> 11878400
#define WS_WHIDBF  11878400   // ushort [128][512]   (32768)   -> 11911168
#define WS_H       11911168   // f32 [2][32][512]    (32768)   -> 11943936
#define WS_XN      11943936   // f32 [32][512]       (16384)   -> 11960320
#define WS_C       11960320   // f32 [32][512]       (16384)   -> 11976704
#define WS_FLAGS   11976704   // 160 slots x 16 u32  (2560)    -> 11979264
#define WS_G       11979264   // f32 [32][2048]      (65536)   -> 12044800
// prep scratch (inside Wbf slot [0,8192000); dead before W_head cast)
#define PS_IMGBF   0          // ushort [1664][2048] (1703936) -> 1703936
#define PS_WCTXBF  1703936    // ushort [512][2048]  (524288)  -> 2228224
#define PS_WIMGBF  2228224    // ushort [128][2048]  (131072)  -> 2359296
#define PS_WMIXRBF 2359296    // ushort [512][512]   (131072)  -> 2490368
#define PS_IMGE    2490368    // f32 [1664][512]     (851968)  -> 3342336
#define PS_IMGEBF  3342336    // ushort [1664][512]  (425984)  -> 3768320
#define PS_EMBG    3768320    // ushort [2048][512]  (524288)  -> 4292608
#define PS_WMIXLBF 4292608    // ushort [512][512]   (131072)  -> 4423680

__device__ __forceinline__ float fsig(float x) {
    x = fminf(fmaxf(x, -30.f), 30.f);
    return 1.f / (1.f + __expf(-x));
}
__device__ __forceinline__ float ftanh(float x) {
    x = fminf(fmaxf(x, -15.f), 15.f);
    float e = __expf(2.f * x);
    return (e - 1.f) / (e + 1.f);
}
__device__ __forceinline__ unsigned short f2bf(float f) {
    union { float f; unsigned int u; } v; v.f = f;
    unsigned int u = v.u;
    return (unsigned short)((u + 0x7FFFu + ((u >> 16) & 1u)) >> 16);
}
__device__ __forceinline__ float bf_lo(unsigned u) { return __uint_as_float(u << 16); }
__device__ __forceinline__ float bf_hi(unsigned u) { return __uint_as_float(u & 0xffff0000u); }
__device__ __forceinline__ ull agld(const ull* p) {
    return __hip_atomic_load(p, __ATOMIC_RELAXED, __HIP_MEMORY_SCOPE_AGENT);
}
__device__ __forceinline__ unsigned pk2(ull v) {
    return (unsigned)f2bf(__uint_as_float((unsigned)v)) |
           ((unsigned)f2bf(__uint_as_float((unsigned)(v >> 32))) << 16);
}

// ---------------- prep kernels (R8-proven structure) ----------------

__global__ __launch_bounds__(256) void k_castpad(const float* __restrict__ in,
        ushort* __restrict__ out, int R, int Rpad, int K, int ldi, int off) {
    size_t i = ((size_t)blockIdx.x * 256 + threadIdx.x) * 8;
    if (i >= (size_t)Rpad * K) return;
    int r = (int)(i / K), k = (int)(i % K);
    uint4 o = {0, 0, 0, 0};
    if (r < R) {
        const float* p = in + (size_t)r * ldi + off + k;
        float4 a = *(const float4*)(p);
        float4 b = *(const float4*)(p + 4);
        o.x = (unsigned)f2bf(a.x) | ((unsigned)f2bf(a.y) << 16);
        o.y = (unsigned)f2bf(a.z) | ((unsigned)f2bf(a.w) << 16);
        o.z = (unsigned)f2bf(b.x) | ((unsigned)f2bf(b.y) << 16);
        o.w = (unsigned)f2bf(b.z) | ((unsigned)f2bf(b.w) << 16);
    }
    *(uint4*)(out + i) = o;
}

// gather token embeddings: embG[(t*32+b)][k] = bf16(embed[tok]*(tok!=0))
__global__ __launch_bounds__(128) void k_embg(const int* __restrict__ toks,
        const float* __restrict__ embed, ushort* __restrict__ embG) {
    int row = blockIdx.x;
    int t = row >> 5, b = row & 31;
    int tok = toks[b * 64 + t];
    int e = threadIdx.x * 4;
    uint2 o = {0, 0};
    if (tok != 0) {
        float4 a = *(const float4*)&embed[(size_t)tok * 512 + e];
        o.x = (unsigned)f2bf(a.x) | ((unsigned)f2bf(a.y) << 16);
        o.y = (unsigned)f2bf(a.z) | ((unsigned)f2bf(a.w) << 16);
    }
    *(uint2*)&embG[(size_t)row * 512 + e] = o;
}

// C[m][n] = sum_k A[m][k]*B[n][k]
__global__ __launch_bounds__(256) void k_gemm(const ushort* __restrict__ A,
        const ushort* __restrict__ B, float* __restrict__ C, int N, int K) {
    __shared__ ushort Al[128][72];
    __shared__ ushort Bl[128][72];
    int n0 = blockIdx.x * 128, m0 = blockIdx.y * 128;
    int tid = threadIdx.x, lane = tid & 63, wid = tid >> 6;
    int wm = wid >> 1, wn = wid & 1;
    v4f acc[4][4] = {};
    for (int kt = 0; kt < K; kt += 64) {
        __syncthreads();
        #pragma unroll
        for (int i = 0; i < 4; i++) {
            int idx = i * 256 + tid;
            int row = idx >> 3, c8 = (idx & 7) * 8;
            *(uint4*)&Al[row][c8] = *(const uint4*)&A[(size_t)(m0 + row) * K + kt + c8];
            *(uint4*)&Bl[row][c8] = *(const uint4*)&B[(size_t)(n0 + row) * K + kt + c8];
        }
        __syncthreads();
        #pragma unroll
        for (int kk = 0; kk < 2; kk++) {
            v8s a[4], bfr[4];
            int ko = kk * 32 + (lane >> 4) * 8;
            #pragma unroll
            for (int mi = 0; mi < 4; mi++)
                a[mi] = *(const v8s*)&Al[wm * 64 + mi * 16 + (lane & 15)][ko];
            #pragma unroll
            for (int ni = 0; ni < 4; ni++)
                bfr[ni] = *(const v8s*)&Bl[wn * 64 + ni * 16 + (lane & 15)][ko];
            #pragma unroll
            for (int mi = 0; mi < 4; mi++)
                #pragma unroll
                for (int ni = 0; ni < 4; ni++)
                    acc[mi][ni] = __builtin_amdgcn_mfma_f32_16x16x32_bf16(a[mi], bfr[ni], acc[mi][ni], 0, 0, 0);
        }
    }
    int col = lane & 15, rbase = (lane >> 4) * 4;
    #pragma unroll
    for (int mi = 0; mi < 4; mi++)
        #pragma unroll
        for (int ni = 0; ni < 4; ni++)
            #pragma unroll
            for (int r = 0; r < 4; r++) {
                int m = m0 + wm * 64 + mi * 16 + rbase + r;
                int v = n0 + wn * 64 + ni * 16 + col;
                C[(size_t)m * N + v] = acc[mi][ni][r];
            }
}

__global__ __launch_bounds__(256) void k_gmean(const float* __restrict__ img,
                                               float* __restrict__ g) {
    int b = blockIdx.x;
    for (int d = threadIdx.x; d < 2048; d += 256) {
        float s = 0.f;
        for (int ss = 0; ss < 49; ss++) s += img[((size_t)(b * 49 + ss)) * 2048 + d];
        g[b * 2048 + d] = s * (1.f / 49.f);
    }
}

__global__ __launch_bounds__(256) void k_h0c0(const float* __restrict__ g,
        const float* __restrict__ Wh0, const float* __restrict__ bh0,
        const float* __restrict__ Wc0, const float* __restrict__ bc0,
        float* __restrict__ h0, float* __restrict__ c0) {
    int b = blockIdx.x >> 1, m = blockIdx.x & 1;
    __shared__ float gs[2048];
    for (int d = threadIdx.x; d < 2048; d += 256) gs[d] = g[b * 2048 + d];
    __syncthreads();
    const float* W = m ? Wc0 : Wh0;
    const float* bb = m ? bc0 : bh0;
    float* out = m ? c0 : h0;
    for (int r = threadIdx.x; r < 512; r += 256) {
        float acc = 0.f;
        const float* wr = W + (size_t)r * 2048;
        for (int d = 0; d < 2048; d += 4) {
            float4 w = *(const float4*)(wr + d);
            acc += w.x * gs[d] + w.y * gs[d + 1] + w.z * gs[d + 2] + w.w * gs[d + 3];
        }
        out[b * 512 + r] = ftanh(acc + bb[r]) * 0.5f;
    }
}

// ---------------- persistent recurrence (exact R8 structure) ----------------
// 128 gates blocks (jc x bg): LDS-pinned weights, MFMA gates GEMM.
// 32 attn blocks: per-batch attention + LN.
// Sync via per-producer epoch flags (64B-padded slots), no global barrier.

__device__ __forceinline__ void waitflags(unsigned* FLG, int base, int stride,
                                          int n, unsigned tgt) {
    if (threadIdx.x < 64) {
        bool done;
        do {
            unsigned v = tgt;
            if ((int)threadIdx.x < n)
                v = __hip_atomic_load(FLG + (base + (int)threadIdx.x * stride) * 16,
                                      __ATOMIC_RELAXED, __HIP_MEMORY_SCOPE_AGENT);
            done = __all((int)(v >= tgt));
            if (!done) __builtin_amdgcn_s_sleep(1);
        } while (!done);
    }
    __syncthreads();
}

union SMem {
    struct {                       // gates role (blocks 0..127)
        ushort wh[64][520];        // W_hh rows (64 = 4 gates x 16 j), bf16
        ushort wi[64][520];        // W_ih rows
        ushort hsb[16][520];       // h / xn staged bf16 (rows 8..15 zero)
        float gtmp[4][16][16];     // [gate][jl][m]
    } g;                           // 153856 B
    struct {                       // attention role (blocks 128..159)
        float hb[512];
        float ebs[512];
        float php[8][128];
        float ph[128];
        float scp[64][16];
        float wsm[64];
        float xps[2][512];
        float wred[8][2];
        float bc[2];
    } a;
};

__global__ __launch_bounds__(1024, 1) void k_persist(
        const int* __restrict__ toks, const float* __restrict__ embed,
        const float* __restrict__ lng, const float* __restrict__ lnb,
        const float* __restrict__ bih, const float* __restrict__ bhh,
        const float* __restrict__ wsc, const ushort* __restrict__ whidbf,
        const ushort* __restrict__ whhbf, const ushort* __restrict__ wihbf,
        const float* __restrict__ proj, const float* __restrict__ imgEM,
        const float* __restrict__ embM, float* __restrict__ H,
        const float* __restrict__ C0, float* __restrict__ XN,
        unsigned* __restrict__ FLG, ushort* __restrict__ h2bf) {
    __shared__ SMem sm;
    int blk = blockIdx.x, tid = threadIdx.x;

    if (blk < 128) {
        // ---------------- gates role ----------------
        int jc = blk >> 2, bg = blk & 3, b0 = bg * 8;
        int wid = tid >> 6, lane = tid & 63;
        int gate = wid & 3;
        for (int i = tid; i < 4096; i += 1024) {
            int rr = i >> 6, c8 = (i & 63) * 8;
            size_t R = (size_t)((rr >> 4) * 512 + jc * 16 + (rr & 15)) * 512 + c8;
            *(uint4*)&sm.g.wh[rr][c8] = *(const uint4*)&whhbf[R];
            *(uint4*)&sm.g.wi[rr][c8] = *(const uint4*)&wihbf[R];
        }
        for (int i = tid; i < 2080; i += 1024) ((ull*)sm.g.hsb)[i] = 0;
        float c_reg = 0.f, bs0 = 0.f, bs1 = 0.f, bs2 = 0.f, bs3 = 0.f;
        if (tid < 128) {
            int jl = tid >> 3, bb = tid & 7;
            int j = jc * 16 + jl;
            c_reg = C0[(b0 + bb) * 512 + j];
            bs0 = bih[j] + bhh[j];
            bs1 = bih[512 + j] + bhh[512 + j];
            bs2 = bih[1024 + j] + bhh[1024 + j];
            bs3 = bih[1536 + j] + bhh[1536 + j];
        }
        __syncthreads();

        for (int t = 0; t < NT; t++) {
            waitflags(FLG, bg, 4, 32, (unsigned)t);
            {   // stage h -> hsb bf16 (rows 0..7)
                const float* Hb = H + (t & 1) * 16384 + b0 * 512;
                if (tid < 512) {
                    int bb = tid >> 6, c8 = (tid & 63) * 8;
                    const ull* p = (const ull*)(Hb + bb * 512 + c8);
                    uint4 o = { pk2(agld(p)), pk2(agld(p + 1)),
                                pk2(agld(p + 2)), pk2(agld(p + 3)) };
                    *(uint4*)&sm.g.hsb[bb][c8] = o;
                }
            }
            __syncthreads();
            v4f acc = {};
            if (wid < 4) {
                #pragma unroll
                for (int ks = 0; ks < 16; ks++) {
                    int ko = ks * 32 + (lane >> 4) * 8;
                    v8s a = *(const v8s*)&sm.g.hsb[lane & 15][ko];
                    v8s b = *(const v8s*)&sm.g.wh[gate * 16 + (lane & 15)][ko];
                    acc = __builtin_amdgcn_mfma_f32_16x16x32_bf16(a, b, acc, 0, 0, 0);
                }
            }
            waitflags(FLG, 128 + b0, 1, 8, (unsigned)(t + 1));
            {   // stage xn -> hsb bf16
                const float* Xb = XN + b0 * 512;
                if (tid < 512) {
                    int bb = tid >> 6, c8 = (tid & 63) * 8;
                    const ull* p = (const ull*)(Xb + bb * 512 + c8);
                    uint4 o = { pk2(agld(p)), pk2(agld(p + 1)),
                                pk2(agld(p + 2)), pk2(agld(p + 3)) };
                    *(uint4*)&sm.g.hsb[bb][c8] = o;
                }
            }
            __syncthreads();
            if (wid < 4) {
                #pragma unroll
                for (int ks = 0; ks < 16; ks++) {
                    int ko = ks * 32 + (lane >> 4) * 8;
                    v8s a = *(const v8s*)&sm.g.hsb[lane & 15][ko];
                    v8s b = *(const v8s*)&sm.g.wi[gate * 16 + (lane & 15)][ko];
                    acc = __builtin_amdgcn_mfma_f32_16x16x32_bf16(a, b, acc, 0, 0, 0);
                }
                #pragma unroll
                for (int q = 0; q < 4; q++)
                    sm.g.gtmp[gate][lane & 15][(lane >> 4) * 4 + q] = acc[q];
            }
            __syncthreads();
            if (tid < 128) {
                int jl = tid >> 3, bb = tid & 7;
                float vi = sm.g.gtmp[0][jl][bb] + bs0;
                float vf = sm.g.gtmp[1][jl][bb] + bs1;
                float vg = sm.g.gtmp[2][jl][bb] + bs2;
                float vo = sm.g.gtmp[3][jl][bb] + bs3;
                float c2 = fsig(vf) * c_reg + fsig(vi) * ftanh(vg);
                float h2 = fsig(vo) * ftanh(c2);
                c_reg = c2;
                int bglob = b0 + bb, j = jc * 16 + jl;
                __hip_atomic_store((unsigned*)&H[((t + 1) & 1) * 16384 + bglob * 512 + j],
                                   __float_as_uint(h2), __ATOMIC_RELAXED, __HIP_MEMORY_SCOPE_AGENT);
                h2bf[(size_t)(t * 32 + bglob) * 512 + j] = f2bf(h2);
            }
            __syncthreads();
            if (tid == 0)
                __hip_atomic_store(FLG + blk * 16, (unsigned)(t + 1),
                                   __ATOMIC_RELAXED, __HIP_MEMORY_SCOPE_AGENT);
        }
    } else {
        // ---------------- attention role ----------------
        int b = blk - 128, bgb = b >> 3;
        for (int t = 0; t < NT; t++) {
            waitflags(FLG, bgb, 4, 32, (unsigned)t);
            int tok = toks[b * 64 + t];
            if (tid < 256) {
                ull v = agld((const ull*)(H + (t & 1) * 16384) + b * 256 + tid);
                *(ull*)&sm.a.hb[tid * 2] = v;
            } else if (tid < 768) {
                int k = tid - 256;
                sm.a.ebs[k] = (tok == 0) ? 0.f : embed[(size_t)tok * 512 + k];
            }
            __syncthreads();
            {   // ph partials (whid from L2, bf16)
                int a = tid & 127, kq = tid >> 7;
                const ushort* wr2 = whidbf + (size_t)a * 512 + kq * 64;
                const float* hp = sm.a.hb + kq * 64;
                float p = 0.f;
                #pragma unroll
                for (int k = 0; k < 64; k += 8) {
                    uint4 q = *(const uint4*)(wr2 + k);
                    float4 ha = *(const float4*)(hp + k);
                    float4 hb4 = *(const float4*)(hp + k + 4);
                    p += bf_lo(q.x)*ha.x + bf_hi(q.x)*ha.y + bf_lo(q.y)*ha.z + bf_hi(q.y)*ha.w
                       + bf_lo(q.z)*hb4.x + bf_hi(q.z)*hb4.y + bf_lo(q.w)*hb4.z + bf_hi(q.w)*hb4.w;
                }
                sm.a.php[kq][a] = p;
            }
            __syncthreads();
            if (tid < 128) {
                float p = 0.f;
                #pragma unroll
                for (int kq = 0; kq < 8; kq++) p += sm.a.php[kq][tid];
                sm.a.ph[tid] = p;
            }
            __syncthreads();
            {   // score partials
                int s = tid >> 4, aq = tid & 15;
                float p = 0.f;
                if (s < 49) {
                    const float* pr = proj + (size_t)(b * 49 + s) * 128 + aq * 8;
                    #pragma unroll
                    for (int a = 0; a < 8; a++)
                        p += ftanh(pr[a] + sm.a.ph[aq * 8 + a]) * wsc[aq * 8 + a];
                }
                sm.a.scp[s][aq] = p;
            }
            __syncthreads();
            if (tid < 64) {
                float v = 0.f;
                #pragma unroll
                for (int q = 0; q < 16; q++) v += sm.a.scp[tid][q];
                if (tid >= 49) v = -1e30f;
                float m = v;
                for (int o = 32; o > 0; o >>= 1) m = fmaxf(m, __shfl_xor(m, o));
                float e = (tid < 49) ? __expf(v - m) : 0.f;
                float su = e;
                for (int o = 32; o > 0; o >>= 1) su += __shfl_xor(su, o);
                sm.a.wsm[tid] = e / su;
            }
            __syncthreads();
            {   // x = embM + sum_s w_s imgEM   (split s over 2 halves)
                int e = tid & 511, sh = tid >> 9;
                float xp = 0.f;
                if (sh == 0) xp = embM[(size_t)(t * 32 + b) * 512 + e];
                int s0 = sh * 25, s1 = sh ? 49 : 25;
                for (int s = s0; s < s1; s++)
                    xp += sm.a.wsm[s] * imgEM[(size_t)(b * 49 + s) * 512 + e];
                sm.a.xps[sh][e] = xp;
            }
            __syncthreads();
            if (tid < 512) {
                float x = fmaxf(sm.a.xps[0][tid] + sm.a.xps[1][tid], 0.f);
                float s = x, s2 = x * x;
                for (int o = 32; o > 0; o >>= 1) { s += __shfl_xor(s, o); s2 += __shfl_xor(s2, o); }
                if ((tid & 63) == 0) { sm.a.wred[tid >> 6][0] = s; sm.a.wred[tid >> 6][1] = s2; }
            }
            __syncthreads();
            if (tid == 0) {
                float s = 0.f, s2 = 0.f;
                #pragma unroll
                for (int w = 0; w < 8; w++) { s += sm.a.wred[w][0]; s2 += sm.a.wred[w][1]; }
                float mu = s * (1.f / 512.f);
                float var = s2 * (1.f / 512.f) - mu * mu;
                sm.a.bc[0] = mu; sm.a.bc[1] = rsqrtf(var + 1e-5f);
            }
            __syncthreads();
            if (tid < 512) {
                float x = fmaxf(sm.a.xps[0][tid] + sm.a.xps[1][tid], 0.f);
                float xn = (x - sm.a.bc[0]) * sm.a.bc[1] * lng[tid] + lnb[tid] + sm.a.ebs[tid];
                __hip_atomic_store((unsigned*)&XN[b * 512 + tid], __float_as_uint(xn),
                                   __ATOMIC_RELAXED, __HIP_MEMORY_SCOPE_AGENT);
            }
            __syncthreads();
            if (tid == 0)
                __hip_atomic_store(FLG + (128 + b) * 16, (unsigned)(t + 1),
                                   __ATOMIC_RELAXED, __HIP_MEMORY_SCOPE_AGENT);
        }
    }
}

// ---------------- deferred head GEMM: 256(m)x128(n) tile, 512 thr ----------------
// grid (8 m-tiles, 250 n-tiles), m fastest: the 8 same-n blocks dispatch
// consecutively across XCDs -> each B-tile is read concurrently (L3-hit).
// B traffic halves vs 128^2 (16 -> 8 m-tile re-reads of 32MB Wbf).
__global__ __launch_bounds__(512) void k_head(const ushort* __restrict__ h2bf,
        const ushort* __restrict__ Wbf, float* __restrict__ out) {
    __shared__ ushort Al[256][72];
    __shared__ ushort Bl[128][72];
    int m0 = blockIdx.x * 256;   // (t,b) tile
    int n0 = blockIdx.y * 128;   // vocab tile
    int tid = threadIdx.x, lane = tid & 63, wid = tid >> 6;
    int wm = wid >> 1, wn = wid & 1;   // 4 m-quadrants x 2 n-halves, 64x64 each
    v4f acc[4][4] = {};
    for (int kt = 0; kt < 512; kt += 64) {
        __syncthreads();
        #pragma unroll
        for (int i = 0; i < 4; i++) {
            int idx = i * 512 + tid;
            int row = idx >> 3, c8 = (idx & 7) * 8;
            *(uint4*)&Al[row][c8] = *(const uint4*)&h2bf[(size_t)(m0 + row) * 512 + kt + c8];
        }
        #pragma unroll
        for (int i = 0; i < 2; i++) {
            int idx = i * 512 + tid;
            int row = idx >> 3, c8 = (idx & 7) * 8;
            *(uint4*)&Bl[row][c8] = *(const uint4*)&Wbf[(size_t)(n0 + row) * 512 + kt + c8];
        }
        __syncthreads();
        #pragma unroll
        for (int kk = 0; kk < 2; kk++) {
            v8s a[4], bfr[4];
            int ko = kk * 32 + (lane >> 4) * 8;
            #pragma unroll
            for (int mi = 0; mi < 4; mi++)
                a[mi] = *(const v8s*)&Al[wm * 64 + mi * 16 + (lane & 15)][ko];
            #pragma unroll
            for (int ni = 0; ni < 4; ni++)
                bfr[ni] = *(const v8s*)&Bl[wn * 64 + ni * 16 + (lane & 15)][ko];
            #pragma unroll
            for (int mi = 0; mi < 4; mi++)
                #pragma unroll
                for (int ni = 0; ni < 4; ni++)
                    acc[mi][ni] = __builtin_amdgcn_mfma_f32_16x16x32_bf16(a[mi], bfr[ni], acc[mi][ni], 0, 0, 0);
        }
    }
    int col = lane & 15, rbase = (lane >> 4) * 4;
    #pragma unroll
    for (int mi = 0; mi < 4; mi++)
        #pragma unroll
        for (int ni = 0; ni < 4; ni++)
            #pragma unroll
            for (int r = 0; r < 4; r++) {
                int m = m0 + wm * 64 + mi * 16 + rbase + r;
                int v = n0 + wn * 64 + ni * 16 + col;
                int b = m & 31, t = m >> 5;
                out[((size_t)(b * 64 + t)) * 32000 + v] = acc[mi][ni][r];
            }
}

// ---------------- launch ----------------
extern "C" void kernel_launch(void* const* d_in, const int* in_sizes, int n_in,
                              void* d_out, int out_size, void* d_ws, size_t ws_size,
                              hipStream_t stream) {
    const float* img    = (const float*)d_in[0];
    const int*   toks   = (const int*)d_in[1];
    const float* embed  = (const float*)d_in[2];
    const float* W_ctx  = (const float*)d_in[3];
    const float* W_mix  = (const float*)d_in[4];
    const float* ln_g   = (const float*)d_in[5];
    const float* ln_b   = (const float*)d_in[6];
    const float* W_ih   = (const float*)d_in[7];
    const float* W_hh   = (const float*)d_in[8];
    const float* b_ih   = (const float*)d_in[9];
    const float* b_hh   = (const float*)d_in[10];
    const float* W_head = (const float*)d_in[11];
    const float* W_img  = (const float*)d_in[12];
    const float* W_hid  = (const float*)d_in[13];
    const float* w_sc   = (const float*)d_in[14];
    const float* W_h0   = (const float*)d_in[15];
    const float* b_h0   = (const float*)d_in[16];
    const float* W_c0   = (const float*)d_in[17];
    const float* b_c0   = (const float*)d_in[18];

    float* out = (float*)d_out;
    float* ws  = (float*)d_ws;
    ushort* Wbf    = (ushort*)(ws + WS_WBF);
    ushort* h2bf   = (ushort*)(ws + WS_H2BF);
    float*  imgEM  = ws + WS_IMGEM;
    float*  proj   = ws + WS_PROJ;
    float*  embM   = ws + WS_EMBM;
    ushort* whhbf  = (ushort*)(ws + WS_WHHBF);
    ushort* wihbf  = (ushort*)(ws + WS_WIHBF);
    ushort* whidbf = (ushort*)(ws + WS_WHIDBF);
    float*  H      = ws + WS_H;
    float*  XN     = ws + WS_XN;
    float*  C      = ws + WS_C;
    unsigned* flg  = (unsigned*)(ws + WS_FLAGS);
    float*  g      = ws + WS_G;
    // prep scratch (inside Wbf slot)
    ushort* imgbf   = (ushort*)(ws + PS_IMGBF);
    ushort* wctxbf  = (ushort*)(ws + PS_WCTXBF);
    ushort* wimgbf  = (ushort*)(ws + PS_WIMGBF);
    ushort* wmixRbf = (ushort*)(ws + PS_WMIXRBF);
    float*  imgE    = ws + PS_IMGE;
    ushort* imgEbf  = (ushort*)(ws + PS_IMGEBF);
    ushort* embG    = (ushort*)(ws + PS_EMBG);
    ushort* wmixLbf = (ushort*)(ws + PS_WMIXLBF);

    // prep A: casts into scratch (R8-proven)
    k_castpad<<<1664, 256, 0, stream>>>(img,   imgbf,   1568, 1664, 2048, 2048, 0);
    k_castpad<<<512,  256, 0, stream>>>(W_ctx, wctxbf,  512,  512,  2048, 2048, 0);
    k_castpad<<<128,  256, 0, stream>>>(W_img, wimgbf,  128,  128,  2048, 2048, 0);
    k_castpad<<<128,  256, 0, stream>>>(W_mix, wmixRbf, 512,  512,  512,  1024, 512);
    k_castpad<<<128,  256, 0, stream>>>(W_mix, wmixLbf, 512,  512,  512,  1024, 0);
    k_embg<<<2048, 128, 0, stream>>>(toks, embed, embG);
    // prep B: MFMA GEMMs
    k_gemm<<<dim3(4, 13), 256, 0, stream>>>(imgbf, wctxbf, imgE, 512, 2048);
    k_gemm<<<dim3(1, 13), 256, 0, stream>>>(imgbf, wimgbf, proj, 128, 2048);
    k_gemm<<<dim3(4, 16), 256, 0, stream>>>(embG, wmixLbf, embM, 512, 512);
    k_castpad<<<416, 256, 0, stream>>>(imgE, imgEbf, 1664, 1664, 512, 512, 0);
    k_gemm<<<dim3(4, 13), 256, 0, stream>>>(imgEbf, wmixRbf, imgEM, 512, 512);
    // prep C: persistent bf16 weights
    k_castpad<<<512, 256, 0, stream>>>(W_hh,  whhbf,  2048, 2048, 512, 512, 0);
    k_castpad<<<512, 256, 0, stream>>>(W_ih,  wihbf,  2048, 2048, 512, 512, 0);
    k_castpad<<<32,  256, 0, stream>>>(W_hid, whidbf, 128,  128,  512, 512, 0);
    // prep D: head weights (overwrites scratch region)
    k_castpad<<<8000, 256, 0, stream>>>(W_head, Wbf, 32000, 32000, 512, 512, 0);
    // prep E: init state (h0 into H parity-0 buffer)
    k_gmean<<<32, 256, 0, stream>>>(img, g);
    k_h0c0<<<64, 256, 0, stream>>>(g, W_h0, b_h0, W_c0, b_c0, H, C);
    hipMemsetAsync(flg, 0, 10240, stream);   // 160 flag slots (64B each)

    // recurrence: flag-synced, MFMA gates, LDS-pinned weights (R8-proven)
    k_persist<<<NBLK, 1024, 0, stream>>>(toks, embed, ln_g, ln_b, b_ih, b_hh, w_sc,
                                         whidbf, whhbf, wihbf, proj, imgEM, embM,
                                         H, C, XN, flg, h2bf);

    // deferred batched head GEMM: 256x128 tiles, grid (m=8, n=250)
    k_head<<<dim3(8, 250), 512, 0, stream>>>(h2bf, Wbf, out);
}

// Round 12
// 1146.598 us; speedup vs baseline: 1.2167x; 1.0091x over previous
//
#include <hip/hip_runtime.h>

#define NV 32000
#define NT 64
#define NBLK 160u

typedef unsigned long long ull;
typedef unsigned short ushort;
typedef __attribute__((ext_vector_type(8))) short v8s;
typedef __attribute__((ext_vector_type(4))) float v4f;

// persistent ws layout (float offsets; ushort regions = count/2 floats)
#define WS_WBF     0          // ushort [32000][512]           -> 8192000
#define WS_H2BF    8192000    // ushort [2048][512]  (524288)  -> 8716288
#define WS_IMGEM   8716288    // f32 [1664][512]     (851968)  -> 9568256
#define WS_PROJ    9568256    // f32 [1664][128]     (212992)  -> 9781248
#define WS_EMBM    9781248    // f32 [2048][512]     (1048576) -> 10829824
#define WS_WHHBF   10829824   // ushort [2048][512]  (524288)  -> 11354112
#define WS_WIHBF   11354112   // ushort [2048][512]  (524288)  -> 11878400
#define WS_WHIDBF  11878400   // ushort [128][512]   (32768)   -> 11911168
#define WS_H       11911168   // f32 [2][32][512]    (32768)   -> 11943936
#define WS_XN      11943936   // f32 [32][512]       (16384)   -> 11960320
#define WS_C       11960320   // f32 [32][512]       (16384)   -> 11976704
#define WS_FLAGS   11976704   // 160 slots x 16 u32  (2560)    -> 11979264
#define WS_G       11979264   // f32 [32][2048]      (65536)   -> 12044800
// prep scratch (inside Wbf slot [0,8192000); dead before W_head cast)
#define PS_IMGBF   0          // ushort [1664][2048] (1703936) -> 1703936
#define PS_WCTXBF  1703936    // ushort [512][2048]  (524288)  -> 2228224
#define PS_WIMGBF  2228224    // ushort [128][2048]  (131072)  -> 2359296
#define PS_WMIXRBF 2359296    // ushort [512][512]   (131072)  -> 2490368
#define PS_WMIXLBF 2490368    // ushort [512][512]   (131072)  -> 2621440
#define PS_IMGEBF  3342336    // ushort [1664][512]  (425984)  -> 3768320

__device__ __forceinline__ float fsig(float x) {
    x = fminf(fmaxf(x, -30.f), 30.f);
    return 1.f / (1.f + __expf(-x));
}
__device__ __forceinline__ float ftanh(float x) {
    x = fminf(fmaxf(x, -15.f), 15.f);
    float e = __expf(2.f * x);
    return (e - 1.f) / (e + 1.f);
}
__device__ __forceinline__ unsigned short f2bf(float f) {
    union { float f; unsigned int u; } v; v.f = f;
    unsigned int u = v.u;
    return (unsigned short)((u + 0x7FFFu + ((u >> 16) & 1u)) >> 16);
}
__device__ __forceinline__ unsigned pkf(float x, float y) {
    return (unsigned)f2bf(x) | ((unsigned)f2bf(y) << 16);
}
__device__ __forceinline__ float bf_lo(unsigned u) { return __uint_as_float(u << 16); }
__device__ __forceinline__ float bf_hi(unsigned u) { return __uint_as_float(u & 0xffff0000u); }
__device__ __forceinline__ ull agld(const ull* p) {
    return __hip_atomic_load(p, __ATOMIC_RELAXED, __HIP_MEMORY_SCOPE_AGENT);
}
__device__ __forceinline__ unsigned pk2(ull v) {
    return (unsigned)f2bf(__uint_as_float((unsigned)v)) |
           ((unsigned)f2bf(__uint_as_float((unsigned)(v >> 32))) << 16);
}

// ---------------- prep kernels ----------------

// plain fp32->bf16 cast (W_head only)
__global__ __launch_bounds__(256) void k_castpad(const float* __restrict__ in,
        ushort* __restrict__ out, int R, int Rpad, int K, int ldi, int off) {
    size_t i = ((size_t)blockIdx.x * 256 + threadIdx.x) * 8;
    if (i >= (size_t)Rpad * K) return;
    int r = (int)(i / K), k = (int)(i % K);
    uint4 o = {0, 0, 0, 0};
    if (r < R) {
        const float* p = in + (size_t)r * ldi + off + k;
        float4 a = *(const float4*)(p);
        float4 b = *(const float4*)(p + 4);
        o.x = pkf(a.x, a.y); o.y = pkf(a.z, a.w);
        o.z = pkf(b.x, b.y); o.w = pkf(b.z, b.w);
    }
    *(uint4*)(out + i) = o;
}

// single launch: all 8 bf16 weight/input casts + flag zeroing
__global__ __launch_bounds__(256) void k_castall(
        const float* __restrict__ img, const float* __restrict__ Wctx,
        const float* __restrict__ Wimg, const float* __restrict__ Wmix,
        const float* __restrict__ Whh, const float* __restrict__ Wih,
        const float* __restrict__ Whid,
        ushort* __restrict__ imgbf, ushort* __restrict__ wctxbf,
        ushort* __restrict__ wimgbf, ushort* __restrict__ wmixRbf,
        ushort* __restrict__ wmixLbf, ushort* __restrict__ whhbf,
        ushort* __restrict__ wihbf, ushort* __restrict__ whidbf,
        unsigned* __restrict__ flg) {
    int blk = blockIdx.x, tid = threadIdx.x;
    if (blk >= 3616) {                       // zero the 160 flag slots
        for (int i = tid; i < 2560; i += 256) flg[i] = 0u;
        return;
    }
    const float* in; ushort* out; int R, K, ldi, off;
    if (blk < 1664)      { in = img;  out = imgbf;   R = 1568; K = 2048; ldi = 2048; off = 0; }
    else if (blk < 2176) { in = Wctx; out = wctxbf;  R = 512;  K = 2048; ldi = 2048; off = 0;   blk -= 1664; }
    else if (blk < 2304) { in = Wimg; out = wimgbf;  R = 128;  K = 2048; ldi = 2048; off = 0;   blk -= 2176; }
    else if (blk < 2432) { in = Wmix; out = wmixRbf; R = 512;  K = 512;  ldi = 1024; off = 512; blk -= 2304; }
    else if (blk < 2560) { in = Wmix; out = wmixLbf; R = 512;  K = 512;  ldi = 1024; off = 0;   blk -= 2432; }
    else if (blk < 3072) { in = Whh;  out = whhbf;   R = 2048; K = 512;  ldi = 512;  off = 0;   blk -= 2560; }
    else if (blk < 3584) { in = Wih;  out = wihbf;   R = 2048; K = 512;  ldi = 512;  off = 0;   blk -= 3072; }
    else                 { in = Whid; out = whidbf;  R = 128;  K = 512;  ldi = 512;  off = 0;   blk -= 3584; }
    size_t i = ((size_t)blk * 256 + tid) * 8;
    int r = (int)(i / K), k = (int)(i % K);
    uint4 o = {0, 0, 0, 0};
    if (r < R) {
        const float* p = in + (size_t)r * ldi + off + k;
        float4 a = *(const float4*)(p);
        float4 b = *(const float4*)(p + 4);
        o.x = pkf(a.x, a.y); o.y = pkf(a.z, a.w);
        o.z = pkf(b.x, b.y); o.w = pkf(b.z, b.w);
    }
    *(uint4*)(out + i) = o;
}

// generic bf16 GEMM, fp32 out: C[m][n] = sum_k A[m][k]*B[n][k]
__global__ __launch_bounds__(256) void k_gemm(const ushort* __restrict__ A,
        const ushort* __restrict__ B, float* __restrict__ C, int N, int K) {
    __shared__ ushort Al[128][72];
    __shared__ ushort Bl[128][72];
    int n0 = blockIdx.x * 128, m0 = blockIdx.y * 128;
    int tid = threadIdx.x, lane = tid & 63, wid = tid >> 6;
    int wm = wid >> 1, wn = wid & 1;
    v4f acc[4][4] = {};
    for (int kt = 0; kt < K; kt += 64) {
        __syncthreads();
        #pragma unroll
        for (int i = 0; i < 4; i++) {
            int idx = i * 256 + tid;
            int row = idx >> 3, c8 = (idx & 7) * 8;
            *(uint4*)&Al[row][c8] = *(const uint4*)&A[(size_t)(m0 + row) * K + kt + c8];
            *(uint4*)&Bl[row][c8] = *(const uint4*)&B[(size_t)(n0 + row) * K + kt + c8];
        }
        __syncthreads();
        #pragma unroll
        for (int kk = 0; kk < 2; kk++) {
            v8s a[4], bfr[4];
            int ko = kk * 32 + (lane >> 4) * 8;
            #pragma unroll
            for (int mi = 0; mi < 4; mi++)
                a[mi] = *(const v8s*)&Al[wm * 64 + mi * 16 + (lane & 15)][ko];
            #pragma unroll
            for (int ni = 0; ni < 4; ni++)
                bfr[ni] = *(const v8s*)&Bl[wn * 64 + ni * 16 + (lane & 15)][ko];
            #pragma unroll
            for (int mi = 0; mi < 4; mi++)
                #pragma unroll
                for (int ni = 0; ni < 4; ni++)
                    acc[mi][ni] = __builtin_amdgcn_mfma_f32_16x16x32_bf16(a[mi], bfr[ni], acc[mi][ni], 0, 0, 0);
        }
    }
    int col = lane & 15, rbase = (lane >> 4) * 4;
    #pragma unroll
    for (int mi = 0; mi < 4; mi++)
        #pragma unroll
        for (int ni = 0; ni < 4; ni++)
            #pragma unroll
            for (int r = 0; r < 4; r++) {
                int m = m0 + wm * 64 + mi * 16 + rbase + r;
                int v = n0 + wn * 64 + ni * 16 + col;
                C[(size_t)m * N + v] = acc[mi][ni][r];
            }
}

// fused triple GEMM in one launch:
//  blocks [0,52):   imgEbf = bf16(imgbf @ wctxbf^T)        K=2048, bf16 out
//  blocks [52,65):  proj   = imgbf @ wimgbf^T              K=2048, fp32 out
//  blocks [65,129): embM   = gather(embed,toks) @ wmixL^T  K=512,  fp32 out
__global__ __launch_bounds__(256) void k_gemm3(
        const ushort* __restrict__ imgbf, const ushort* __restrict__ wctxbf,
        const ushort* __restrict__ wimgbf, const float* __restrict__ embed,
        const int* __restrict__ toks, const ushort* __restrict__ wmixLbf,
        ushort* __restrict__ imgEbf, float* __restrict__ proj,
        float* __restrict__ embM) {
    __shared__ ushort Al[128][72];
    __shared__ ushort Bl[128][72];
    int bid = blockIdx.x;
    const ushort* A; const ushort* B; int mode, K, N, n0, m0;
    if (bid < 52)      { mode = 0; A = imgbf; B = wctxbf;  K = 2048; N = 512; n0 = (bid & 3) * 128; m0 = (bid >> 2) * 128; }
    else if (bid < 65) { mode = 1; A = imgbf; B = wimgbf;  K = 2048; N = 128; n0 = 0;               m0 = (bid - 52) * 128; }
    else { int e = bid - 65; mode = 2; A = nullptr; B = wmixLbf; K = 512; N = 512; n0 = (e & 3) * 128; m0 = (e >> 2) * 128; }
    int tid = threadIdx.x, lane = tid & 63, wid = tid >> 6;
    int wm = wid >> 1, wn = wid & 1;
    v4f acc[4][4] = {};
    for (int kt = 0; kt < K; kt += 64) {
        __syncthreads();
        #pragma unroll
        for (int i = 0; i < 4; i++) {
            int idx = i * 256 + tid;
            int row = idx >> 3, c8 = (idx & 7) * 8;
            if (mode == 2) {
                int rowg = m0 + row;
                int tok = toks[(rowg & 31) * 64 + (rowg >> 5)];
                uint4 oa = {0, 0, 0, 0};
                if (tok != 0) {
                    const float* pa = embed + (size_t)tok * 512 + kt + c8;
                    float4 a0 = *(const float4*)pa, a1 = *(const float4*)(pa + 4);
                    oa.x = pkf(a0.x, a0.y); oa.y = pkf(a0.z, a0.w);
                    oa.z = pkf(a1.x, a1.y); oa.w = pkf(a1.z, a1.w);
                }
                *(uint4*)&Al[row][c8] = oa;
            } else {
                *(uint4*)&Al[row][c8] = *(const uint4*)&A[(size_t)(m0 + row) * K + kt + c8];
            }
            *(uint4*)&Bl[row][c8] = *(const uint4*)&B[(size_t)(n0 + row) * K + kt + c8];
        }
        __syncthreads();
        #pragma unroll
        for (int kk = 0; kk < 2; kk++) {
            v8s a[4], bfr[4];
            int ko = kk * 32 + (lane >> 4) * 8;
            #pragma unroll
            for (int mi = 0; mi < 4; mi++)
                a[mi] = *(const v8s*)&Al[wm * 64 + mi * 16 + (lane & 15)][ko];
            #pragma unroll
            for (int ni = 0; ni < 4; ni++)
                bfr[ni] = *(const v8s*)&Bl[wn * 64 + ni * 16 + (lane & 15)][ko];
            #pragma unroll
            for (int mi = 0; mi < 4; mi++)
                #pragma unroll
                for (int ni = 0; ni < 4; ni++)
                    acc[mi][ni] = __builtin_amdgcn_mfma_f32_16x16x32_bf16(a[mi], bfr[ni], acc[mi][ni], 0, 0, 0);
        }
    }
    int col = lane & 15, rbase = (lane >> 4) * 4;
    #pragma unroll
    for (int mi = 0; mi < 4; mi++)
        #pragma unroll
        for (int ni = 0; ni < 4; ni++)
            #pragma unroll
            for (int r = 0; r < 4; r++) {
                int m = m0 + wm * 64 + mi * 16 + rbase + r;
                int v = n0 + wn * 64 + ni * 16 + col;
                if (mode == 0)      imgEbf[(size_t)m * 512 + v] = f2bf(acc[mi][ni][r]);
                else if (mode == 1) proj[(size_t)m * 128 + v] = acc[mi][ni][r];
                else                embM[(size_t)m * 512 + v] = acc[mi][ni][r];
            }
}

__global__ __launch_bounds__(256) void k_gmean(const float* __restrict__ img,
                                               float* __restrict__ g) {
    int b = blockIdx.x;
    for (int d = threadIdx.x; d < 2048; d += 256) {
        float s = 0.f;
        for (int ss = 0; ss < 49; ss++) s += img[((size_t)(b * 49 + ss)) * 2048 + d];
        g[b * 2048 + d] = s * (1.f / 49.f);
    }
}

__global__ __launch_bounds__(256) void k_h0c0(const float* __restrict__ g,
        const float* __restrict__ Wh0, const float* __restrict__ bh0,
        const float* __restrict__ Wc0, const float* __restrict__ bc0,
        float* __restrict__ h0, float* __restrict__ c0) {
    int b = blockIdx.x >> 1, m = blockIdx.x & 1;
    __shared__ float gs[2048];
    for (int d = threadIdx.x; d < 2048; d += 256) gs[d] = g[b * 2048 + d];
    __syncthreads();
    const float* W = m ? Wc0 : Wh0;
    const float* bb = m ? bc0 : bh0;
    float* out = m ? c0 : h0;
    for (int r = threadIdx.x; r < 512; r += 256) {
        float acc = 0.f;
        const float* wr = W + (size_t)r * 2048;
        for (int d = 0; d < 2048; d += 4) {
            float4 w = *(const float4*)(wr + d);
            acc += w.x * gs[d] + w.y * gs[d + 1] + w.z * gs[d + 2] + w.w * gs[d + 3];
        }
        out[b * 512 + r] = ftanh(acc + bb[r]) * 0.5f;
    }
}

// ---------------- persistent recurrence (exact R8 structure) ----------------
// 128 gates blocks (jc x bg): LDS-pinned weights, MFMA gates GEMM.
// 32 attn blocks: per-batch attention + LN.
// Sync via per-producer epoch flags (64B-padded slots), no global barrier.

__device__ __forceinline__ void waitflags(unsigned* FLG, int base, int stride,
                                          int n, unsigned tgt) {
    if (threadIdx.x < 64) {
        bool done;
        do {
            unsigned v = tgt;
            if ((int)threadIdx.x < n)
                v = __hip_atomic_load(FLG + (base + (int)threadIdx.x * stride) * 16,
                                      __ATOMIC_RELAXED, __HIP_MEMORY_SCOPE_AGENT);
            done = __all((int)(v >= tgt));
            if (!done) __builtin_amdgcn_s_sleep(1);
        } while (!done);
    }
    __syncthreads();
}

union SMem {
    struct {                       // gates role (blocks 0..127)
        ushort wh[64][520];        // W_hh rows (64 = 4 gates x 16 j), bf16
        ushort wi[64][520];        // W_ih rows
        ushort hsb[16][520];       // h / xn staged bf16 (rows 8..15 zero)
        float gtmp[4][16][16];     // [gate][jl][m]
    } g;                           // 153856 B
    struct {                       // attention role (blocks 128..159)
        float hb[512];
        float ebs[512];
        float php[8][128];
        float ph[128];
        float scp[64][16];
        float wsm[64];
        float xps[2][512];
        float wred[8][2];
        float bc[2];
    } a;
};

__global__ __launch_bounds__(1024, 1) void k_persist(
        const int* __restrict__ toks, const float* __restrict__ embed,
        const float* __restrict__ lng, const float* __restrict__ lnb,
        const float* __restrict__ bih, const float* __restrict__ bhh,
        const float* __restrict__ wsc, const ushort* __restrict__ whidbf,
        const ushort* __restrict__ whhbf, const ushort* __restrict__ wihbf,
        const float* __restrict__ proj, const float* __restrict__ imgEM,
        const float* __restrict__ embM, float* __restrict__ H,
        const float* __restrict__ C0, float* __restrict__ XN,
        unsigned* __restrict__ FLG, ushort* __restrict__ h2bf) {
    __shared__ SMem sm;
    int blk = blockIdx.x, tid = threadIdx.x;

    if (blk < 128) {
        // ---------------- gates role ----------------
        int jc = blk >> 2, bg = blk & 3, b0 = bg * 8;
        int wid = tid >> 6, lane = tid & 63;
        int gate = wid & 3;
        for (int i = tid; i < 4096; i += 1024) {
            int rr = i >> 6, c8 = (i & 63) * 8;
            size_t R = (size_t)((rr >> 4) * 512 + jc * 16 + (rr & 15)) * 512 + c8;
            *(uint4*)&sm.g.wh[rr][c8] = *(const uint4*)&whhbf[R];
            *(uint4*)&sm.g.wi[rr][c8] = *(const uint4*)&wihbf[R];
        }
        for (int i = tid; i < 2080; i += 1024) ((ull*)sm.g.hsb)[i] = 0;
        float c_reg = 0.f, bs0 = 0.f, bs1 = 0.f, bs2 = 0.f, bs3 = 0.f;
        if (tid < 128) {
            int jl = tid >> 3, bb = tid & 7;
            int j = jc * 16 + jl;
            c_reg = C0[(b0 + bb) * 512 + j];
            bs0 = bih[j] + bhh[j];
            bs1 = bih[512 + j] + bhh[512 + j];
            bs2 = bih[1024 + j] + bhh[1024 + j];
            bs3 = bih[1536 + j] + bhh[1536 + j];
        }
        __syncthreads();

        for (int t = 0; t < NT; t++) {
            waitflags(FLG, bg, 4, 32, (unsigned)t);
            {   // stage h -> hsb bf16 (rows 0..7)
                const float* Hb = H + (t & 1) * 16384 + b0 * 512;
                if (tid < 512) {
                    int bb = tid >> 6, c8 = (tid & 63) * 8;
                    const ull* p = (const ull*)(Hb + bb * 512 + c8);
                    uint4 o = { pk2(agld(p)), pk2(agld(p + 1)),
                                pk2(agld(p + 2)), pk2(agld(p + 3)) };
                    *(uint4*)&sm.g.hsb[bb][c8] = o;
                }
            }
            __syncthreads();
            v4f acc = {};
            if (wid < 4) {
                #pragma unroll
                for (int ks = 0; ks < 16; ks++) {
                    int ko = ks * 32 + (lane >> 4) * 8;
                    v8s a = *(const v8s*)&sm.g.hsb[lane & 15][ko];
                    v8s b = *(const v8s*)&sm.g.wh[gate * 16 + (lane & 15)][ko];
                    acc = __builtin_amdgcn_mfma_f32_16x16x32_bf16(a, b, acc, 0, 0, 0);
                }
            }
            waitflags(FLG, 128 + b0, 1, 8, (unsigned)(t + 1));
            {   // stage xn -> hsb bf16
                const float* Xb = XN + b0 * 512;
                if (tid < 512) {
                    int bb = tid >> 6, c8 = (tid & 63) * 8;
                    const ull* p = (const ull*)(Xb + bb * 512 + c8);
                    uint4 o = { pk2(agld(p)), pk2(agld(p + 1)),
                                pk2(agld(p + 2)), pk2(agld(p + 3)) };
                    *(uint4*)&sm.g.hsb[bb][c8] = o;
                }
            }
            __syncthreads();
            if (wid < 4) {
                #pragma unroll
                for (int ks = 0; ks < 16; ks++) {
                    int ko = ks * 32 + (lane >> 4) * 8;
                    v8s a = *(const v8s*)&sm.g.hsb[lane & 15][ko];
                    v8s b = *(const v8s*)&sm.g.wi[gate * 16 + (lane & 15)][ko];
                    acc = __builtin_amdgcn_mfma_f32_16x16x32_bf16(a, b, acc, 0, 0, 0);
                }
                #pragma unroll
                for (int q = 0; q < 4; q++)
                    sm.g.gtmp[gate][lane & 15][(lane >> 4) * 4 + q] = acc[q];
            }
            __syncthreads();
            if (tid < 128) {
                int jl = tid >> 3, bb = tid & 7;
                float vi = sm.g.gtmp[0][jl][bb] + bs0;
                float vf = sm.g.gtmp[1][jl][bb] + bs1;
                float vg = sm.g.gtmp[2][jl][bb] + bs2;
                float vo = sm.g.gtmp[3][jl][bb] + bs3;
                float c2 = fsig(vf) * c_reg + fsig(vi) * ftanh(vg);
                float h2 = fsig(vo) * ftanh(c2);
                c_reg = c2;
                int bglob = b0 + bb, j = jc * 16 + jl;
                __hip_atomic_store((unsigned*)&H[((t + 1) & 1) * 16384 + bglob * 512 + j],
                                   __float_as_uint(h2), __ATOMIC_RELAXED, __HIP_MEMORY_SCOPE_AGENT);
                h2bf[(size_t)(t * 32 + bglob) * 512 + j] = f2bf(h2);
            }
            __syncthreads();
            if (tid == 0)
                __hip_atomic_store(FLG + blk * 16, (unsigned)(t + 1),
                                   __ATOMIC_RELAXED, __HIP_MEMORY_SCOPE_AGENT);
        }
    } else {
        // ---------------- attention role ----------------
        int b = blk - 128, bgb = b >> 3;
        for (int t = 0; t < NT; t++) {
            waitflags(FLG, bgb, 4, 32, (unsigned)t);
            int tok = toks[b * 64 + t];
            if (tid < 256) {
                ull v = agld((const ull*)(H + (t & 1) * 16384) + b * 256 + tid);
                *(ull*)&sm.a.hb[tid * 2] = v;
            } else if (tid < 768) {
                int k = tid - 256;
                sm.a.ebs[k] = (tok == 0) ? 0.f : embed[(size_t)tok * 512 + k];
            }
            __syncthreads();
            {   // ph partials (whid from L2, bf16)
                int a = tid & 127, kq = tid >> 7;
                const ushort* wr2 = whidbf + (size_t)a * 512 + kq * 64;
                const float* hp = sm.a.hb + kq * 64;
                float p = 0.f;
                #pragma unroll
                for (int k = 0; k < 64; k += 8) {
                    uint4 q = *(const uint4*)(wr2 + k);
                    float4 ha = *(const float4*)(hp + k);
                    float4 hb4 = *(const float4*)(hp + k + 4);
                    p += bf_lo(q.x)*ha.x + bf_hi(q.x)*ha.y + bf_lo(q.y)*ha.z + bf_hi(q.y)*ha.w
                       + bf_lo(q.z)*hb4.x + bf_hi(q.z)*hb4.y + bf_lo(q.w)*hb4.z + bf_hi(q.w)*hb4.w;
                }
                sm.a.php[kq][a] = p;
            }
            __syncthreads();
            if (tid < 128) {
                float p = 0.f;
                #pragma unroll
                for (int kq = 0; kq < 8; kq++) p += sm.a.php[kq][tid];
                sm.a.ph[tid] = p;
            }
            __syncthreads();
            {   // score partials
                int s = tid >> 4, aq = tid & 15;
                float p = 0.f;
                if (s < 49) {
                    const float* pr = proj + (size_t)(b * 49 + s) * 128 + aq * 8;
                    #pragma unroll
                    for (int a = 0; a < 8; a++)
                        p += ftanh(pr[a] + sm.a.ph[aq * 8 + a]) * wsc[aq * 8 + a];
                }
                sm.a.scp[s][aq] = p;
            }
            __syncthreads();
            if (tid < 64) {
                float v = 0.f;
                #pragma unroll
                for (int q = 0; q < 16; q++) v += sm.a.scp[tid][q];
                if (tid >= 49) v = -1e30f;
                float m = v;
                for (int o = 32; o > 0; o >>= 1) m = fmaxf(m, __shfl_xor(m, o));
                float e = (tid < 49) ? __expf(v - m) : 0.f;
                float su = e;
                for (int o = 32; o > 0; o >>= 1) su += __shfl_xor(su, o);
                sm.a.wsm[tid] = e / su;
            }
            __syncthreads();
            {   // x = embM + sum_s w_s imgEM   (split s over 2 halves)
                int e = tid & 511, sh = tid >> 9;
                float xp = 0.f;
                if (sh == 0) xp = embM[(size_t)(t * 32 + b) * 512 + e];
                int s0 = sh * 25, s1 = sh ? 49 : 25;
                for (int s = s0; s < s1; s++)
                    xp += sm.a.wsm[s] * imgEM[(size_t)(b * 49 + s) * 512 + e];
                sm.a.xps[sh][e] = xp;
            }
            __syncthreads();
            if (tid < 512) {
                float x = fmaxf(sm.a.xps[0][tid] + sm.a.xps[1][tid], 0.f);
                float s = x, s2 = x * x;
                for (int o = 32; o > 0; o >>= 1) { s += __shfl_xor(s, o); s2 += __shfl_xor(s2, o); }
                if ((tid & 63) == 0) { sm.a.wred[tid >> 6][0] = s; sm.a.wred[tid >> 6][1] = s2; }
            }
            __syncthreads();
            if (tid == 0) {
                float s = 0.f, s2 = 0.f;
                #pragma unroll
                for (int w = 0; w < 8; w++) { s += sm.a.wred[w][0]; s2 += sm.a.wred[w][1]; }
                float mu = s * (1.f / 512.f);
                float var = s2 * (1.f / 512.f) - mu * mu;
                sm.a.bc[0] = mu; sm.a.bc[1] = rsqrtf(var + 1e-5f);
            }
            __syncthreads();
            if (tid < 512) {
                float x = fmaxf(sm.a.xps[0][tid] + sm.a.xps[1][tid], 0.f);
                float xn = (x - sm.a.bc[0]) * sm.a.bc[1] * lng[tid] + lnb[tid] + sm.a.ebs[tid];
                __hip_atomic_store((unsigned*)&XN[b * 512 + tid], __float_as_uint(xn),
                                   __ATOMIC_RELAXED, __HIP_MEMORY_SCOPE_AGENT);
            }
            __syncthreads();
            if (tid == 0)
                __hip_atomic_store(FLG + (128 + b) * 16, (unsigned)(t + 1),
                                   __ATOMIC_RELAXED, __HIP_MEMORY_SCOPE_AGENT);
        }
    }
}

// ---------------- deferred head GEMM: 256(m)x128(n) tile, 512 thr ----------------
__global__ __launch_bounds__(512) void k_head(const ushort* __restrict__ h2bf,
        const ushort* __restrict__ Wbf, float* __restrict__ out) {
    __shared__ ushort Al[256][72];
    __shared__ ushort Bl[128][72];
    int m0 = blockIdx.x * 256;   // (t,b) tile
    int n0 = blockIdx.y * 128;   // vocab tile
    int tid = threadIdx.x, lane = tid & 63, wid = tid >> 6;
    int wm = wid >> 1, wn = wid & 1;
    v4f acc[4][4] = {};
    for (int kt = 0; kt < 512; kt += 64) {
        __syncthreads();
        #pragma unroll
        for (int i = 0; i < 4; i++) {
            int idx = i * 512 + tid;
            int row = idx >> 3, c8 = (idx & 7) * 8;
            *(uint4*)&Al[row][c8] = *(const uint4*)&h2bf[(size_t)(m0 + row) * 512 + kt + c8];
        }
        #pragma unroll
        for (int i = 0; i < 2; i++) {
            int idx = i * 512 + tid;
            int row = idx >> 3, c8 = (idx & 7) * 8;
            *(uint4*)&Bl[row][c8] = *(const uint4*)&Wbf[(size_t)(n0 + row) * 512 + kt + c8];
        }
        __syncthreads();
        #pragma unroll
        for (int kk = 0; kk < 2; kk++) {
            v8s a[4], bfr[4];
            int ko = kk * 32 + (lane >> 4) * 8;
            #pragma unroll
            for (int mi = 0; mi < 4; mi++)
                a[mi] = *(const v8s*)&Al[wm * 64 + mi * 16 + (lane & 15)][ko];
            #pragma unroll
            for (int ni = 0; ni < 4; ni++)
                bfr[ni] = *(const v8s*)&Bl[wn * 64 + ni * 16 + (lane & 15)][ko];
            #pragma unroll
            for (int mi = 0; mi < 4; mi++)
                #pragma unroll
                for (int ni = 0; ni < 4; ni++)
                    acc[mi][ni] = __builtin_amdgcn_mfma_f32_16x16x32_bf16(a[mi], bfr[ni], acc[mi][ni], 0, 0, 0);
        }
    }
    int col = lane & 15, rbase = (lane >> 4) * 4;
    #pragma unroll
    for (int mi = 0; mi < 4; mi++)
        #pragma unroll
        for (int ni = 0; ni < 4; ni++)
            #pragma unroll
            for (int r = 0; r < 4; r++) {
                int m = m0 + wm * 64 + mi * 16 + rbase + r;
                int v = n0 + wn * 64 + ni * 16 + col;
                int b = m & 31, t = m >> 5;
                out[((size_t)(b * 64 + t)) * 32000 + v] = acc[mi][ni][r];
            }
}

// ---------------- launch ----------------
extern "C" void kernel_launch(void* const* d_in, const int* in_sizes, int n_in,
                              void* d_out, int out_size, void* d_ws, size_t ws_size,
                              hipStream_t stream) {
    const float* img    = (const float*)d_in[0];
    const int*   toks   = (const int*)d_in[1];
    const float* embed  = (const float*)d_in[2];
    const float* W_ctx  = (const float*)d_in[3];
    const float* W_mix  = (const float*)d_in[4];
    const float* ln_g   = (const float*)d_in[5];
    const float* ln_b   = (const float*)d_in[6];
    const float* W_ih   = (const float*)d_in[7];
    const float* W_hh   = (const float*)d_in[8];
    const float* b_ih   = (const float*)d_in[9];
    const float* b_hh   = (const float*)d_in[10];
    const float* W_head = (const float*)d_in[11];
    const float* W_img  = (const float*)d_in[12];
    const float* W_hid  = (const float*)d_in[13];
    const float* w_sc   = (const float*)d_in[14];
    const float* W_h0   = (const float*)d_in[15];
    const float* b_h0   = (const float*)d_in[16];
    const float* W_c0   = (const float*)d_in[17];
    const float* b_c0   = (const float*)d_in[18];

    float* out = (float*)d_out;
    float* ws  = (float*)d_ws;
    ushort* Wbf    = (ushort*)(ws + WS_WBF);
    ushort* h2bf   = (ushort*)(ws + WS_H2BF);
    float*  imgEM  = ws + WS_IMGEM;
    float*  proj   = ws + WS_PROJ;
    float*  embM   = ws + WS_EMBM;
    ushort* whhbf  = (ushort*)(ws + WS_WHHBF);
    ushort* wihbf  = (ushort*)(ws + WS_WIHBF);
    ushort* whidbf = (ushort*)(ws + WS_WHIDBF);
    float*  H      = ws + WS_H;
    float*  XN     = ws + WS_XN;
    float*  C      = ws + WS_C;
    unsigned* flg  = (unsigned*)(ws + WS_FLAGS);
    float*  g      = ws + WS_G;
    // prep scratch (inside Wbf slot; dead before W_head cast)
    ushort* imgbf   = (ushort*)(ws + PS_IMGBF);
    ushort* wctxbf  = (ushort*)(ws + PS_WCTXBF);
    ushort* wimgbf  = (ushort*)(ws + PS_WIMGBF);
    ushort* wmixRbf = (ushort*)(ws + PS_WMIXRBF);
    ushort* wmixLbf = (ushort*)(ws + PS_WMIXLBF);
    ushort* imgEbf  = (ushort*)(ws + PS_IMGEBF);

    // prep 1: all casts (img + 7 weights) + flag zeroing, one launch
    k_castall<<<3617, 256, 0, stream>>>(img, W_ctx, W_img, W_mix, W_hh, W_ih, W_hid,
                                        imgbf, wctxbf, wimgbf, wmixRbf, wmixLbf,
                                        whhbf, wihbf, whidbf, flg);
    // prep 2: fused triple GEMM (imgEbf bf16-direct, proj, embM with embed gather)
    k_gemm3<<<129, 256, 0, stream>>>(imgbf, wctxbf, wimgbf, embed, toks, wmixLbf,
                                     imgEbf, proj, embM);
    // prep 3: imgEM = imgEbf @ wmixR^T
    k_gemm<<<dim3(4, 13), 256, 0, stream>>>(imgEbf, wmixRbf, imgEM, 512, 512);
    // prep 4: head weights (overwrites scratch region — after all scratch reads)
    k_castpad<<<8000, 256, 0, stream>>>(W_head, Wbf, 32000, 32000, 512, 512, 0);
    // prep 5: init state
    k_gmean<<<32, 256, 0, stream>>>(img, g);
    k_h0c0<<<64, 256, 0, stream>>>(g, W_h0, b_h0, W_c0, b_c0, H, C);

    // recurrence: flag-synced, MFMA gates, LDS-pinned weights (R8-proven)
    k_persist<<<NBLK, 1024, 0, stream>>>(toks, embed, ln_g, ln_b, b_ih, b_hh, w_sc,
                                         whidbf, whhbf, wihbf, proj, imgEM, embM,
                                         H, C, XN, flg, h2bf);

    // deferred batched head GEMM: 256x128 tiles, grid (m=8, n=250)
    k_head<<<dim3(8, 250), 512, 0, stream>>>(h2bf, Wbf, out);
}

// Round 13
// 1044.140 us; speedup vs baseline: 1.3361x; 1.0981x over previous
//
#include <hip/hip_runtime.h>

#define NV 32000
#define NT 64
#define NBLK 160u

typedef unsigned long long ull;
typedef unsigned short ushort;
typedef __attribute__((ext_vector_type(8))) short v8s;
typedef __attribute__((ext_vector_type(4))) float v4f;

// persistent ws layout (float offsets; ushort regions = count/2 floats)
#define WS_WBF     0          // ushort [32000][512]           -> 8192000
#define WS_H2BF    8192000    // ushort [2048][512]  (524288)  -> 8716288
#define WS_IMGEM   8716288    // f32 [1664][512]     (851968)  -> 9568256
#define WS_PROJ    9568256    // f32 [1664][128]     (212992)  -> 9781248
#define WS_EMBM    9781248    // f32 [2048][512]     (1048576) -> 10829824
#define WS_WHHBF   10829824   // ushort [2048][512]  (524288)  -> 11354112
#define WS_WIHBF   11354112   // ushort [2048][512]  (524288)  -> 11878400
#define WS_WHIDBF  11878400   // ushort [128][512]   (32768)   -> 11911168
#define WS_H       11911168   // f32 [2][32][512]    (32768)   -> 11943936
#define WS_XN      11943936   // f32 [32][512]       (16384)   -> 11960320
#define WS_C       11960320   // f32 [32][512]       (16384)   -> 11976704
#define WS_FLAGS   11976704   // 160 slots x 16 u32  (2560)    -> 11979264
#define WS_G       11979264   // f32 [32][2048]      (65536)   -> 12044800
// prep scratch (inside Wbf slot [0,8192000); dead before W_head cast)
#define PS_IMGBF   0          // ushort [1664][2048] (1703936) -> 1703936
#define PS_WCTXBF  1703936    // ushort [512][2048]  (524288)  -> 2228224
#define PS_WIMGBF  2228224    // ushort [128][2048]  (131072)  -> 2359296
#define PS_WMIXRBF 2359296    // ushort [512][512]   (131072)  -> 2490368
#define PS_WMIXLBF 2490368    // ushort [512][512]   (131072)  -> 2621440
#define PS_IMGEBF  3342336    // ushort [1664][512]  (425984)  -> 3768320

__device__ __forceinline__ float fsig(float x) {
    x = fminf(fmaxf(x, -30.f), 30.f);
    return 1.f / (1.f + __expf(-x));
}
__device__ __forceinline__ float ftanh(float x) {
    x = fminf(fmaxf(x, -15.f), 15.f);
    float e = __expf(2.f * x);
    return (e - 1.f) / (e + 1.f);
}
__device__ __forceinline__ unsigned short f2bf(float f) {
    union { float f; unsigned int u; } v; v.f = f;
    unsigned int u = v.u;
    return (unsigned short)((u + 0x7FFFu + ((u >> 16) & 1u)) >> 16);
}
__device__ __forceinline__ unsigned pkf(float x, float y) {
    return (unsigned)f2bf(x) | ((unsigned)f2bf(y) << 16);
}
__device__ __forceinline__ float bf_lo(unsigned u) { return __uint_as_float(u << 16); }
__device__ __forceinline__ float bf_hi(unsigned u) { return __uint_as_float(u & 0xffff0000u); }
__device__ __forceinline__ ull agld(const ull* p) {
    return __hip_atomic_load(p, __ATOMIC_RELAXED, __HIP_MEMORY_SCOPE_AGENT);
}
__device__ __forceinline__ unsigned pk2(ull v) {
    return (unsigned)f2bf(__uint_as_float((unsigned)v)) |
           ((unsigned)f2bf(__uint_as_float((unsigned)(v >> 32))) << 16);
}

// ---------------- prep kernels ----------------

// plain fp32->bf16 cast (W_head only)
__global__ __launch_bounds__(256) void k_castpad(const float* __restrict__ in,
        ushort* __restrict__ out, int R, int Rpad, int K, int ldi, int off) {
    size_t i = ((size_t)blockIdx.x * 256 + threadIdx.x) * 8;
    if (i >= (size_t)Rpad * K) return;
    int r = (int)(i / K), k = (int)(i % K);
    uint4 o = {0, 0, 0, 0};
    if (r < R) {
        const float* p = in + (size_t)r * ldi + off + k;
        float4 a = *(const float4*)(p);
        float4 b = *(const float4*)(p + 4);
        o.x = pkf(a.x, a.y); o.y = pkf(a.z, a.w);
        o.z = pkf(b.x, b.y); o.w = pkf(b.z, b.w);
    }
    *(uint4*)(out + i) = o;
}

// single launch: all 8 bf16 weight/input casts + flag zeroing
__global__ __launch_bounds__(256) void k_castall(
        const float* __restrict__ img, const float* __restrict__ Wctx,
        const float* __restrict__ Wimg, const float* __restrict__ Wmix,
        const float* __restrict__ Whh, const float* __restrict__ Wih,
        const float* __restrict__ Whid,
        ushort* __restrict__ imgbf, ushort* __restrict__ wctxbf,
        ushort* __restrict__ wimgbf, ushort* __restrict__ wmixRbf,
        ushort* __restrict__ wmixLbf, ushort* __restrict__ whhbf,
        ushort* __restrict__ wihbf, ushort* __restrict__ whidbf,
        unsigned* __restrict__ flg) {
    int blk = blockIdx.x, tid = threadIdx.x;
    if (blk >= 3616) {                       // zero the 160 flag slots
        for (int i = tid; i < 2560; i += 256) flg[i] = 0u;
        return;
    }
    const float* in; ushort* out; int R, K, ldi, off;
    if (blk < 1664)      { in = img;  out = imgbf;   R = 1568; K = 2048; ldi = 2048; off = 0; }
    else if (blk < 2176) { in = Wctx; out = wctxbf;  R = 512;  K = 2048; ldi = 2048; off = 0;   blk -= 1664; }
    else if (blk < 2304) { in = Wimg; out = wimgbf;  R = 128;  K = 2048; ldi = 2048; off = 0;   blk -= 2176; }
    else if (blk < 2432) { in = Wmix; out = wmixRbf; R = 512;  K = 512;  ldi = 1024; off = 512; blk -= 2304; }
    else if (blk < 2560) { in = Wmix; out = wmixLbf; R = 512;  K = 512;  ldi = 1024; off = 0;   blk -= 2432; }
    else if (blk < 3072) { in = Whh;  out = whhbf;   R = 2048; K = 512;  ldi = 512;  off = 0;   blk -= 2560; }
    else if (blk < 3584) { in = Wih;  out = wihbf;   R = 2048; K = 512;  ldi = 512;  off = 0;   blk -= 3072; }
    else                 { in = Whid; out = whidbf;  R = 128;  K = 512;  ldi = 512;  off = 0;   blk -= 3584; }
    size_t i = ((size_t)blk * 256 + tid) * 8;
    int r = (int)(i / K), k = (int)(i % K);
    uint4 o = {0, 0, 0, 0};
    if (r < R) {
        const float* p = in + (size_t)r * ldi + off + k;
        float4 a = *(const float4*)(p);
        float4 b = *(const float4*)(p + 4);
        o.x = pkf(a.x, a.y); o.y = pkf(a.z, a.w);
        o.z = pkf(b.x, b.y); o.w = pkf(b.z, b.w);
    }
    *(uint4*)(out + i) = o;
}

// generic bf16 GEMM, fp32 out: C[m][n] = sum_k A[m][k]*B[n][k]
__global__ __launch_bounds__(256) void k_gemm(const ushort* __restrict__ A,
        const ushort* __restrict__ B, float* __restrict__ C, int N, int K) {
    __shared__ ushort Al[128][72];
    __shared__ ushort Bl[128][72];
    int n0 = blockIdx.x * 128, m0 = blockIdx.y * 128;
    int tid = threadIdx.x, lane = tid & 63, wid = tid >> 6;
    int wm = wid >> 1, wn = wid & 1;
    v4f acc[4][4] = {};
    for (int kt = 0; kt < K; kt += 64) {
        __syncthreads();
        #pragma unroll
        for (int i = 0; i < 4; i++) {
            int idx = i * 256 + tid;
            int row = idx >> 3, c8 = (idx & 7) * 8;
            *(uint4*)&Al[row][c8] = *(const uint4*)&A[(size_t)(m0 + row) * K + kt + c8];
            *(uint4*)&Bl[row][c8] = *(const uint4*)&B[(size_t)(n0 + row) * K + kt + c8];
        }
        __syncthreads();
        #pragma unroll
        for (int kk = 0; kk < 2; kk++) {
            v8s a[4], bfr[4];
            int ko = kk * 32 + (lane >> 4) * 8;
            #pragma unroll
            for (int mi = 0; mi < 4; mi++)
                a[mi] = *(const v8s*)&Al[wm * 64 + mi * 16 + (lane & 15)][ko];
            #pragma unroll
            for (int ni = 0; ni < 4; ni++)
                bfr[ni] = *(const v8s*)&Bl[wn * 64 + ni * 16 + (lane & 15)][ko];
            #pragma unroll
            for (int mi = 0; mi < 4; mi++)
                #pragma unroll
                for (int ni = 0; ni < 4; ni++)
                    acc[mi][ni] = __builtin_amdgcn_mfma_f32_16x16x32_bf16(a[mi], bfr[ni], acc[mi][ni], 0, 0, 0);
        }
    }
    int col = lane & 15, rbase = (lane >> 4) * 4;
    #pragma unroll
    for (int mi = 0; mi < 4; mi++)
        #pragma unroll
        for (int ni = 0; ni < 4; ni++)
            #pragma unroll
            for (int r = 0; r < 4; r++) {
                int m = m0 + wm * 64 + mi * 16 + rbase + r;
                int v = n0 + wn * 64 + ni * 16 + col;
                C[(size_t)m * N + v] = acc[mi][ni][r];
            }
}

// fused triple GEMM in one launch:
//  blocks [0,52):   imgEbf = bf16(imgbf @ wctxbf^T)        K=2048, bf16 out
//  blocks [52,65):  proj   = imgbf @ wimgbf^T              K=2048, fp32 out
//  blocks [65,129): embM   = gather(embed,toks) @ wmixL^T  K=512,  fp32 out
__global__ __launch_bounds__(256) void k_gemm3(
        const ushort* __restrict__ imgbf, const ushort* __restrict__ wctxbf,
        const ushort* __restrict__ wimgbf, const float* __restrict__ embed,
        const int* __restrict__ toks, const ushort* __restrict__ wmixLbf,
        ushort* __restrict__ imgEbf, float* __restrict__ proj,
        float* __restrict__ embM) {
    __shared__ ushort Al[128][72];
    __shared__ ushort Bl[128][72];
    int bid = blockIdx.x;
    const ushort* A; const ushort* B; int mode, K, N, n0, m0;
    if (bid < 52)      { mode = 0; A = imgbf; B = wctxbf;  K = 2048; N = 512; n0 = (bid & 3) * 128; m0 = (bid >> 2) * 128; }
    else if (bid < 65) { mode = 1; A = imgbf; B = wimgbf;  K = 2048; N = 128; n0 = 0;               m0 = (bid - 52) * 128; }
    else { int e = bid - 65; mode = 2; A = nullptr; B = wmixLbf; K = 512; N = 512; n0 = (e & 3) * 128; m0 = (e >> 2) * 128; }
    int tid = threadIdx.x, lane = tid & 63, wid = tid >> 6;
    int wm = wid >> 1, wn = wid & 1;
    v4f acc[4][4] = {};
    for (int kt = 0; kt < K; kt += 64) {
        __syncthreads();
        #pragma unroll
        for (int i = 0; i < 4; i++) {
            int idx = i * 256 + tid;
            int row = idx >> 3, c8 = (idx & 7) * 8;
            if (mode == 2) {
                int rowg = m0 + row;
                int tok = toks[(rowg & 31) * 64 + (rowg >> 5)];
                uint4 oa = {0, 0, 0, 0};
                if (tok != 0) {
                    const float* pa = embed + (size_t)tok * 512 + kt + c8;
                    float4 a0 = *(const float4*)pa, a1 = *(const float4*)(pa + 4);
                    oa.x = pkf(a0.x, a0.y); oa.y = pkf(a0.z, a0.w);
                    oa.z = pkf(a1.x, a1.y); oa.w = pkf(a1.z, a1.w);
                }
                *(uint4*)&Al[row][c8] = oa;
            } else {
                *(uint4*)&Al[row][c8] = *(const uint4*)&A[(size_t)(m0 + row) * K + kt + c8];
            }
            *(uint4*)&Bl[row][c8] = *(const uint4*)&B[(size_t)(n0 + row) * K + kt + c8];
        }
        __syncthreads();
        #pragma unroll
        for (int kk = 0; kk < 2; kk++) {
            v8s a[4], bfr[4];
            int ko = kk * 32 + (lane >> 4) * 8;
            #pragma unroll
            for (int mi = 0; mi < 4; mi++)
                a[mi] = *(const v8s*)&Al[wm * 64 + mi * 16 + (lane & 15)][ko];
            #pragma unroll
            for (int ni = 0; ni < 4; ni++)
                bfr[ni] = *(const v8s*)&Bl[wn * 64 + ni * 16 + (lane & 15)][ko];
            #pragma unroll
            for (int mi = 0; mi < 4; mi++)
                #pragma unroll
                for (int ni = 0; ni < 4; ni++)
                    acc[mi][ni] = __builtin_amdgcn_mfma_f32_16x16x32_bf16(a[mi], bfr[ni], acc[mi][ni], 0, 0, 0);
        }
    }
    int col = lane & 15, rbase = (lane >> 4) * 4;
    #pragma unroll
    for (int mi = 0; mi < 4; mi++)
        #pragma unroll
        for (int ni = 0; ni < 4; ni++)
            #pragma unroll
            for (int r = 0; r < 4; r++) {
                int m = m0 + wm * 64 + mi * 16 + rbase + r;
                int v = n0 + wn * 64 + ni * 16 + col;
                if (mode == 0)      imgEbf[(size_t)m * 512 + v] = f2bf(acc[mi][ni][r]);
                else if (mode == 1) proj[(size_t)m * 128 + v] = acc[mi][ni][r];
                else                embM[(size_t)m * 512 + v] = acc[mi][ni][r];
            }
}

__global__ __launch_bounds__(256) void k_gmean(const float* __restrict__ img,
                                               float* __restrict__ g) {
    int b = blockIdx.x;
    for (int d = threadIdx.x; d < 2048; d += 256) {
        float s = 0.f;
        for (int ss = 0; ss < 49; ss++) s += img[((size_t)(b * 49 + ss)) * 2048 + d];
        g[b * 2048 + d] = s * (1.f / 49.f);
    }
}

__global__ __launch_bounds__(256) void k_h0c0(const float* __restrict__ g,
        const float* __restrict__ Wh0, const float* __restrict__ bh0,
        const float* __restrict__ Wc0, const float* __restrict__ bc0,
        float* __restrict__ h0, float* __restrict__ c0) {
    int b = blockIdx.x >> 1, m = blockIdx.x & 1;
    __shared__ float gs[2048];
    for (int d = threadIdx.x; d < 2048; d += 256) gs[d] = g[b * 2048 + d];
    __syncthreads();
    const float* W = m ? Wc0 : Wh0;
    const float* bb = m ? bc0 : bh0;
    float* out = m ? c0 : h0;
    for (int r = threadIdx.x; r < 512; r += 256) {
        float acc = 0.f;
        const float* wr = W + (size_t)r * 2048;
        for (int d = 0; d < 2048; d += 4) {
            float4 w = *(const float4*)(wr + d);
            acc += w.x * gs[d] + w.y * gs[d + 1] + w.z * gs[d + 2] + w.w * gs[d + 3];
        }
        out[b * 512 + r] = ftanh(acc + bb[r]) * 0.5f;
    }
}

// ---------------- persistent recurrence ----------------
// Gates role: exact R8 structure (twice-validated).
// Attn role: R8 structure, ONLY change = imgEM[b]/proj[b] pinned in LDS
// (single-variable experiment isolating R9's LDS-pinning from its other edits).

__device__ __forceinline__ void waitflags(unsigned* FLG, int base, int stride,
                                          int n, unsigned tgt) {
    if (threadIdx.x < 64) {
        bool done;
        do {
            unsigned v = tgt;
            if ((int)threadIdx.x < n)
                v = __hip_atomic_load(FLG + (base + (int)threadIdx.x * stride) * 16,
                                      __ATOMIC_RELAXED, __HIP_MEMORY_SCOPE_AGENT);
            done = __all((int)(v >= tgt));
            if (!done) __builtin_amdgcn_s_sleep(1);
        } while (!done);
    }
    __syncthreads();
}

union SMem {
    struct {                       // gates role (blocks 0..127)
        ushort wh[64][520];        // W_hh rows (64 = 4 gates x 16 j), bf16
        ushort wi[64][520];        // W_ih rows
        ushort hsb[16][520];       // h / xn staged bf16 (rows 8..15 zero)
        float gtmp[4][16][16];     // [gate][jl][m]
    } g;                           // 153856 B
    struct {                       // attention role (blocks 128..159)
        float imgem[49][512];      // pinned imgEM[b]  100352 B
        float projl[49][128];      // pinned proj[b]    25088 B
        float hb[512];
        float ebs[512];
        float php[8][128];
        float ph[128];
        float scp[64][16];
        float wsm[64];
        float xps[2][512];
        float wred[8][2];
        float bc[2];
    } a;                           // ~142.5 KB (< gates 153.9 KB)
};

__global__ __launch_bounds__(1024, 1) void k_persist(
        const int* __restrict__ toks, const float* __restrict__ embed,
        const float* __restrict__ lng, const float* __restrict__ lnb,
        const float* __restrict__ bih, const float* __restrict__ bhh,
        const float* __restrict__ wsc, const ushort* __restrict__ whidbf,
        const ushort* __restrict__ whhbf, const ushort* __restrict__ wihbf,
        const float* __restrict__ proj, const float* __restrict__ imgEM,
        const float* __restrict__ embM, float* __restrict__ H,
        const float* __restrict__ C0, float* __restrict__ XN,
        unsigned* __restrict__ FLG, ushort* __restrict__ h2bf) {
    __shared__ SMem sm;
    int blk = blockIdx.x, tid = threadIdx.x;

    if (blk < 128) {
        // ---------------- gates role (byte-identical to R8/R12) ----------------
        int jc = blk >> 2, bg = blk & 3, b0 = bg * 8;
        int wid = tid >> 6, lane = tid & 63;
        int gate = wid & 3;
        for (int i = tid; i < 4096; i += 1024) {
            int rr = i >> 6, c8 = (i & 63) * 8;
            size_t R = (size_t)((rr >> 4) * 512 + jc * 16 + (rr & 15)) * 512 + c8;
            *(uint4*)&sm.g.wh[rr][c8] = *(const uint4*)&whhbf[R];
            *(uint4*)&sm.g.wi[rr][c8] = *(const uint4*)&wihbf[R];
        }
        for (int i = tid; i < 2080; i += 1024) ((ull*)sm.g.hsb)[i] = 0;
        float c_reg = 0.f, bs0 = 0.f, bs1 = 0.f, bs2 = 0.f, bs3 = 0.f;
        if (tid < 128) {
            int jl = tid >> 3, bb = tid & 7;
            int j = jc * 16 + jl;
            c_reg = C0[(b0 + bb) * 512 + j];
            bs0 = bih[j] + bhh[j];
            bs1 = bih[512 + j] + bhh[512 + j];
            bs2 = bih[1024 + j] + bhh[1024 + j];
            bs3 = bih[1536 + j] + bhh[1536 + j];
        }
        __syncthreads();

        for (int t = 0; t < NT; t++) {
            waitflags(FLG, bg, 4, 32, (unsigned)t);
            {   // stage h -> hsb bf16 (rows 0..7)
                const float* Hb = H + (t & 1) * 16384 + b0 * 512;
                if (tid < 512) {
                    int bb = tid >> 6, c8 = (tid & 63) * 8;
                    const ull* p = (const ull*)(Hb + bb * 512 + c8);
                    uint4 o = { pk2(agld(p)), pk2(agld(p + 1)),
                                pk2(agld(p + 2)), pk2(agld(p + 3)) };
                    *(uint4*)&sm.g.hsb[bb][c8] = o;
                }
            }
            __syncthreads();
            v4f acc = {};
            if (wid < 4) {
                #pragma unroll
                for (int ks = 0; ks < 16; ks++) {
                    int ko = ks * 32 + (lane >> 4) * 8;
                    v8s a = *(const v8s*)&sm.g.hsb[lane & 15][ko];
                    v8s b = *(const v8s*)&sm.g.wh[gate * 16 + (lane & 15)][ko];
                    acc = __builtin_amdgcn_mfma_f32_16x16x32_bf16(a, b, acc, 0, 0, 0);
                }
            }
            waitflags(FLG, 128 + b0, 1, 8, (unsigned)(t + 1));
            {   // stage xn -> hsb bf16
                const float* Xb = XN + b0 * 512;
                if (tid < 512) {
                    int bb = tid >> 6, c8 = (tid & 63) * 8;
                    const ull* p = (const ull*)(Xb + bb * 512 + c8);
                    uint4 o = { pk2(agld(p)), pk2(agld(p + 1)),
                                pk2(agld(p + 2)), pk2(agld(p + 3)) };
                    *(uint4*)&sm.g.hsb[bb][c8] = o;
                }
            }
            __syncthreads();
            if (wid < 4) {
                #pragma unroll
                for (int ks = 0; ks < 16; ks++) {
                    int ko = ks * 32 + (lane >> 4) * 8;
                    v8s a = *(const v8s*)&sm.g.hsb[lane & 15][ko];
                    v8s b = *(const v8s*)&sm.g.wi[gate * 16 + (lane & 15)][ko];
                    acc = __builtin_amdgcn_mfma_f32_16x16x32_bf16(a, b, acc, 0, 0, 0);
                }
                #pragma unroll
                for (int q = 0; q < 4; q++)
                    sm.g.gtmp[gate][lane & 15][(lane >> 4) * 4 + q] = acc[q];
            }
            __syncthreads();
            if (tid < 128) {
                int jl = tid >> 3, bb = tid & 7;
                float vi = sm.g.gtmp[0][jl][bb] + bs0;
                float vf = sm.g.gtmp[1][jl][bb] + bs1;
                float vg = sm.g.gtmp[2][jl][bb] + bs2;
                float vo = sm.g.gtmp[3][jl][bb] + bs3;
                float c2 = fsig(vf) * c_reg + fsig(vi) * ftanh(vg);
                float h2 = fsig(vo) * ftanh(c2);
                c_reg = c2;
                int bglob = b0 + bb, j = jc * 16 + jl;
                __hip_atomic_store((unsigned*)&H[((t + 1) & 1) * 16384 + bglob * 512 + j],
                                   __float_as_uint(h2), __ATOMIC_RELAXED, __HIP_MEMORY_SCOPE_AGENT);
                h2bf[(size_t)(t * 32 + bglob) * 512 + j] = f2bf(h2);
            }
            __syncthreads();
            if (tid == 0)
                __hip_atomic_store(FLG + blk * 16, (unsigned)(t + 1),
                                   __ATOMIC_RELAXED, __HIP_MEMORY_SCOPE_AGENT);
        }
    } else {
        // ---------------- attention role ----------------
        int b = blk - 128, bgb = b >> 3;
        // ONLY change vs R8: pin imgEM[b] and proj[b] in LDS once
        for (int i = tid; i < 49 * 512; i += 1024)
            sm.a.imgem[i >> 9][i & 511] = imgEM[(size_t)b * 49 * 512 + i];
        for (int i = tid; i < 49 * 128; i += 1024)
            sm.a.projl[i >> 7][i & 127] = proj[(size_t)b * 49 * 128 + i];
        __syncthreads();
        for (int t = 0; t < NT; t++) {
            waitflags(FLG, bgb, 4, 32, (unsigned)t);
            int tok = toks[b * 64 + t];
            if (tid < 256) {
                ull v = agld((const ull*)(H + (t & 1) * 16384) + b * 256 + tid);
                *(ull*)&sm.a.hb[tid * 2] = v;
            } else if (tid < 768) {
                int k = tid - 256;
                sm.a.ebs[k] = (tok == 0) ? 0.f : embed[(size_t)tok * 512 + k];
            }
            __syncthreads();
            {   // ph partials (whid from L2, bf16)
                int a = tid & 127, kq = tid >> 7;
                const ushort* wr2 = whidbf + (size_t)a * 512 + kq * 64;
                const float* hp = sm.a.hb + kq * 64;
                float p = 0.f;
                #pragma unroll
                for (int k = 0; k < 64; k += 8) {
                    uint4 q = *(const uint4*)(wr2 + k);
                    float4 ha = *(const float4*)(hp + k);
                    float4 hb4 = *(const float4*)(hp + k + 4);
                    p += bf_lo(q.x)*ha.x + bf_hi(q.x)*ha.y + bf_lo(q.y)*ha.z + bf_hi(q.y)*ha.w
                       + bf_lo(q.z)*hb4.x + bf_hi(q.z)*hb4.y + bf_lo(q.w)*hb4.z + bf_hi(q.w)*hb4.w;
                }
                sm.a.php[kq][a] = p;
            }
            __syncthreads();
            if (tid < 128) {
                float p = 0.f;
                #pragma unroll
                for (int kq = 0; kq < 8; kq++) p += sm.a.php[kq][tid];
                sm.a.ph[tid] = p;
            }
            __syncthreads();
            {   // score partials (proj from LDS)
                int s = tid >> 4, aq = tid & 15;
                float p = 0.f;
                if (s < 49) {
                    const float* pr = &sm.a.projl[s][aq * 8];
                    #pragma unroll
                    for (int a = 0; a < 8; a++)
                        p += ftanh(pr[a] + sm.a.ph[aq * 8 + a]) * wsc[aq * 8 + a];
                }
                sm.a.scp[s][aq] = p;
            }
            __syncthreads();
            if (tid < 64) {
                float v = 0.f;
                #pragma unroll
                for (int q = 0; q < 16; q++) v += sm.a.scp[tid][q];
                if (tid >= 49) v = -1e30f;
                float m = v;
                for (int o = 32; o > 0; o >>= 1) m = fmaxf(m, __shfl_xor(m, o));
                float e = (tid < 49) ? __expf(v - m) : 0.f;
                float su = e;
                for (int o = 32; o > 0; o >>= 1) su += __shfl_xor(su, o);
                sm.a.wsm[tid] = e / su;
            }
            __syncthreads();
            {   // x = embM + sum_s w_s imgEM (imgem from LDS; split s over 2 halves)
                int e = tid & 511, sh = tid >> 9;
                float xp = 0.f;
                if (sh == 0) xp = embM[(size_t)(t * 32 + b) * 512 + e];
                int s0 = sh * 25, s1 = sh ? 49 : 25;
                for (int s = s0; s < s1; s++)
                    xp += sm.a.wsm[s] * sm.a.imgem[s][e];
                sm.a.xps[sh][e] = xp;
            }
            __syncthreads();
            if (tid < 512) {
                float x = fmaxf(sm.a.xps[0][tid] + sm.a.xps[1][tid], 0.f);
                float s = x, s2 = x * x;
                for (int o = 32; o > 0; o >>= 1) { s += __shfl_xor(s, o); s2 += __shfl_xor(s2, o); }
                if ((tid & 63) == 0) { sm.a.wred[tid >> 6][0] = s; sm.a.wred[tid >> 6][1] = s2; }
            }
            __syncthreads();
            if (tid == 0) {
                float s = 0.f, s2 = 0.f;
                #pragma unroll
                for (int w = 0; w < 8; w++) { s += sm.a.wred[w][0]; s2 += sm.a.wred[w][1]; }
                float mu = s * (1.f / 512.f);
                float var = s2 * (1.f / 512.f) - mu * mu;
                sm.a.bc[0] = mu; sm.a.bc[1] = rsqrtf(var + 1e-5f);
            }
            __syncthreads();
            if (tid < 512) {
                float x = fmaxf(sm.a.xps[0][tid] + sm.a.xps[1][tid], 0.f);
                float xn = (x - sm.a.bc[0]) * sm.a.bc[1] * lng[tid] + lnb[tid] + sm.a.ebs[tid];
                __hip_atomic_store((unsigned*)&XN[b * 512 + tid], __float_as_uint(xn),
                                   __ATOMIC_RELAXED, __HIP_MEMORY_SCOPE_AGENT);
            }
            __syncthreads();
            if (tid == 0)
                __hip_atomic_store(FLG + (128 + b) * 16, (unsigned)(t + 1),
                                   __ATOMIC_RELAXED, __HIP_MEMORY_SCOPE_AGENT);
        }
    }
}

// ---------------- deferred head GEMM: 256(m)x128(n) tile, 512 thr ----------------
__global__ __launch_bounds__(512) void k_head(const ushort* __restrict__ h2bf,
        const ushort* __restrict__ Wbf, float* __restrict__ out) {
    __shared__ ushort Al[256][72];
    __shared__ ushort Bl[128][72];
    int m0 = blockIdx.x * 256;   // (t,b) tile
    int n0 = blockIdx.y * 128;   // vocab tile
    int tid = threadIdx.x, lane = tid & 63, wid = tid >> 6;
    int wm = wid >> 1, wn = wid & 1;
    v4f acc[4][4] = {};
    for (int kt = 0; kt < 512; kt += 64) {
        __syncthreads();
        #pragma unroll
        for (int i = 0; i < 4; i++) {
            int idx = i * 512 + tid;
            int row = idx >> 3, c8 = (idx & 7) * 8;
            *(uint4*)&Al[row][c8] = *(const uint4*)&h2bf[(size_t)(m0 + row) * 512 + kt + c8];
        }
        #pragma unroll
        for (int i = 0; i < 2; i++) {
            int idx = i * 512 + tid;
            int row = idx >> 3, c8 = (idx & 7) * 8;
            *(uint4*)&Bl[row][c8] = *(const uint4*)&Wbf[(size_t)(n0 + row) * 512 + kt + c8];
        }
        __syncthreads();
        #pragma unroll
        for (int kk = 0; kk < 2; kk++) {
            v8s a[4], bfr[4];
            int ko = kk * 32 + (lane >> 4) * 8;
            #pragma unroll
            for (int mi = 0; mi < 4; mi++)
                a[mi] = *(const v8s*)&Al[wm * 64 + mi * 16 + (lane & 15)][ko];
            #pragma unroll
            for (int ni = 0; ni < 4; ni++)
                bfr[ni] = *(const v8s*)&Bl[wn * 64 + ni * 16 + (lane & 15)][ko];
            #pragma unroll
            for (int mi = 0; mi < 4; mi++)
                #pragma unroll
                for (int ni = 0; ni < 4; ni++)
                    acc[mi][ni] = __builtin_amdgcn_mfma_f32_16x16x32_bf16(a[mi], bfr[ni], acc[mi][ni], 0, 0, 0);
        }
    }
    int col = lane & 15, rbase = (lane >> 4) * 4;
    #pragma unroll
    for (int mi = 0; mi < 4; mi++)
        #pragma unroll
        for (int ni = 0; ni < 4; ni++)
            #pragma unroll
            for (int r = 0; r < 4; r++) {
                int m = m0 + wm * 64 + mi * 16 + rbase + r;
                int v = n0 + wn * 64 + ni * 16 + col;
                int b = m & 31, t = m >> 5;
                out[((size_t)(b * 64 + t)) * 32000 + v] = acc[mi][ni][r];
            }
}

// ---------------- launch ----------------
extern "C" void kernel_launch(void* const* d_in, const int* in_sizes, int n_in,
                              void* d_out, int out_size, void* d_ws, size_t ws_size,
                              hipStream_t stream) {
    const float* img    = (const float*)d_in[0];
    const int*   toks   = (const int*)d_in[1];
    const float* embed  = (const float*)d_in[2];
    const float* W_ctx  = (const float*)d_in[3];
    const float* W_mix  = (const float*)d_in[4];
    const float* ln_g   = (const float*)d_in[5];
    const float* ln_b   = (const float*)d_in[6];
    const float* W_ih   = (const float*)d_in[7];
    const float* W_hh   = (const float*)d_in[8];
    const float* b_ih   = (const float*)d_in[9];
    const float* b_hh   = (const float*)d_in[10];
    const float* W_head = (const float*)d_in[11];
    const float* W_img  = (const float*)d_in[12];
    const float* W_hid  = (const float*)d_in[13];
    const float* w_sc   = (const float*)d_in[14];
    const float* W_h0   = (const float*)d_in[15];
    const float* b_h0   = (const float*)d_in[16];
    const float* W_c0   = (const float*)d_in[17];
    const float* b_c0   = (const float*)d_in[18];

    float* out = (float*)d_out;
    float* ws  = (float*)d_ws;
    ushort* Wbf    = (ushort*)(ws + WS_WBF);
    ushort* h2bf   = (ushort*)(ws + WS_H2BF);
    float*  imgEM  = ws + WS_IMGEM;
    float*  proj   = ws + WS_PROJ;
    float*  embM   = ws + WS_EMBM;
    ushort* whhbf  = (ushort*)(ws + WS_WHHBF);
    ushort* wihbf  = (ushort*)(ws + WS_WIHBF);
    ushort* whidbf = (ushort*)(ws + WS_WHIDBF);
    float*  H      = ws + WS_H;
    float*  XN     = ws + WS_XN;
    float*  C      = ws + WS_C;
    unsigned* flg  = (unsigned*)(ws + WS_FLAGS);
    float*  g      = ws + WS_G;
    // prep scratch (inside Wbf slot; dead before W_head cast)
    ushort* imgbf   = (ushort*)(ws + PS_IMGBF);
    ushort* wctxbf  = (ushort*)(ws + PS_WCTXBF);
    ushort* wimgbf  = (ushort*)(ws + PS_WIMGBF);
    ushort* wmixRbf = (ushort*)(ws + PS_WMIXRBF);
    ushort* wmixLbf = (ushort*)(ws + PS_WMIXLBF);
    ushort* imgEbf  = (ushort*)(ws + PS_IMGEBF);

    // prep 1: all casts (img + 7 weights) + flag zeroing, one launch
    k_castall<<<3617, 256, 0, stream>>>(img, W_ctx, W_img, W_mix, W_hh, W_ih, W_hid,
                                        imgbf, wctxbf, wimgbf, wmixRbf, wmixLbf,
                                        whhbf, wihbf, whidbf, flg);
    // prep 2: fused triple GEMM (imgEbf bf16-direct, proj, embM with embed gather)
    k_gemm3<<<129, 256, 0, stream>>>(imgbf, wctxbf, wimgbf, embed, toks, wmixLbf,
                                     imgEbf, proj, embM);
    // prep 3: imgEM = imgEbf @ wmixR^T
    k_gemm<<<dim3(4, 13), 256, 0, stream>>>(imgEbf, wmixRbf, imgEM, 512, 512);
    // prep 4: head weights (overwrites scratch region — after all scratch reads)
    k_castpad<<<8000, 256, 0, stream>>>(W_head, Wbf, 32000, 32000, 512, 512, 0);
    // prep 5: init state
    k_gmean<<<32, 256, 0, stream>>>(img, g);
    k_h0c0<<<64, 256, 0, stream>>>(g, W_h0, b_h0, W_c0, b_c0, H, C);

    // recurrence: flag-synced, MFMA gates, LDS-pinned weights + attn imgEM/proj
    k_persist<<<NBLK, 1024, 0, stream>>>(toks, embed, ln_g, ln_b, b_ih, b_hh, w_sc,
                                         whidbf, whhbf, wihbf, proj, imgEM, embM,
                                         H, C, XN, flg, h2bf);

    // deferred batched head GEMM: 256x128 tiles, grid (m=8, n=250)
    k_head<<<dim3(8, 250), 512, 0, stream>>>(h2bf, Wbf, out);
}

// Round 14
// 1006.518 us; speedup vs baseline: 1.3860x; 1.0374x over previous
//
#include <hip/hip_runtime.h>

#define NV 32000
#define NT 64
#define NBLK 256u

typedef unsigned long long ull;
typedef unsigned short ushort;
typedef __attribute__((ext_vector_type(8))) short v8s;
typedef __attribute__((ext_vector_type(4))) float v4f;

// persistent ws layout (float offsets; ushort regions = count/2 floats)
#define WS_WBF     0          // ushort [32000][512]           -> 8192000
#define WS_H2BF    8192000    // ushort [2048][512]  (524288)  -> 8716288
#define WS_IMGEM   8716288    // f32 [1664][512]     (851968)  -> 9568256
#define WS_PROJ    9568256    // f32 [1664][128]     (212992)  -> 9781248
#define WS_EMBM    9781248    // f32 [2048][512]     (1048576) -> 10829824
#define WS_WHHBF   10829824   // ushort [2048][512]  (524288)  -> 11354112
#define WS_WIHBF   11354112   // ushort [2048][512]  (524288)  -> 11878400
#define WS_WHIDBF  11878400   // ushort [128][512]   (32768)   -> 11911168
#define WS_H       11911168   // f32 [2][32][512]    (32768)   -> 11943936
#define WS_XN      11943936   // f32 [32][512]       (16384)   -> 11960320
#define WS_C       11960320   // f32 [32][512]       (16384)   -> 11976704
#define WS_FLAGS   11976704   // 160 slots x 16 u32  (2560)    -> 11979264
#define WS_G       11979264   // f32 [32][2048]      (65536)   -> 12044800
// prep scratch (inside Wbf slot [0,8192000); dead before W_head cast)
#define PS_IMGBF   0          // ushort [1664][2048] (1703936) -> 1703936
#define PS_WCTXBF  1703936    // ushort [512][2048]  (524288)  -> 2228224
#define PS_WIMGBF  2228224    // ushort [128][2048]  (131072)  -> 2359296
#define PS_WMIXRBF 2359296    // ushort [512][512]   (131072)  -> 2490368
#define PS_WMIXLBF 2490368    // ushort [512][512]   (131072)  -> 2621440
#define PS_IMGEBF  3342336    // ushort [1664][512]  (425984)  -> 3768320

__device__ __forceinline__ float fsig(float x) {
    x = fminf(fmaxf(x, -30.f), 30.f);
    return 1.f / (1.f + __expf(-x));
}
__device__ __forceinline__ float ftanh(float x) {
    x = fminf(fmaxf(x, -15.f), 15.f);
    float e = __expf(2.f * x);
    return (e - 1.f) / (e + 1.f);
}
__device__ __forceinline__ unsigned short f2bf(float f) {
    union { float f; unsigned int u; } v; v.f = f;
    unsigned int u = v.u;
    return (unsigned short)((u + 0x7FFFu + ((u >> 16) & 1u)) >> 16);
}
__device__ __forceinline__ unsigned pkf(float x, float y) {
    return (unsigned)f2bf(x) | ((unsigned)f2bf(y) << 16);
}
__device__ __forceinline__ float bf_lo(unsigned u) { return __uint_as_float(u << 16); }
__device__ __forceinline__ float bf_hi(unsigned u) { return __uint_as_float(u & 0xffff0000u); }
__device__ __forceinline__ ull agld(const ull* p) {
    return __hip_atomic_load(p, __ATOMIC_RELAXED, __HIP_MEMORY_SCOPE_AGENT);
}
__device__ __forceinline__ unsigned pk2(ull v) {
    return (unsigned)f2bf(__uint_as_float((unsigned)v)) |
           ((unsigned)f2bf(__uint_as_float((unsigned)(v >> 32))) << 16);
}

// ---------------- prep kernels ----------------

// plain fp32->bf16 cast (W_head only)
__global__ __launch_bounds__(256) void k_castpad(const float* __restrict__ in,
        ushort* __restrict__ out, int R, int Rpad, int K, int ldi, int off) {
    size_t i = ((size_t)blockIdx.x * 256 + threadIdx.x) * 8;
    if (i >= (size_t)Rpad * K) return;
    int r = (int)(i / K), k = (int)(i % K);
    uint4 o = {0, 0, 0, 0};
    if (r < R) {
        const float* p = in + (size_t)r * ldi + off + k;
        float4 a = *(const float4*)(p);
        float4 b = *(const float4*)(p + 4);
        o.x = pkf(a.x, a.y); o.y = pkf(a.z, a.w);
        o.z = pkf(b.x, b.y); o.w = pkf(b.z, b.w);
    }
    *(uint4*)(out + i) = o;
}

// single launch: all 8 bf16 weight/input casts + flag zeroing
__global__ __launch_bounds__(256) void k_castall(
        const float* __restrict__ img, const float* __restrict__ Wctx,
        const float* __restrict__ Wimg, const float* __restrict__ Wmix,
        const float* __restrict__ Whh, const float* __restrict__ Wih,
        const float* __restrict__ Whid,
        ushort* __restrict__ imgbf, ushort* __restrict__ wctxbf,
        ushort* __restrict__ wimgbf, ushort* __restrict__ wmixRbf,
        ushort* __restrict__ wmixLbf, ushort* __restrict__ whhbf,
        ushort* __restrict__ wihbf, ushort* __restrict__ whidbf,
        unsigned* __restrict__ flg) {
    int blk = blockIdx.x, tid = threadIdx.x;
    if (blk >= 3616) {                       // zero the 160 flag slots
        for (int i = tid; i < 2560; i += 256) flg[i] = 0u;
        return;
    }
    const float* in; ushort* out; int R, K, ldi, off;
    if (blk < 1664)      { in = img;  out = imgbf;   R = 1568; K = 2048; ldi = 2048; off = 0; }
    else if (blk < 2176) { in = Wctx; out = wctxbf;  R = 512;  K = 2048; ldi = 2048; off = 0;   blk -= 1664; }
    else if (blk < 2304) { in = Wimg; out = wimgbf;  R = 128;  K = 2048; ldi = 2048; off = 0;   blk -= 2176; }
    else if (blk < 2432) { in = Wmix; out = wmixRbf; R = 512;  K = 512;  ldi = 1024; off = 512; blk -= 2304; }
    else if (blk < 2560) { in = Wmix; out = wmixLbf; R = 512;  K = 512;  ldi = 1024; off = 0;   blk -= 2432; }
    else if (blk < 3072) { in = Whh;  out = whhbf;   R = 2048; K = 512;  ldi = 512;  off = 0;   blk -= 2560; }
    else if (blk < 3584) { in = Wih;  out = wihbf;   R = 2048; K = 512;  ldi = 512;  off = 0;   blk -= 3072; }
    else                 { in = Whid; out = whidbf;  R = 128;  K = 512;  ldi = 512;  off = 0;   blk -= 3584; }
    size_t i = ((size_t)blk * 256 + tid) * 8;
    int r = (int)(i / K), k = (int)(i % K);
    uint4 o = {0, 0, 0, 0};
    if (r < R) {
        const float* p = in + (size_t)r * ldi + off + k;
        float4 a = *(const float4*)(p);
        float4 b = *(const float4*)(p + 4);
        o.x = pkf(a.x, a.y); o.y = pkf(a.z, a.w);
        o.z = pkf(b.x, b.y); o.w = pkf(b.z, b.w);
    }
    *(uint4*)(out + i) = o;
}

// generic bf16 GEMM, fp32 out: C[m][n] = sum_k A[m][k]*B[n][k]
__global__ __launch_bounds__(256) void k_gemm(const ushort* __restrict__ A,
        const ushort* __restrict__ B, float* __restrict__ C, int N, int K) {
    __shared__ ushort Al[128][72];
    __shared__ ushort Bl[128][72];
    int n0 = blockIdx.x * 128, m0 = blockIdx.y * 128;
    int tid = threadIdx.x, lane = tid & 63, wid = tid >> 6;
    int wm = wid >> 1, wn = wid & 1;
    v4f acc[4][4] = {};
    for (int kt = 0; kt < K; kt += 64) {
        __syncthreads();
        #pragma unroll
        for (int i = 0; i < 4; i++) {
            int idx = i * 256 + tid;
            int row = idx >> 3, c8 = (idx & 7) * 8;
            *(uint4*)&Al[row][c8] = *(const uint4*)&A[(size_t)(m0 + row) * K + kt + c8];
            *(uint4*)&Bl[row][c8] = *(const uint4*)&B[(size_t)(n0 + row) * K + kt + c8];
        }
        __syncthreads();
        #pragma unroll
        for (int kk = 0; kk < 2; kk++) {
            v8s a[4], bfr[4];
            int ko = kk * 32 + (lane >> 4) * 8;
            #pragma unroll
            for (int mi = 0; mi < 4; mi++)
                a[mi] = *(const v8s*)&Al[wm * 64 + mi * 16 + (lane & 15)][ko];
            #pragma unroll
            for (int ni = 0; ni < 4; ni++)
                bfr[ni] = *(const v8s*)&Bl[wn * 64 + ni * 16 + (lane & 15)][ko];
            #pragma unroll
            for (int mi = 0; mi < 4; mi++)
                #pragma unroll
                for (int ni = 0; ni < 4; ni++)
                    acc[mi][ni] = __builtin_amdgcn_mfma_f32_16x16x32_bf16(a[mi], bfr[ni], acc[mi][ni], 0, 0, 0);
        }
    }
    int col = lane & 15, rbase = (lane >> 4) * 4;
    #pragma unroll
    for (int mi = 0; mi < 4; mi++)
        #pragma unroll
        for (int ni = 0; ni < 4; ni++)
            #pragma unroll
            for (int r = 0; r < 4; r++) {
                int m = m0 + wm * 64 + mi * 16 + rbase + r;
                int v = n0 + wn * 64 + ni * 16 + col;
                C[(size_t)m * N + v] = acc[mi][ni][r];
            }
}

// fused triple GEMM in one launch
__global__ __launch_bounds__(256) void k_gemm3(
        const ushort* __restrict__ imgbf, const ushort* __restrict__ wctxbf,
        const ushort* __restrict__ wimgbf, const float* __restrict__ embed,
        const int* __restrict__ toks, const ushort* __restrict__ wmixLbf,
        ushort* __restrict__ imgEbf, float* __restrict__ proj,
        float* __restrict__ embM) {
    __shared__ ushort Al[128][72];
    __shared__ ushort Bl[128][72];
    int bid = blockIdx.x;
    const ushort* A; const ushort* B; int mode, K, N, n0, m0;
    if (bid < 52)      { mode = 0; A = imgbf; B = wctxbf;  K = 2048; N = 512; n0 = (bid & 3) * 128; m0 = (bid >> 2) * 128; }
    else if (bid < 65) { mode = 1; A = imgbf; B = wimgbf;  K = 2048; N = 128; n0 = 0;               m0 = (bid - 52) * 128; }
    else { int e = bid - 65; mode = 2; A = nullptr; B = wmixLbf; K = 512; N = 512; n0 = (e & 3) * 128; m0 = (e >> 2) * 128; }
    int tid = threadIdx.x, lane = tid & 63, wid = tid >> 6;
    int wm = wid >> 1, wn = wid & 1;
    v4f acc[4][4] = {};
    for (int kt = 0; kt < K; kt += 64) {
        __syncthreads();
        #pragma unroll
        for (int i = 0; i < 4; i++) {
            int idx = i * 256 + tid;
            int row = idx >> 3, c8 = (idx & 7) * 8;
            if (mode == 2) {
                int rowg = m0 + row;
                int tok = toks[(rowg & 31) * 64 + (rowg >> 5)];
                uint4 oa = {0, 0, 0, 0};
                if (tok != 0) {
                    const float* pa = embed + (size_t)tok * 512 + kt + c8;
                    float4 a0 = *(const float4*)pa, a1 = *(const float4*)(pa + 4);
                    oa.x = pkf(a0.x, a0.y); oa.y = pkf(a0.z, a0.w);
                    oa.z = pkf(a1.x, a1.y); oa.w = pkf(a1.z, a1.w);
                }
                *(uint4*)&Al[row][c8] = oa;
            } else {
                *(uint4*)&Al[row][c8] = *(const uint4*)&A[(size_t)(m0 + row) * K + kt + c8];
            }
            *(uint4*)&Bl[row][c8] = *(const uint4*)&B[(size_t)(n0 + row) * K + kt + c8];
        }
        __syncthreads();
        #pragma unroll
        for (int kk = 0; kk < 2; kk++) {
            v8s a[4], bfr[4];
            int ko = kk * 32 + (lane >> 4) * 8;
            #pragma unroll
            for (int mi = 0; mi < 4; mi++)
                a[mi] = *(const v8s*)&Al[wm * 64 + mi * 16 + (lane & 15)][ko];
            #pragma unroll
            for (int ni = 0; ni < 4; ni++)
                bfr[ni] = *(const v8s*)&Bl[wn * 64 + ni * 16 + (lane & 15)][ko];
            #pragma unroll
            for (int mi = 0; mi < 4; mi++)
                #pragma unroll
                for (int ni = 0; ni < 4; ni++)
                    acc[mi][ni] = __builtin_amdgcn_mfma_f32_16x16x32_bf16(a[mi], bfr[ni], acc[mi][ni], 0, 0, 0);
        }
    }
    int col = lane & 15, rbase = (lane >> 4) * 4;
    #pragma unroll
    for (int mi = 0; mi < 4; mi++)
        #pragma unroll
        for (int ni = 0; ni < 4; ni++)
            #pragma unroll
            for (int r = 0; r < 4; r++) {
                int m = m0 + wm * 64 + mi * 16 + rbase + r;
                int v = n0 + wn * 64 + ni * 16 + col;
                if (mode == 0)      imgEbf[(size_t)m * 512 + v] = f2bf(acc[mi][ni][r]);
                else if (mode == 1) proj[(size_t)m * 128 + v] = acc[mi][ni][r];
                else                embM[(size_t)m * 512 + v] = acc[mi][ni][r];
            }
}

__global__ __launch_bounds__(256) void k_gmean(const float* __restrict__ img,
                                               float* __restrict__ g) {
    int b = blockIdx.x;
    for (int d = threadIdx.x; d < 2048; d += 256) {
        float s = 0.f;
        for (int ss = 0; ss < 49; ss++) s += img[((size_t)(b * 49 + ss)) * 2048 + d];
        g[b * 2048 + d] = s * (1.f / 49.f);
    }
}

__global__ __launch_bounds__(256) void k_h0c0(const float* __restrict__ g,
        const float* __restrict__ Wh0, const float* __restrict__ bh0,
        const float* __restrict__ Wc0, const float* __restrict__ bc0,
        float* __restrict__ h0, float* __restrict__ c0) {
    int b = blockIdx.x >> 1, m = blockIdx.x & 1;
    __shared__ float gs[2048];
    for (int d = threadIdx.x; d < 2048; d += 256) gs[d] = g[b * 2048 + d];
    __syncthreads();
    const float* W = m ? Wc0 : Wh0;
    const float* bb = m ? bc0 : bh0;
    float* out = m ? c0 : h0;
    for (int r = threadIdx.x; r < 512; r += 256) {
        float acc = 0.f;
        const float* wr = W + (size_t)r * 2048;
        for (int d = 0; d < 2048; d += 4) {
            float4 w = *(const float4*)(wr + d);
            acc += w.x * gs[d] + w.y * gs[d + 1] + w.z * gs[d + 2] + w.w * gs[d + 3];
        }
        out[b * 512 + r] = ftanh(acc + bb[r]) * 0.5f;
    }
}

// ---------------- persistent kernel: gates + attn + head roles ----------------
// 128 gates (R13-proven) + 32 attn (R13-proven) + 96 head blocks.
// Head consumes h2bf m-tiles as gates flags advance; h2bf is written as
// packed-u32 agent-scope atomics and read with agent-scope ull loads (G16).

__device__ __forceinline__ void waitflags(unsigned* FLG, int base, int stride,
                                          int n, unsigned tgt) {
    if (threadIdx.x < 64) {
        bool done;
        do {
            unsigned v = tgt;
            if ((int)threadIdx.x < n)
                v = __hip_atomic_load(FLG + (base + (int)threadIdx.x * stride) * 16,
                                      __ATOMIC_RELAXED, __HIP_MEMORY_SCOPE_AGENT);
            done = __all((int)(v >= tgt));
            if (!done) __builtin_amdgcn_s_sleep(1);
        } while (!done);
    }
    __syncthreads();
}

union SMem {
    struct {                       // gates role (blocks 0..127)
        ushort wh[64][520];
        ushort wi[64][520];
        ushort hsb[16][520];
        float gtmp[4][16][16];
        ushort h2s[16][8];         // h2 stash for packed h2bf stores
    } g;                           // ~154.1 KB
    struct {                       // attention role (blocks 128..159)
        float imgem[49][512];
        float projl[49][128];
        float hb[512];
        float ebs[512];
        float php[8][128];
        float ph[128];
        float scp[64][16];
        float wsm[64];
        float xps[2][512];
        float wred[8][2];
        float bc[2];
    } a;                           // ~142.5 KB
    struct {                       // head role (blocks 160..255)
        ushort Al[256][72];
        ushort Bl[128][72];
    } h;                           // 55.3 KB
};

__global__ __launch_bounds__(1024, 1) void k_persist(
        const int* __restrict__ toks, const float* __restrict__ embed,
        const float* __restrict__ lng, const float* __restrict__ lnb,
        const float* __restrict__ bih, const float* __restrict__ bhh,
        const float* __restrict__ wsc, const ushort* __restrict__ whidbf,
        const ushort* __restrict__ whhbf, const ushort* __restrict__ wihbf,
        const float* __restrict__ proj, const float* __restrict__ imgEM,
        const float* __restrict__ embM, float* __restrict__ H,
        const float* __restrict__ C0, float* __restrict__ XN,
        unsigned* __restrict__ FLG, ushort* __restrict__ h2bf,
        const ushort* __restrict__ Wbf, float* __restrict__ out) {
    __shared__ SMem sm;
    int blk = blockIdx.x, tid = threadIdx.x;

    if (blk < 128) {
        // ---------------- gates role ----------------
        int jc = blk >> 2, bg = blk & 3, b0 = bg * 8;
        int wid = tid >> 6, lane = tid & 63;
        int gate = wid & 3;
        for (int i = tid; i < 4096; i += 1024) {
            int rr = i >> 6, c8 = (i & 63) * 8;
            size_t R = (size_t)((rr >> 4) * 512 + jc * 16 + (rr & 15)) * 512 + c8;
            *(uint4*)&sm.g.wh[rr][c8] = *(const uint4*)&whhbf[R];
            *(uint4*)&sm.g.wi[rr][c8] = *(const uint4*)&wihbf[R];
        }
        for (int i = tid; i < 2080; i += 1024) ((ull*)sm.g.hsb)[i] = 0;
        float c_reg = 0.f, bs0 = 0.f, bs1 = 0.f, bs2 = 0.f, bs3 = 0.f;
        if (tid < 128) {
            int jl = tid >> 3, bb = tid & 7;
            int j = jc * 16 + jl;
            c_reg = C0[(b0 + bb) * 512 + j];
            bs0 = bih[j] + bhh[j];
            bs1 = bih[512 + j] + bhh[512 + j];
            bs2 = bih[1024 + j] + bhh[1024 + j];
            bs3 = bih[1536 + j] + bhh[1536 + j];
        }
        __syncthreads();

        for (int t = 0; t < NT; t++) {
            waitflags(FLG, bg, 4, 32, (unsigned)t);
            {   // stage h -> hsb bf16 (rows 0..7)
                const float* Hb = H + (t & 1) * 16384 + b0 * 512;
                if (tid < 512) {
                    int bb = tid >> 6, c8 = (tid & 63) * 8;
                    const ull* p = (const ull*)(Hb + bb * 512 + c8);
                    uint4 o = { pk2(agld(p)), pk2(agld(p + 1)),
                                pk2(agld(p + 2)), pk2(agld(p + 3)) };
                    *(uint4*)&sm.g.hsb[bb][c8] = o;
                }
            }
            __syncthreads();
            v4f acc = {};
            if (wid < 4) {
                #pragma unroll
                for (int ks = 0; ks < 16; ks++) {
                    int ko = ks * 32 + (lane >> 4) * 8;
                    v8s a = *(const v8s*)&sm.g.hsb[lane & 15][ko];
                    v8s b = *(const v8s*)&sm.g.wh[gate * 16 + (lane & 15)][ko];
                    acc = __builtin_amdgcn_mfma_f32_16x16x32_bf16(a, b, acc, 0, 0, 0);
                }
            }
            waitflags(FLG, 128 + b0, 1, 8, (unsigned)(t + 1));
            {   // stage xn -> hsb bf16
                const float* Xb = XN + b0 * 512;
                if (tid < 512) {
                    int bb = tid >> 6, c8 = (tid & 63) * 8;
                    const ull* p = (const ull*)(Xb + bb * 512 + c8);
                    uint4 o = { pk2(agld(p)), pk2(agld(p + 1)),
                                pk2(agld(p + 2)), pk2(agld(p + 3)) };
                    *(uint4*)&sm.g.hsb[bb][c8] = o;
                }
            }
            __syncthreads();
            if (wid < 4) {
                #pragma unroll
                for (int ks = 0; ks < 16; ks++) {
                    int ko = ks * 32 + (lane >> 4) * 8;
                    v8s a = *(const v8s*)&sm.g.hsb[lane & 15][ko];
                    v8s b = *(const v8s*)&sm.g.wi[gate * 16 + (lane & 15)][ko];
                    acc = __builtin_amdgcn_mfma_f32_16x16x32_bf16(a, b, acc, 0, 0, 0);
                }
                #pragma unroll
                for (int q = 0; q < 4; q++)
                    sm.g.gtmp[gate][lane & 15][(lane >> 4) * 4 + q] = acc[q];
            }
            __syncthreads();
            if (tid < 128) {
                int jl = tid >> 3, bb = tid & 7;
                float vi = sm.g.gtmp[0][jl][bb] + bs0;
                float vf = sm.g.gtmp[1][jl][bb] + bs1;
                float vg = sm.g.gtmp[2][jl][bb] + bs2;
                float vo = sm.g.gtmp[3][jl][bb] + bs3;
                float c2 = fsig(vf) * c_reg + fsig(vi) * ftanh(vg);
                float h2 = fsig(vo) * ftanh(c2);
                c_reg = c2;
                int bglob = b0 + bb, j = jc * 16 + jl;
                __hip_atomic_store((unsigned*)&H[((t + 1) & 1) * 16384 + bglob * 512 + j],
                                   __float_as_uint(h2), __ATOMIC_RELAXED, __HIP_MEMORY_SCOPE_AGENT);
                sm.g.h2s[jl][bb] = f2bf(h2);
            }
            __syncthreads();
            if (tid < 64) {   // packed agent-scope h2bf store (u32 = 2 adjacent j)
                int jlp = tid >> 3, bb = tid & 7;
                unsigned pk = (unsigned)sm.g.h2s[2 * jlp][bb]
                            | ((unsigned)sm.g.h2s[2 * jlp + 1][bb] << 16);
                int bglob = b0 + bb, j = jc * 16 + 2 * jlp;
                __hip_atomic_store((unsigned*)&h2bf[(size_t)(t * 32 + bglob) * 512 + j],
                                   pk, __ATOMIC_RELAXED, __HIP_MEMORY_SCOPE_AGENT);
            }
            __syncthreads();
            if (tid == 0)
                __hip_atomic_store(FLG + blk * 16, (unsigned)(t + 1),
                                   __ATOMIC_RELAXED, __HIP_MEMORY_SCOPE_AGENT);
        }
    } else if (blk < 160) {
        // ---------------- attention role (R13-proven) ----------------
        int b = blk - 128, bgb = b >> 3;
        for (int i = tid; i < 49 * 512; i += 1024)
            sm.a.imgem[i >> 9][i & 511] = imgEM[(size_t)b * 49 * 512 + i];
        for (int i = tid; i < 49 * 128; i += 1024)
            sm.a.projl[i >> 7][i & 127] = proj[(size_t)b * 49 * 128 + i];
        __syncthreads();
        for (int t = 0; t < NT; t++) {
            waitflags(FLG, bgb, 4, 32, (unsigned)t);
            int tok = toks[b * 64 + t];
            if (tid < 256) {
                ull v = agld((const ull*)(H + (t & 1) * 16384) + b * 256 + tid);
                *(ull*)&sm.a.hb[tid * 2] = v;
            } else if (tid < 768) {
                int k = tid - 256;
                sm.a.ebs[k] = (tok == 0) ? 0.f : embed[(size_t)tok * 512 + k];
            }
            __syncthreads();
            {   // ph partials (whid from L2, bf16)
                int a = tid & 127, kq = tid >> 7;
                const ushort* wr2 = whidbf + (size_t)a * 512 + kq * 64;
                const float* hp = sm.a.hb + kq * 64;
                float p = 0.f;
                #pragma unroll
                for (int k = 0; k < 64; k += 8) {
                    uint4 q = *(const uint4*)(wr2 + k);
                    float4 ha = *(const float4*)(hp + k);
                    float4 hb4 = *(const float4*)(hp + k + 4);
                    p += bf_lo(q.x)*ha.x + bf_hi(q.x)*ha.y + bf_lo(q.y)*ha.z + bf_hi(q.y)*ha.w
                       + bf_lo(q.z)*hb4.x + bf_hi(q.z)*hb4.y + bf_lo(q.w)*hb4.z + bf_hi(q.w)*hb4.w;
                }
                sm.a.php[kq][a] = p;
            }
            __syncthreads();
            if (tid < 128) {
                float p = 0.f;
                #pragma unroll
                for (int kq = 0; kq < 8; kq++) p += sm.a.php[kq][tid];
                sm.a.ph[tid] = p;
            }
            __syncthreads();
            {   // score partials (proj from LDS)
                int s = tid >> 4, aq = tid & 15;
                float p = 0.f;
                if (s < 49) {
                    const float* pr = &sm.a.projl[s][aq * 8];
                    #pragma unroll
                    for (int a = 0; a < 8; a++)
                        p += ftanh(pr[a] + sm.a.ph[aq * 8 + a]) * wsc[aq * 8 + a];
                }
                sm.a.scp[s][aq] = p;
            }
            __syncthreads();
            if (tid < 64) {
                float v = 0.f;
                #pragma unroll
                for (int q = 0; q < 16; q++) v += sm.a.scp[tid][q];
                if (tid >= 49) v = -1e30f;
                float m = v;
                for (int o = 32; o > 0; o >>= 1) m = fmaxf(m, __shfl_xor(m, o));
                float e = (tid < 49) ? __expf(v - m) : 0.f;
                float su = e;
                for (int o = 32; o > 0; o >>= 1) su += __shfl_xor(su, o);
                sm.a.wsm[tid] = e / su;
            }
            __syncthreads();
            {   // x = embM + sum_s w_s imgEM (imgem from LDS)
                int e = tid & 511, sh = tid >> 9;
                float xp = 0.f;
                if (sh == 0) xp = embM[(size_t)(t * 32 + b) * 512 + e];
                int s0 = sh * 25, s1 = sh ? 49 : 25;
                for (int s = s0; s < s1; s++)
                    xp += sm.a.wsm[s] * sm.a.imgem[s][e];
                sm.a.xps[sh][e] = xp;
            }
            __syncthreads();
            if (tid < 512) {
                float x = fmaxf(sm.a.xps[0][tid] + sm.a.xps[1][tid], 0.f);
                float s = x, s2 = x * x;
                for (int o = 32; o > 0; o >>= 1) { s += __shfl_xor(s, o); s2 += __shfl_xor(s2, o); }
                if ((tid & 63) == 0) { sm.a.wred[tid >> 6][0] = s; sm.a.wred[tid >> 6][1] = s2; }
            }
            __syncthreads();
            if (tid == 0) {
                float s = 0.f, s2 = 0.f;
                #pragma unroll
                for (int w = 0; w < 8; w++) { s += sm.a.wred[w][0]; s2 += sm.a.wred[w][1]; }
                float mu = s * (1.f / 512.f);
                float var = s2 * (1.f / 512.f) - mu * mu;
                sm.a.bc[0] = mu; sm.a.bc[1] = rsqrtf(var + 1e-5f);
            }
            __syncthreads();
            if (tid < 512) {
                float x = fmaxf(sm.a.xps[0][tid] + sm.a.xps[1][tid], 0.f);
                float xn = (x - sm.a.bc[0]) * sm.a.bc[1] * lng[tid] + lnb[tid] + sm.a.ebs[tid];
                __hip_atomic_store((unsigned*)&XN[b * 512 + tid], __float_as_uint(xn),
                                   __ATOMIC_RELAXED, __HIP_MEMORY_SCOPE_AGENT);
            }
            __syncthreads();
            if (tid == 0)
                __hip_atomic_store(FLG + (128 + b) * 16, (unsigned)(t + 1),
                                   __ATOMIC_RELAXED, __HIP_MEMORY_SCOPE_AGENT);
        }
    } else {
        // ---------------- head role (blocks 160..255) ----------------
        int hb = blk - 160;
        int lane = tid & 63, wid = tid >> 6;
        int wm = wid >> 1, wn = wid & 1;   // for wid<8: 4 m-quadrants x 2 n-halves
        unsigned have = 0;
        for (int w = hb; w < 2000; w += 96) {
            int mt = w / 250, nt = w % 250;
            unsigned need = (unsigned)(mt * 8 + 8);
            if (have < need) {
                if (tid < 64) {
                    bool done;
                    do {
                        unsigned v0 = __hip_atomic_load(FLG + tid * 16,
                                        __ATOMIC_RELAXED, __HIP_MEMORY_SCOPE_AGENT);
                        unsigned v1 = __hip_atomic_load(FLG + (tid + 64) * 16,
                                        __ATOMIC_RELAXED, __HIP_MEMORY_SCOPE_AGENT);
                        done = __all((int)(v0 >= need && v1 >= need));
                        if (!done) __builtin_amdgcn_s_sleep(8);
                    } while (!done);
                }
                __syncthreads();
                have = need;
            }
            int m0 = mt * 256, n0 = nt * 128;
            v4f acc[4][4] = {};
            for (int kt = 0; kt < 512; kt += 64) {
                __syncthreads();
                #pragma unroll
                for (int i = 0; i < 2; i++) {   // A: 2048 uint4 over 1024 thr
                    int idx = i * 1024 + tid;
                    int row = idx >> 3, c8 = (idx & 7) * 8;
                    const ull* p = (const ull*)&h2bf[(size_t)(m0 + row) * 512 + kt + c8];
                    ull v0 = agld(p), v1 = agld(p + 1);
                    *(ull*)&sm.h.Al[row][c8] = v0;
                    *(ull*)&sm.h.Al[row][c8 + 4] = v1;
                }
                {   // B: 1024 uint4 over 1024 thr
                    int row = tid >> 3, c8 = (tid & 7) * 8;
                    *(uint4*)&sm.h.Bl[row][c8] = *(const uint4*)&Wbf[(size_t)(n0 + row) * 512 + kt + c8];
                }
                __syncthreads();
                if (wid < 8) {
                    #pragma unroll
                    for (int kk = 0; kk < 2; kk++) {
                        v8s a[4], bfr[4];
                        int ko = kk * 32 + (lane >> 4) * 8;
                        #pragma unroll
                        for (int mi = 0; mi < 4; mi++)
                            a[mi] = *(const v8s*)&sm.h.Al[wm * 64 + mi * 16 + (lane & 15)][ko];
                        #pragma unroll
                        for (int ni = 0; ni < 4; ni++)
                            bfr[ni] = *(const v8s*)&sm.h.Bl[wn * 64 + ni * 16 + (lane & 15)][ko];
                        #pragma unroll
                        for (int mi = 0; mi < 4; mi++)
                            #pragma unroll
                            for (int ni = 0; ni < 4; ni++)
                                acc[mi][ni] = __builtin_amdgcn_mfma_f32_16x16x32_bf16(a[mi], bfr[ni], acc[mi][ni], 0, 0, 0);
                    }
                }
            }
            if (wid < 8) {
                int col = lane & 15, rbase = (lane >> 4) * 4;
                #pragma unroll
                for (int mi = 0; mi < 4; mi++)
                    #pragma unroll
                    for (int ni = 0; ni < 4; ni++)
                        #pragma unroll
                        for (int r = 0; r < 4; r++) {
                            int m = m0 + wm * 64 + mi * 16 + rbase + r;
                            int v = n0 + wn * 64 + ni * 16 + col;
                            int b = m & 31, t = m >> 5;
                            out[((size_t)(b * 64 + t)) * 32000 + v] = acc[mi][ni][r];
                        }
            }
        }
    }
}

// ---------------- launch ----------------
extern "C" void kernel_launch(void* const* d_in, const int* in_sizes, int n_in,
                              void* d_out, int out_size, void* d_ws, size_t ws_size,
                              hipStream_t stream) {
    const float* img    = (const float*)d_in[0];
    const int*   toks   = (const int*)d_in[1];
    const float* embed  = (const float*)d_in[2];
    const float* W_ctx  = (const float*)d_in[3];
    const float* W_mix  = (const float*)d_in[4];
    const float* ln_g   = (const float*)d_in[5];
    const float* ln_b   = (const float*)d_in[6];
    const float* W_ih   = (const float*)d_in[7];
    const float* W_hh   = (const float*)d_in[8];
    const float* b_ih   = (const float*)d_in[9];
    const float* b_hh   = (const float*)d_in[10];
    const float* W_head = (const float*)d_in[11];
    const float* W_img  = (const float*)d_in[12];
    const float* W_hid  = (const float*)d_in[13];
    const float* w_sc   = (const float*)d_in[14];
    const float* W_h0   = (const float*)d_in[15];
    const float* b_h0   = (const float*)d_in[16];
    const float* W_c0   = (const float*)d_in[17];
    const float* b_c0   = (const float*)d_in[18];

    float* out = (float*)d_out;
    float* ws  = (float*)d_ws;
    ushort* Wbf    = (ushort*)(ws + WS_WBF);
    ushort* h2bf   = (ushort*)(ws + WS_H2BF);
    float*  imgEM  = ws + WS_IMGEM;
    float*  proj   = ws + WS_PROJ;
    float*  embM   = ws + WS_EMBM;
    ushort* whhbf  = (ushort*)(ws + WS_WHHBF);
    ushort* wihbf  = (ushort*)(ws + WS_WIHBF);
    ushort* whidbf = (ushort*)(ws + WS_WHIDBF);
    float*  H      = ws + WS_H;
    float*  XN     = ws + WS_XN;
    float*  C      = ws + WS_C;
    unsigned* flg  = (unsigned*)(ws + WS_FLAGS);
    float*  g      = ws + WS_G;
    // prep scratch (inside Wbf slot; dead before W_head cast)
    ushort* imgbf   = (ushort*)(ws + PS_IMGBF);
    ushort* wctxbf  = (ushort*)(ws + PS_WCTXBF);
    ushort* wimgbf  = (ushort*)(ws + PS_WIMGBF);
    ushort* wmixRbf = (ushort*)(ws + PS_WMIXRBF);
    ushort* wmixLbf = (ushort*)(ws + PS_WMIXLBF);
    ushort* imgEbf  = (ushort*)(ws + PS_IMGEBF);

    // prep 1: all casts (img + 7 weights) + flag zeroing, one launch
    k_castall<<<3617, 256, 0, stream>>>(img, W_ctx, W_img, W_mix, W_hh, W_ih, W_hid,
                                        imgbf, wctxbf, wimgbf, wmixRbf, wmixLbf,
                                        whhbf, wihbf, whidbf, flg);
    // prep 2: fused triple GEMM
    k_gemm3<<<129, 256, 0, stream>>>(imgbf, wctxbf, wimgbf, embed, toks, wmixLbf,
                                     imgEbf, proj, embM);
    // prep 3: imgEM = imgEbf @ wmixR^T
    k_gemm<<<dim3(4, 13), 256, 0, stream>>>(imgEbf, wmixRbf, imgEM, 512, 512);
    // prep 4: head weights (overwrites scratch region — after all scratch reads)
    k_castpad<<<8000, 256, 0, stream>>>(W_head, Wbf, 32000, 32000, 512, 512, 0);
    // prep 5: init state
    k_gmean<<<32, 256, 0, stream>>>(img, g);
    k_h0c0<<<64, 256, 0, stream>>>(g, W_h0, b_h0, W_c0, b_c0, H, C);

    // fused recurrence + streamed head GEMM (256 blocks = 1/CU)
    k_persist<<<NBLK, 1024, 0, stream>>>(toks, embed, ln_g, ln_b, b_ih, b_hh, w_sc,
                                         whidbf, whhbf, wihbf, proj, imgEM, embM,
                                         H, C, XN, flg, h2bf, Wbf, out);
}

// Round 16
// 983.259 us; speedup vs baseline: 1.4188x; 1.0237x over previous
//
#include <hip/hip_runtime.h>

#define NV 32000
#define NT 64
#define NBLK 256u

typedef unsigned long long ull;
typedef unsigned short ushort;
typedef __attribute__((ext_vector_type(8))) short v8s;
typedef __attribute__((ext_vector_type(4))) float v4f;

// persistent ws layout (float offsets; ushort regions = count/2 floats)
#define WS_WBF     0          // ushort [32000][512]           -> 8192000
#define WS_H2BF    8192000    // ushort [2048][512]  (524288)  -> 8716288
#define WS_IMGEM   8716288    // f32 [1664][512]     (851968)  -> 9568256
#define WS_PROJ    9568256    // f32 [1664][128]     (212992)  -> 9781248
#define WS_EMBM    9781248    // f32 [2048][512]     (1048576) -> 10829824
#define WS_WHHBF   10829824   // ushort [2048][512]  (524288)  -> 11354112
#define WS_WIHBF   11354112   // ushort [2048][512]  (524288)  -> 11878400
#define WS_WHIDBF  11878400   // ushort [128][512]   (32768)   -> 11911168
#define WS_H       11911168   // f32 [2][32][512]    (32768)   -> 11943936
#define WS_XN      11943936   // f32 [32][512]       (16384)   -> 11960320
#define WS_C       11960320   // f32 [32][512]       (16384)   -> 11976704
#define WS_FLAGS   11976704   // 160 slots x 16 u32; word 8 of slot0 = tile counter
#define WS_G       11979264   // f32 [32][2048]      (65536)   -> 12044800
// prep scratch (inside Wbf slot [0,8192000); dead before W_head cast)
#define PS_IMGBF   0          // ushort [1664][2048] (1703936) -> 1703936
#define PS_WCTXBF  1703936    // ushort [512][2048]  (524288)  -> 2228224
#define PS_WIMGBF  2228224    // ushort [128][2048]  (131072)  -> 2359296
#define PS_WMIXRBF 2359296    // ushort [512][512]   (131072)  -> 2490368
#define PS_WMIXLBF 2490368    // ushort [512][512]   (131072)  -> 2621440
#define PS_IMGEBF  3342336    // ushort [1664][512]  (425984)  -> 3768320

__device__ __forceinline__ float fsig(float x) {
    x = fminf(fmaxf(x, -30.f), 30.f);
    return 1.f / (1.f + __expf(-x));
}
__device__ __forceinline__ float ftanh(float x) {
    x = fminf(fmaxf(x, -15.f), 15.f);
    float e = __expf(2.f * x);
    return (e - 1.f) / (e + 1.f);
}
__device__ __forceinline__ unsigned short f2bf(float f) {
    union { float f; unsigned int u; } v; v.f = f;
    unsigned int u = v.u;
    return (unsigned short)((u + 0x7FFFu + ((u >> 16) & 1u)) >> 16);
}
__device__ __forceinline__ unsigned pkf(float x, float y) {
    return (unsigned)f2bf(x) | ((unsigned)f2bf(y) << 16);
}
__device__ __forceinline__ float bf_lo(unsigned u) { return __uint_as_float(u << 16); }
__device__ __forceinline__ float bf_hi(unsigned u) { return __uint_as_float(u & 0xffff0000u); }
__device__ __forceinline__ ull agld(const ull* p) {
    return __hip_atomic_load(p, __ATOMIC_RELAXED, __HIP_MEMORY_SCOPE_AGENT);
}
__device__ __forceinline__ unsigned pk2(ull v) {
    return (unsigned)f2bf(__uint_as_float((unsigned)v)) |
           ((unsigned)f2bf(__uint_as_float((unsigned)(v >> 32))) << 16);
}

// ---------------- prep kernels ----------------

__global__ __launch_bounds__(256) void k_castpad(const float* __restrict__ in,
        ushort* __restrict__ out, int R, int Rpad, int K, int ldi, int off) {
    size_t i = ((size_t)blockIdx.x * 256 + threadIdx.x) * 8;
    if (i >= (size_t)Rpad * K) return;
    int r = (int)(i / K), k = (int)(i % K);
    uint4 o = {0, 0, 0, 0};
    if (r < R) {
        const float* p = in + (size_t)r * ldi + off + k;
        float4 a = *(const float4*)(p);
        float4 b = *(const float4*)(p + 4);
        o.x = pkf(a.x, a.y); o.y = pkf(a.z, a.w);
        o.z = pkf(b.x, b.y); o.w = pkf(b.z, b.w);
    }
    *(uint4*)(out + i) = o;
}

__global__ __launch_bounds__(256) void k_castall(
        const float* __restrict__ img, const float* __restrict__ Wctx,
        const float* __restrict__ Wimg, const float* __restrict__ Wmix,
        const float* __restrict__ Whh, const float* __restrict__ Wih,
        const float* __restrict__ Whid,
        ushort* __restrict__ imgbf, ushort* __restrict__ wctxbf,
        ushort* __restrict__ wimgbf, ushort* __restrict__ wmixRbf,
        ushort* __restrict__ wmixLbf, ushort* __restrict__ whhbf,
        ushort* __restrict__ wihbf, ushort* __restrict__ whidbf,
        unsigned* __restrict__ flg) {
    int blk = blockIdx.x, tid = threadIdx.x;
    if (blk >= 3616) {                       // zero flag slots + tile counter
        for (int i = tid; i < 2560; i += 256) flg[i] = 0u;
        return;
    }
    const float* in; ushort* out; int R, K, ldi, off;
    if (blk < 1664)      { in = img;  out = imgbf;   R = 1568; K = 2048; ldi = 2048; off = 0; }
    else if (blk < 2176) { in = Wctx; out = wctxbf;  R = 512;  K = 2048; ldi = 2048; off = 0;   blk -= 1664; }
    else if (blk < 2304) { in = Wimg; out = wimgbf;  R = 128;  K = 2048; ldi = 2048; off = 0;   blk -= 2176; }
    else if (blk < 2432) { in = Wmix; out = wmixRbf; R = 512;  K = 512;  ldi = 1024; off = 512; blk -= 2304; }
    else if (blk < 2560) { in = Wmix; out = wmixLbf; R = 512;  K = 512;  ldi = 1024; off = 0;   blk -= 2432; }
    else if (blk < 3072) { in = Whh;  out = whhbf;   R = 2048; K = 512;  ldi = 512;  off = 0;   blk -= 2560; }
    else if (blk < 3584) { in = Wih;  out = wihbf;   R = 2048; K = 512;  ldi = 512;  off = 0;   blk -= 3072; }
    else                 { in = Whid; out = whidbf;  R = 128;  K = 512;  ldi = 512;  off = 0;   blk -= 3584; }
    size_t i = ((size_t)blk * 256 + tid) * 8;
    int r = (int)(i / K), k = (int)(i % K);
    uint4 o = {0, 0, 0, 0};
    if (r < R) {
        const float* p = in + (size_t)r * ldi + off + k;
        float4 a = *(const float4*)(p);
        float4 b = *(const float4*)(p + 4);
        o.x = pkf(a.x, a.y); o.y = pkf(a.z, a.w);
        o.z = pkf(b.x, b.y); o.w = pkf(b.z, b.w);
    }
    *(uint4*)(out + i) = o;
}

// generic bf16 GEMM, fp32 out
__global__ __launch_bounds__(256) void k_gemm(const ushort* __restrict__ A,
        const ushort* __restrict__ B, float* __restrict__ C, int N, int K) {
    __shared__ ushort Al[128][72];
    __shared__ ushort Bl[128][72];
    int n0 = blockIdx.x * 128, m0 = blockIdx.y * 128;
    int tid = threadIdx.x, lane = tid & 63, wid = tid >> 6;
    int wm = wid >> 1, wn = wid & 1;
    v4f acc[4][4] = {};
    for (int kt = 0; kt < K; kt += 64) {
        __syncthreads();
        #pragma unroll
        for (int i = 0; i < 4; i++) {
            int idx = i * 256 + tid;
            int row = idx >> 3, c8 = (idx & 7) * 8;
            *(uint4*)&Al[row][c8] = *(const uint4*)&A[(size_t)(m0 + row) * K + kt + c8];
            *(uint4*)&Bl[row][c8] = *(const uint4*)&B[(size_t)(n0 + row) * K + kt + c8];
        }
        __syncthreads();
        #pragma unroll
        for (int kk = 0; kk < 2; kk++) {
            v8s a[4], bfr[4];
            int ko = kk * 32 + (lane >> 4) * 8;
            #pragma unroll
            for (int mi = 0; mi < 4; mi++)
                a[mi] = *(const v8s*)&Al[wm * 64 + mi * 16 + (lane & 15)][ko];
            #pragma unroll
            for (int ni = 0; ni < 4; ni++)
                bfr[ni] = *(const v8s*)&Bl[wn * 64 + ni * 16 + (lane & 15)][ko];
            #pragma unroll
            for (int mi = 0; mi < 4; mi++)
                #pragma unroll
                for (int ni = 0; ni < 4; ni++)
                    acc[mi][ni] = __builtin_amdgcn_mfma_f32_16x16x32_bf16(a[mi], bfr[ni], acc[mi][ni], 0, 0, 0);
        }
    }
    int col = lane & 15, rbase = (lane >> 4) * 4;
    #pragma unroll
    for (int mi = 0; mi < 4; mi++)
        #pragma unroll
        for (int ni = 0; ni < 4; ni++)
            #pragma unroll
            for (int r = 0; r < 4; r++) {
                int m = m0 + wm * 64 + mi * 16 + rbase + r;
                int v = n0 + wn * 64 + ni * 16 + col;
                C[(size_t)m * N + v] = acc[mi][ni][r];
            }
}

// fused triple GEMM in one launch
__global__ __launch_bounds__(256) void k_gemm3(
        const ushort* __restrict__ imgbf, const ushort* __restrict__ wctxbf,
        const ushort* __restrict__ wimgbf, const float* __restrict__ embed,
        const int* __restrict__ toks, const ushort* __restrict__ wmixLbf,
        ushort* __restrict__ imgEbf, float* __restrict__ proj,
        float* __restrict__ embM) {
    __shared__ ushort Al[128][72];
    __shared__ ushort Bl[128][72];
    int bid = blockIdx.x;
    const ushort* A; const ushort* B; int mode, K, N, n0, m0;
    if (bid < 52)      { mode = 0; A = imgbf; B = wctxbf;  K = 2048; N = 512; n0 = (bid & 3) * 128; m0 = (bid >> 2) * 128; }
    else if (bid < 65) { mode = 1; A = imgbf; B = wimgbf;  K = 2048; N = 128; n0 = 0;               m0 = (bid - 52) * 128; }
    else { int e = bid - 65; mode = 2; A = nullptr; B = wmixLbf; K = 512; N = 512; n0 = (e & 3) * 128; m0 = (e >> 2) * 128; }
    int tid = threadIdx.x, lane = tid & 63, wid = tid >> 6;
    int wm = wid >> 1, wn = wid & 1;
    v4f acc[4][4] = {};
    for (int kt = 0; kt < K; kt += 64) {
        __syncthreads();
        #pragma unroll
        for (int i = 0; i < 4; i++) {
            int idx = i * 256 + tid;
            int row = idx >> 3, c8 = (idx & 7) * 8;
            if (mode == 2) {
                int rowg = m0 + row;
                int tok = toks[(rowg & 31) * 64 + (rowg >> 5)];
                uint4 oa = {0, 0, 0, 0};
                if (tok != 0) {
                    const float* pa = embed + (size_t)tok * 512 + kt + c8;
                    float4 a0 = *(const float4*)pa, a1 = *(const float4*)(pa + 4);
                    oa.x = pkf(a0.x, a0.y); oa.y = pkf(a0.z, a0.w);
                    oa.z = pkf(a1.x, a1.y); oa.w = pkf(a1.z, a1.w);
                }
                *(uint4*)&Al[row][c8] = oa;
            } else {
                *(uint4*)&Al[row][c8] = *(const uint4*)&A[(size_t)(m0 + row) * K + kt + c8];
            }
            *(uint4*)&Bl[row][c8] = *(const uint4*)&B[(size_t)(n0 + row) * K + kt + c8];
        }
        __syncthreads();
        #pragma unroll
        for (int kk = 0; kk < 2; kk++) {
            v8s a[4], bfr[4];
            int ko = kk * 32 + (lane >> 4) * 8;
            #pragma unroll
            for (int mi = 0; mi < 4; mi++)
                a[mi] = *(const v8s*)&Al[wm * 64 + mi * 16 + (lane & 15)][ko];
            #pragma unroll
            for (int ni = 0; ni < 4; ni++)
                bfr[ni] = *(const v8s*)&Bl[wn * 64 + ni * 16 + (lane & 15)][ko];
            #pragma unroll
            for (int mi = 0; mi < 4; mi++)
                #pragma unroll
                for (int ni = 0; ni < 4; ni++)
                    acc[mi][ni] = __builtin_amdgcn_mfma_f32_16x16x32_bf16(a[mi], bfr[ni], acc[mi][ni], 0, 0, 0);
        }
    }
    int col = lane & 15, rbase = (lane >> 4) * 4;
    #pragma unroll
    for (int mi = 0; mi < 4; mi++)
        #pragma unroll
        for (int ni = 0; ni < 4; ni++)
            #pragma unroll
            for (int r = 0; r < 4; r++) {
                int m = m0 + wm * 64 + mi * 16 + rbase + r;
                int v = n0 + wn * 64 + ni * 16 + col;
                if (mode == 0)      imgEbf[(size_t)m * 512 + v] = f2bf(acc[mi][ni][r]);
                else if (mode == 1) proj[(size_t)m * 128 + v] = acc[mi][ni][r];
                else                embM[(size_t)m * 512 + v] = acc[mi][ni][r];
            }
}

__global__ __launch_bounds__(256) void k_gmean(const float* __restrict__ img,
                                               float* __restrict__ g) {
    int b = blockIdx.x;
    for (int d = threadIdx.x; d < 2048; d += 256) {
        float s = 0.f;
        for (int ss = 0; ss < 49; ss++) s += img[((size_t)(b * 49 + ss)) * 2048 + d];
        g[b * 2048 + d] = s * (1.f / 49.f);
    }
}

__global__ __launch_bounds__(256) void k_h0c0(const float* __restrict__ g,
        const float* __restrict__ Wh0, const float* __restrict__ bh0,
        const float* __restrict__ Wc0, const float* __restrict__ bc0,
        float* __restrict__ h0, float* __restrict__ c0) {
    int b = blockIdx.x >> 1, m = blockIdx.x & 1;
    __shared__ float gs[2048];
    for (int d = threadIdx.x; d < 2048; d += 256) gs[d] = g[b * 2048 + d];
    __syncthreads();
    const float* W = m ? Wc0 : Wh0;
    const float* bb = m ? bc0 : bh0;
    float* out = m ? c0 : h0;
    for (int r = threadIdx.x; r < 512; r += 256) {
        float acc = 0.f;
        const float* wr = W + (size_t)r * 2048;
        for (int d = 0; d < 2048; d += 4) {
            float4 w = *(const float4*)(wr + d);
            acc += w.x * gs[d] + w.y * gs[d + 1] + w.z * gs[d + 2] + w.w * gs[d + 3];
        }
        out[b * 512 + r] = ftanh(acc + bb[r]) * 0.5f;
    }
}

// ---------------- persistent kernel: gates + attn + head roles ----------------

__device__ __forceinline__ void waitflags(unsigned* FLG, int base, int stride,
                                          int n, unsigned tgt) {
    if (threadIdx.x < 64) {
        bool done;
        do {
            unsigned v = tgt;
            if ((int)threadIdx.x < n)
                v = __hip_atomic_load(FLG + (base + (int)threadIdx.x * stride) * 16,
                                      __ATOMIC_RELAXED, __HIP_MEMORY_SCOPE_AGENT);
            done = __all((int)(v >= tgt));
            if (!done) __builtin_amdgcn_s_sleep(1);
        } while (!done);
    }
    __syncthreads();
}

// wait all 128 gates flags >= tgt (sleep count = compile-time constant)
template <int SLP>
__device__ __forceinline__ void waitgates(unsigned* FLG, unsigned tgt) {
    if (threadIdx.x < 64) {
        bool done;
        do {
            unsigned v0 = __hip_atomic_load(FLG + threadIdx.x * 16,
                            __ATOMIC_RELAXED, __HIP_MEMORY_SCOPE_AGENT);
            unsigned v1 = __hip_atomic_load(FLG + (threadIdx.x + 64) * 16,
                            __ATOMIC_RELAXED, __HIP_MEMORY_SCOPE_AGENT);
            done = __all((int)(v0 >= tgt && v1 >= tgt));
            if (!done) __builtin_amdgcn_s_sleep(SLP);
        } while (!done);
    }
    __syncthreads();
}

union SMem {
    struct {                       // gates role (blocks 0..127)
        ushort wh[64][520];
        ushort wi[64][520];
        ushort hsb[16][520];
        float gtmp[4][16][16];
        ushort h2s[16][8];
    } g;                           // ~154.1 KB
    struct {                       // attention role (blocks 128..159)
        float imgem[49][512];
        float projl[49][128];
        float hb[512];
        float ebs[512];
        float php[8][128];
        float ph[128];
        float scp[64][16];
        float wsm[64];
        float xps[2][512];
        float wred[8][2];
        float bc[2];
    } a;                           // ~142.5 KB
    struct {                       // head staging (any role post-loop, blocks 160+)
        ushort Al[256][72];
        ushort Bl[128][72];
    } h;                           // 55.3 KB
};

// one 256x128 head tile at (m0, n0); 1024 threads, 8 compute waves
__device__ __forceinline__ void head_tile(SMem& sm, const ushort* __restrict__ h2bf,
        const ushort* __restrict__ Wbf, float* __restrict__ out, int m0, int n0) {
    int tid = threadIdx.x, lane = tid & 63, wid = tid >> 6;
    int wm = wid >> 1, wn = wid & 1;
    v4f acc[4][4] = {};
    for (int kt = 0; kt < 512; kt += 64) {
        __syncthreads();
        #pragma unroll
        for (int i = 0; i < 2; i++) {   // A: 2048 uint4 over 1024 thr
            int idx = i * 1024 + tid;
            int row = idx >> 3, c8 = (idx & 7) * 8;
            const ull* p = (const ull*)&h2bf[(size_t)(m0 + row) * 512 + kt + c8];
            ull v0 = agld(p), v1 = agld(p + 1);
            *(ull*)&sm.h.Al[row][c8] = v0;
            *(ull*)&sm.h.Al[row][c8 + 4] = v1;
        }
        {   // B: 1024 uint4 over 1024 thr
            int row = tid >> 3, c8 = (tid & 7) * 8;
            *(uint4*)&sm.h.Bl[row][c8] = *(const uint4*)&Wbf[(size_t)(n0 + row) * 512 + kt + c8];
        }
        __syncthreads();
        if (wid < 8) {
            #pragma unroll
            for (int kk = 0; kk < 2; kk++) {
                v8s a[4], bfr[4];
                int ko = kk * 32 + (lane >> 4) * 8;
                #pragma unroll
                for (int mi = 0; mi < 4; mi++)
                    a[mi] = *(const v8s*)&sm.h.Al[wm * 64 + mi * 16 + (lane & 15)][ko];
                #pragma unroll
                for (int ni = 0; ni < 4; ni++)
                    bfr[ni] = *(const v8s*)&sm.h.Bl[wn * 64 + ni * 16 + (lane & 15)][ko];
                #pragma unroll
                for (int mi = 0; mi < 4; mi++)
                    #pragma unroll
                    for (int ni = 0; ni < 4; ni++)
                        acc[mi][ni] = __builtin_amdgcn_mfma_f32_16x16x32_bf16(a[mi], bfr[ni], acc[mi][ni], 0, 0, 0);
            }
        }
    }
    if (wid < 8) {
        int col = lane & 15, rbase = (lane >> 4) * 4;
        #pragma unroll
        for (int mi = 0; mi < 4; mi++)
            #pragma unroll
            for (int ni = 0; ni < 4; ni++)
                #pragma unroll
                for (int r = 0; r < 4; r++) {
                    int m = m0 + wm * 64 + mi * 16 + rbase + r;
                    int v = n0 + wn * 64 + ni * 16 + col;
                    int b = m & 31, t = m >> 5;
                    out[((size_t)(b * 64 + t)) * 32000 + v] = acc[mi][ni][r];
                }
    }
}

__global__ __launch_bounds__(1024, 1) void k_persist(
        const int* __restrict__ toks, const float* __restrict__ embed,
        const float* __restrict__ lng, const float* __restrict__ lnb,
        const float* __restrict__ bih, const float* __restrict__ bhh,
        const float* __restrict__ wsc, const ushort* __restrict__ whidbf,
        const ushort* __restrict__ whhbf, const ushort* __restrict__ wihbf,
        const float* __restrict__ proj, const float* __restrict__ imgEM,
        const float* __restrict__ embM, float* __restrict__ H,
        const float* __restrict__ C0, float* __restrict__ XN,
        unsigned* __restrict__ FLG, ushort* __restrict__ h2bf,
        const ushort* __restrict__ Wbf, float* __restrict__ out) {
    __shared__ SMem sm;
    __shared__ unsigned sh_w;
    int blk = blockIdx.x, tid = threadIdx.x;

    if (blk < 128) {
        // ---------------- gates role (R13-proven) ----------------
        int jc = blk >> 2, bg = blk & 3, b0 = bg * 8;
        int wid = tid >> 6, lane = tid & 63;
        int gate = wid & 3;
        for (int i = tid; i < 4096; i += 1024) {
            int rr = i >> 6, c8 = (i & 63) * 8;
            size_t R = (size_t)((rr >> 4) * 512 + jc * 16 + (rr & 15)) * 512 + c8;
            *(uint4*)&sm.g.wh[rr][c8] = *(const uint4*)&whhbf[R];
            *(uint4*)&sm.g.wi[rr][c8] = *(const uint4*)&wihbf[R];
        }
        for (int i = tid; i < 2080; i += 1024) ((ull*)sm.g.hsb)[i] = 0;
        float c_reg = 0.f, bs0 = 0.f, bs1 = 0.f, bs2 = 0.f, bs3 = 0.f;
        if (tid < 128) {
            int jl = tid >> 3, bb = tid & 7;
            int j = jc * 16 + jl;
            c_reg = C0[(b0 + bb) * 512 + j];
            bs0 = bih[j] + bhh[j];
            bs1 = bih[512 + j] + bhh[512 + j];
            bs2 = bih[1024 + j] + bhh[1024 + j];
            bs3 = bih[1536 + j] + bhh[1536 + j];
        }
        __syncthreads();

        for (int t = 0; t < NT; t++) {
            waitflags(FLG, bg, 4, 32, (unsigned)t);
            {   // stage h -> hsb bf16 (rows 0..7)
                const float* Hb = H + (t & 1) * 16384 + b0 * 512;
                if (tid < 512) {
                    int bb = tid >> 6, c8 = (tid & 63) * 8;
                    const ull* p = (const ull*)(Hb + bb * 512 + c8);
                    uint4 o = { pk2(agld(p)), pk2(agld(p + 1)),
                                pk2(agld(p + 2)), pk2(agld(p + 3)) };
                    *(uint4*)&sm.g.hsb[bb][c8] = o;
                }
            }
            __syncthreads();
            v4f acc = {};
            if (wid < 4) {
                #pragma unroll
                for (int ks = 0; ks < 16; ks++) {
                    int ko = ks * 32 + (lane >> 4) * 8;
                    v8s a = *(const v8s*)&sm.g.hsb[lane & 15][ko];
                    v8s b = *(const v8s*)&sm.g.wh[gate * 16 + (lane & 15)][ko];
                    acc = __builtin_amdgcn_mfma_f32_16x16x32_bf16(a, b, acc, 0, 0, 0);
                }
            }
            waitflags(FLG, 128 + b0, 1, 8, (unsigned)(t + 1));
            {   // stage xn -> hsb bf16
                const float* Xb = XN + b0 * 512;
                if (tid < 512) {
                    int bb = tid >> 6, c8 = (tid & 63) * 8;
                    const ull* p = (const ull*)(Xb + bb * 512 + c8);
                    uint4 o = { pk2(agld(p)), pk2(agld(p + 1)),
                                pk2(agld(p + 2)), pk2(agld(p + 3)) };
                    *(uint4*)&sm.g.hsb[bb][c8] = o;
                }
            }
            __syncthreads();
            if (wid < 4) {
                #pragma unroll
                for (int ks = 0; ks < 16; ks++) {
                    int ko = ks * 32 + (lane >> 4) * 8;
                    v8s a = *(const v8s*)&sm.g.hsb[lane & 15][ko];
                    v8s b = *(const v8s*)&sm.g.wi[gate * 16 + (lane & 15)][ko];
                    acc = __builtin_amdgcn_mfma_f32_16x16x32_bf16(a, b, acc, 0, 0, 0);
                }
                #pragma unroll
                for (int q = 0; q < 4; q++)
                    sm.g.gtmp[gate][lane & 15][(lane >> 4) * 4 + q] = acc[q];
            }
            __syncthreads();
            if (tid < 128) {
                int jl = tid >> 3, bb = tid & 7;
                float vi = sm.g.gtmp[0][jl][bb] + bs0;
                float vf = sm.g.gtmp[1][jl][bb] + bs1;
                float vg = sm.g.gtmp[2][jl][bb] + bs2;
                float vo = sm.g.gtmp[3][jl][bb] + bs3;
                float c2 = fsig(vf) * c_reg + fsig(vi) * ftanh(vg);
                float h2 = fsig(vo) * ftanh(c2);
                c_reg = c2;
                int bglob = b0 + bb, j = jc * 16 + jl;
                __hip_atomic_store((unsigned*)&H[((t + 1) & 1) * 16384 + bglob * 512 + j],
                                   __float_as_uint(h2), __ATOMIC_RELAXED, __HIP_MEMORY_SCOPE_AGENT);
                sm.g.h2s[jl][bb] = f2bf(h2);
            }
            __syncthreads();
            if (tid < 64) {
                int jlp = tid >> 3, bb = tid & 7;
                unsigned pk = (unsigned)sm.g.h2s[2 * jlp][bb]
                            | ((unsigned)sm.g.h2s[2 * jlp + 1][bb] << 16);
                int bglob = b0 + bb, j = jc * 16 + 2 * jlp;
                __hip_atomic_store((unsigned*)&h2bf[(size_t)(t * 32 + bglob) * 512 + j],
                                   pk, __ATOMIC_RELAXED, __HIP_MEMORY_SCOPE_AGENT);
            }
            __syncthreads();
            if (tid == 0)
                __hip_atomic_store(FLG + blk * 16, (unsigned)(t + 1),
                                   __ATOMIC_RELAXED, __HIP_MEMORY_SCOPE_AGENT);
        }
    } else if (blk < 160) {
        // ---------------- attention role (R13-proven) ----------------
        int b = blk - 128, bgb = b >> 3;
        for (int i = tid; i < 49 * 512; i += 1024)
            sm.a.imgem[i >> 9][i & 511] = imgEM[(size_t)b * 49 * 512 + i];
        for (int i = tid; i < 49 * 128; i += 1024)
            sm.a.projl[i >> 7][i & 127] = proj[(size_t)b * 49 * 128 + i];
        __syncthreads();
        for (int t = 0; t < NT; t++) {
            waitflags(FLG, bgb, 4, 32, (unsigned)t);
            int tok = toks[b * 64 + t];
            if (tid < 256) {
                ull v = agld((const ull*)(H + (t & 1) * 16384) + b * 256 + tid);
                *(ull*)&sm.a.hb[tid * 2] = v;
            } else if (tid < 768) {
                int k = tid - 256;
                sm.a.ebs[k] = (tok == 0) ? 0.f : embed[(size_t)tok * 512 + k];
            }
            __syncthreads();
            {   // ph partials (whid from L2, bf16)
                int a = tid & 127, kq = tid >> 7;
                const ushort* wr2 = whidbf + (size_t)a * 512 + kq * 64;
                const float* hp = sm.a.hb + kq * 64;
                float p = 0.f;
                #pragma unroll
                for (int k = 0; k < 64; k += 8) {
                    uint4 q = *(const uint4*)(wr2 + k);
                    float4 ha = *(const float4*)(hp + k);
                    float4 hb4 = *(const float4*)(hp + k + 4);
                    p += bf_lo(q.x)*ha.x + bf_hi(q.x)*ha.y + bf_lo(q.y)*ha.z + bf_hi(q.y)*ha.w
                       + bf_lo(q.z)*hb4.x + bf_hi(q.z)*hb4.y + bf_lo(q.w)*hb4.z + bf_hi(q.w)*hb4.w;
                }
                sm.a.php[kq][a] = p;
            }
            __syncthreads();
            if (tid < 128) {
                float p = 0.f;
                #pragma unroll
                for (int kq = 0; kq < 8; kq++) p += sm.a.php[kq][tid];
                sm.a.ph[tid] = p;
            }
            __syncthreads();
            {   // score partials (proj from LDS)
                int s = tid >> 4, aq = tid & 15;
                float p = 0.f;
                if (s < 49) {
                    const float* pr = &sm.a.projl[s][aq * 8];
                    #pragma unroll
                    for (int a = 0; a < 8; a++)
                        p += ftanh(pr[a] + sm.a.ph[aq * 8 + a]) * wsc[aq * 8 + a];
                }
                sm.a.scp[s][aq] = p;
            }
            __syncthreads();
            if (tid < 64) {
                float v = 0.f;
                #pragma unroll
                for (int q = 0; q < 16; q++) v += sm.a.scp[tid][q];
                if (tid >= 49) v = -1e30f;
                float m = v;
                for (int o = 32; o > 0; o >>= 1) m = fmaxf(m, __shfl_xor(m, o));
                float e = (tid < 49) ? __expf(v - m) : 0.f;
                float su = e;
                for (int o = 32; o > 0; o >>= 1) su += __shfl_xor(su, o);
                sm.a.wsm[tid] = e / su;
            }
            __syncthreads();
            {   // x = embM + sum_s w_s imgEM (imgem from LDS)
                int e = tid & 511, sh = tid >> 9;
                float xp = 0.f;
                if (sh == 0) xp = embM[(size_t)(t * 32 + b) * 512 + e];
                int s0 = sh * 25, s1 = sh ? 49 : 25;
                for (int s = s0; s < s1; s++)
                    xp += sm.a.wsm[s] * sm.a.imgem[s][e];
                sm.a.xps[sh][e] = xp;
            }
            __syncthreads();
            if (tid < 512) {
                float x = fmaxf(sm.a.xps[0][tid] + sm.a.xps[1][tid], 0.f);
                float s = x, s2 = x * x;
                for (int o = 32; o > 0; o >>= 1) { s += __shfl_xor(s, o); s2 += __shfl_xor(s2, o); }
                if ((tid & 63) == 0) { sm.a.wred[tid >> 6][0] = s; sm.a.wred[tid >> 6][1] = s2; }
            }
            __syncthreads();
            if (tid == 0) {
                float s = 0.f, s2 = 0.f;
                #pragma unroll
                for (int w = 0; w < 8; w++) { s += sm.a.wred[w][0]; s2 += sm.a.wred[w][1]; }
                float mu = s * (1.f / 512.f);
                float var = s2 * (1.f / 512.f) - mu * mu;
                sm.a.bc[0] = mu; sm.a.bc[1] = rsqrtf(var + 1e-5f);
            }
            __syncthreads();
            if (tid < 512) {
                float x = fmaxf(sm.a.xps[0][tid] + sm.a.xps[1][tid], 0.f);
                float xn = (x - sm.a.bc[0]) * sm.a.bc[1] * lng[tid] + lnb[tid] + sm.a.ebs[tid];
                __hip_atomic_store((unsigned*)&XN[b * 512 + tid], __float_as_uint(xn),
                                   __ATOMIC_RELAXED, __HIP_MEMORY_SCOPE_AGENT);
            }
            __syncthreads();
            if (tid == 0)
                __hip_atomic_store(FLG + (128 + b) * 16, (unsigned)(t + 1),
                                   __ATOMIC_RELAXED, __HIP_MEMORY_SCOPE_AGENT);
        }
    } else {
        // ---------------- head role (blocks 160..255): static mt 0..6 ----------------
        int hb = blk - 160;
        unsigned have = 0;
        for (int w = hb; w < 1750; w += 96) {
            int mt = w / 250, nt = w % 250;
            unsigned need = (unsigned)(mt * 8 + 8);
            if (have < need) { waitgates<8>(FLG, need); have = need; }
            head_tile(sm, h2bf, Wbf, out, mt * 256, nt * 128);
        }
    }

    // ---------------- dynamic tail pool: mt=7 tiles on ALL blocks ----------------
    waitgates<2>(FLG, (unsigned)NT);
    for (;;) {
        if (tid == 0)
            sh_w = __hip_atomic_fetch_add(FLG + 8, 1u, __ATOMIC_RELAXED,
                                          __HIP_MEMORY_SCOPE_AGENT);
        __syncthreads();
        unsigned w = sh_w;
        __syncthreads();
        if (w >= 250u) break;
        head_tile(sm, h2bf, Wbf, out, 7 * 256, (int)w * 128);
    }
}

// ---------------- launch ----------------
extern "C" void kernel_launch(void* const* d_in, const int* in_sizes, int n_in,
                              void* d_out, int out_size, void* d_ws, size_t ws_size,
                              hipStream_t stream) {
    const float* img    = (const float*)d_in[0];
    const int*   toks   = (const int*)d_in[1];
    const float* embed  = (const float*)d_in[2];
    const float* W_ctx  = (const float*)d_in[3];
    const float* W_mix  = (const float*)d_in[4];
    const float* ln_g   = (const float*)d_in[5];
    const float* ln_b   = (const float*)d_in[6];
    const float* W_ih   = (const float*)d_in[7];
    const float* W_hh   = (const float*)d_in[8];
    const float* b_ih   = (const float*)d_in[9];
    const float* b_hh   = (const float*)d_in[10];
    const float* W_head = (const float*)d_in[11];
    const float* W_img  = (const float*)d_in[12];
    const float* W_hid  = (const float*)d_in[13];
    const float* w_sc   = (const float*)d_in[14];
    const float* W_h0   = (const float*)d_in[15];
    const float* b_h0   = (const float*)d_in[16];
    const float* W_c0   = (const float*)d_in[17];
    const float* b_c0   = (const float*)d_in[18];

    float* out = (float*)d_out;
    float* ws  = (float*)d_ws;
    ushort* Wbf    = (ushort*)(ws + WS_WBF);
    ushort* h2bf   = (ushort*)(ws + WS_H2BF);
    float*  imgEM  = ws + WS_IMGEM;
    float*  proj   = ws + WS_PROJ;
    float*  embM   = ws + WS_EMBM;
    ushort* whhbf  = (ushort*)(ws + WS_WHHBF);
    ushort* wihbf  = (ushort*)(ws + WS_WIHBF);
    ushort* whidbf = (ushort*)(ws + WS_WHIDBF);
    float*  H      = ws + WS_H;
    float*  XN     = ws + WS_XN;
    float*  C      = ws + WS_C;
    unsigned* flg  = (unsigned*)(ws + WS_FLAGS);
    float*  g      = ws + WS_G;
    // prep scratch (inside Wbf slot; dead before W_head cast)
    ushort* imgbf   = (ushort*)(ws + PS_IMGBF);
    ushort* wctxbf  = (ushort*)(ws + PS_WCTXBF);
    ushort* wimgbf  = (ushort*)(ws + PS_WIMGBF);
    ushort* wmixRbf = (ushort*)(ws + PS_WMIXRBF);
    ushort* wmixLbf = (ushort*)(ws + PS_WMIXLBF);
    ushort* imgEbf  = (ushort*)(ws + PS_IMGEBF);

    // prep 1: all casts (img + 7 weights) + flag/counter zeroing, one launch
    k_castall<<<3617, 256, 0, stream>>>(img, W_ctx, W_img, W_mix, W_hh, W_ih, W_hid,
                                        imgbf, wctxbf, wimgbf, wmixRbf, wmixLbf,
                                        whhbf, wihbf, whidbf, flg);
    // prep 2: fused triple GEMM
    k_gemm3<<<129, 256, 0, stream>>>(imgbf, wctxbf, wimgbf, embed, toks, wmixLbf,
                                     imgEbf, proj, embM);
    // prep 3: imgEM = imgEbf @ wmixR^T
    k_gemm<<<dim3(4, 13), 256, 0, stream>>>(imgEbf, wmixRbf, imgEM, 512, 512);
    // prep 4: head weights (overwrites scratch region — after all scratch reads)
    k_castpad<<<8000, 256, 0, stream>>>(W_head, Wbf, 32000, 32000, 512, 512, 0);
    // prep 5: init state
    k_gmean<<<32, 256, 0, stream>>>(img, g);
    k_h0c0<<<64, 256, 0, stream>>>(g, W_h0, b_h0, W_c0, b_c0, H, C);

    // fused recurrence + streamed head GEMM + dynamic tail (256 blocks = 1/CU)
    k_persist<<<NBLK, 1024, 0, stream>>>(toks, embed, ln_g, ln_b, b_ih, b_hh, w_sc,
                                         whidbf, whhbf, wihbf, proj, imgEM, embM,
                                         H, C, XN, flg, h2bf, Wbf, out);
}

// Round 17
// 906.719 us; speedup vs baseline: 1.5386x; 1.0844x over previous
//
#include <hip/hip_runtime.h>

#define NV 32000
#define NT 64
#define NBLK 256u

typedef unsigned long long ull;
typedef unsigned short ushort;
typedef __attribute__((ext_vector_type(8))) short v8s;
typedef __attribute__((ext_vector_type(4))) float v4f;

// persistent ws layout (float offsets; ushort regions = count/2 floats)
#define WS_WBF     0          // ushort [32000][512]           -> 8192000
#define WS_H2BF    8192000    // ushort [2048][512]  (524288)  -> 8716288
#define WS_IMGEM   8716288    // f32 [1664][512]     (851968)  -> 9568256
#define WS_PROJ    9568256    // f32 [1664][128]     (212992)  -> 9781248
#define WS_EMBM    9781248    // f32 [2048][512]     (1048576) -> 10829824
#define WS_WHHBF   10829824   // ushort [2048][512]  (524288)  -> 11354112
#define WS_WIHBF   11354112   // ushort [2048][512]  (524288)  -> 11878400
#define WS_WHIDBF  11878400   // ushort [128][512]   (32768)   -> 11911168
#define WS_H       11911168   // f32 [2][32][512]    (32768)   -> 11943936
#define WS_XN      11943936   // f32 [32][512]       (16384)   -> 11960320
#define WS_C       11960320   // f32 [32][512]       (16384)   -> 11976704
#define WS_FLAGS   11976704   // 160 slots x 16 u32; slot0 word8 = tile ctr, word12 = cast ctr
#define WS_G       11979264   // f32 [32][2048]      (65536)   -> 12044800
// prep scratch (inside Wbf slot [0,8192000); dead before in-kernel Wbf cast)
#define PS_IMGBF   0          // ushort [1664][2048] (1703936) -> 1703936
#define PS_WCTXBF  1703936    // ushort [512][2048]  (524288)  -> 2228224
#define PS_WIMGBF  2228224    // ushort [128][2048]  (131072)  -> 2359296
#define PS_WMIXRBF 2359296    // ushort [512][512]   (131072)  -> 2490368
#define PS_WMIXLBF 2490368    // ushort [512][512]   (131072)  -> 2621440
#define PS_IMGEBF  3342336    // ushort [1664][512]  (425984)  -> 3768320

__device__ __forceinline__ float fsig(float x) {
    x = fminf(fmaxf(x, -30.f), 30.f);
    return 1.f / (1.f + __expf(-x));
}
__device__ __forceinline__ float ftanh(float x) {
    x = fminf(fmaxf(x, -15.f), 15.f);
    float e = __expf(2.f * x);
    return (e - 1.f) / (e + 1.f);
}
__device__ __forceinline__ unsigned short f2bf(float f) {
    union { float f; unsigned int u; } v; v.f = f;
    unsigned int u = v.u;
    return (unsigned short)((u + 0x7FFFu + ((u >> 16) & 1u)) >> 16);
}
__device__ __forceinline__ unsigned pkf(float x, float y) {
    return (unsigned)f2bf(x) | ((unsigned)f2bf(y) << 16);
}
__device__ __forceinline__ float bf_lo(unsigned u) { return __uint_as_float(u << 16); }
__device__ __forceinline__ float bf_hi(unsigned u) { return __uint_as_float(u & 0xffff0000u); }
__device__ __forceinline__ ull agld(const ull* p) {
    return __hip_atomic_load(p, __ATOMIC_RELAXED, __HIP_MEMORY_SCOPE_AGENT);
}
__device__ __forceinline__ unsigned pk2(ull v) {
    return (unsigned)f2bf(__uint_as_float((unsigned)v)) |
           ((unsigned)f2bf(__uint_as_float((unsigned)(v >> 32))) << 16);
}

// ---------------- prep kernels ----------------

__global__ __launch_bounds__(256) void k_castall(
        const float* __restrict__ img, const float* __restrict__ Wctx,
        const float* __restrict__ Wimg, const float* __restrict__ Wmix,
        const float* __restrict__ Whh, const float* __restrict__ Wih,
        const float* __restrict__ Whid,
        ushort* __restrict__ imgbf, ushort* __restrict__ wctxbf,
        ushort* __restrict__ wimgbf, ushort* __restrict__ wmixRbf,
        ushort* __restrict__ wmixLbf, ushort* __restrict__ whhbf,
        ushort* __restrict__ wihbf, ushort* __restrict__ whidbf,
        unsigned* __restrict__ flg) {
    int blk = blockIdx.x, tid = threadIdx.x;
    if (blk >= 3616) {                       // zero flag slots + counters
        for (int i = tid; i < 2560; i += 256) flg[i] = 0u;
        return;
    }
    const float* in; ushort* out; int R, K, ldi, off;
    if (blk < 1664)      { in = img;  out = imgbf;   R = 1568; K = 2048; ldi = 2048; off = 0; }
    else if (blk < 2176) { in = Wctx; out = wctxbf;  R = 512;  K = 2048; ldi = 2048; off = 0;   blk -= 1664; }
    else if (blk < 2304) { in = Wimg; out = wimgbf;  R = 128;  K = 2048; ldi = 2048; off = 0;   blk -= 2176; }
    else if (blk < 2432) { in = Wmix; out = wmixRbf; R = 512;  K = 512;  ldi = 1024; off = 512; blk -= 2304; }
    else if (blk < 2560) { in = Wmix; out = wmixLbf; R = 512;  K = 512;  ldi = 1024; off = 0;   blk -= 2432; }
    else if (blk < 3072) { in = Whh;  out = whhbf;   R = 2048; K = 512;  ldi = 512;  off = 0;   blk -= 2560; }
    else if (blk < 3584) { in = Wih;  out = wihbf;   R = 2048; K = 512;  ldi = 512;  off = 0;   blk -= 3072; }
    else                 { in = Whid; out = whidbf;  R = 128;  K = 512;  ldi = 512;  off = 0;   blk -= 3584; }
    size_t i = ((size_t)blk * 256 + tid) * 8;
    int r = (int)(i / K), k = (int)(i % K);
    uint4 o = {0, 0, 0, 0};
    if (r < R) {
        const float* p = in + (size_t)r * ldi + off + k;
        float4 a = *(const float4*)(p);
        float4 b = *(const float4*)(p + 4);
        o.x = pkf(a.x, a.y); o.y = pkf(a.z, a.w);
        o.z = pkf(b.x, b.y); o.w = pkf(b.z, b.w);
    }
    *(uint4*)(out + i) = o;
}

// generic bf16 GEMM, fp32 out
__global__ __launch_bounds__(256) void k_gemm(const ushort* __restrict__ A,
        const ushort* __restrict__ B, float* __restrict__ C, int N, int K) {
    __shared__ ushort Al[128][72];
    __shared__ ushort Bl[128][72];
    int n0 = blockIdx.x * 128, m0 = blockIdx.y * 128;
    int tid = threadIdx.x, lane = tid & 63, wid = tid >> 6;
    int wm = wid >> 1, wn = wid & 1;
    v4f acc[4][4] = {};
    for (int kt = 0; kt < K; kt += 64) {
        __syncthreads();
        #pragma unroll
        for (int i = 0; i < 4; i++) {
            int idx = i * 256 + tid;
            int row = idx >> 3, c8 = (idx & 7) * 8;
            *(uint4*)&Al[row][c8] = *(const uint4*)&A[(size_t)(m0 + row) * K + kt + c8];
            *(uint4*)&Bl[row][c8] = *(const uint4*)&B[(size_t)(n0 + row) * K + kt + c8];
        }
        __syncthreads();
        #pragma unroll
        for (int kk = 0; kk < 2; kk++) {
            v8s a[4], bfr[4];
            int ko = kk * 32 + (lane >> 4) * 8;
            #pragma unroll
            for (int mi = 0; mi < 4; mi++)
                a[mi] = *(const v8s*)&Al[wm * 64 + mi * 16 + (lane & 15)][ko];
            #pragma unroll
            for (int ni = 0; ni < 4; ni++)
                bfr[ni] = *(const v8s*)&Bl[wn * 64 + ni * 16 + (lane & 15)][ko];
            #pragma unroll
            for (int mi = 0; mi < 4; mi++)
                #pragma unroll
                for (int ni = 0; ni < 4; ni++)
                    acc[mi][ni] = __builtin_amdgcn_mfma_f32_16x16x32_bf16(a[mi], bfr[ni], acc[mi][ni], 0, 0, 0);
        }
    }
    int col = lane & 15, rbase = (lane >> 4) * 4;
    #pragma unroll
    for (int mi = 0; mi < 4; mi++)
        #pragma unroll
        for (int ni = 0; ni < 4; ni++)
            #pragma unroll
            for (int r = 0; r < 4; r++) {
                int m = m0 + wm * 64 + mi * 16 + rbase + r;
                int v = n0 + wn * 64 + ni * 16 + col;
                C[(size_t)m * N + v] = acc[mi][ni][r];
            }
}

// fused triple GEMM in one launch
__global__ __launch_bounds__(256) void k_gemm3(
        const ushort* __restrict__ imgbf, const ushort* __restrict__ wctxbf,
        const ushort* __restrict__ wimgbf, const float* __restrict__ embed,
        const int* __restrict__ toks, const ushort* __restrict__ wmixLbf,
        ushort* __restrict__ imgEbf, float* __restrict__ proj,
        float* __restrict__ embM) {
    __shared__ ushort Al[128][72];
    __shared__ ushort Bl[128][72];
    int bid = blockIdx.x;
    const ushort* A; const ushort* B; int mode, K, N, n0, m0;
    if (bid < 52)      { mode = 0; A = imgbf; B = wctxbf;  K = 2048; N = 512; n0 = (bid & 3) * 128; m0 = (bid >> 2) * 128; }
    else if (bid < 65) { mode = 1; A = imgbf; B = wimgbf;  K = 2048; N = 128; n0 = 0;               m0 = (bid - 52) * 128; }
    else { int e = bid - 65; mode = 2; A = nullptr; B = wmixLbf; K = 512; N = 512; n0 = (e & 3) * 128; m0 = (e >> 2) * 128; }
    int tid = threadIdx.x, lane = tid & 63, wid = tid >> 6;
    int wm = wid >> 1, wn = wid & 1;
    v4f acc[4][4] = {};
    for (int kt = 0; kt < K; kt += 64) {
        __syncthreads();
        #pragma unroll
        for (int i = 0; i < 4; i++) {
            int idx = i * 256 + tid;
            int row = idx >> 3, c8 = (idx & 7) * 8;
            if (mode == 2) {
                int rowg = m0 + row;
                int tok = toks[(rowg & 31) * 64 + (rowg >> 5)];
                uint4 oa = {0, 0, 0, 0};
                if (tok != 0) {
                    const float* pa = embed + (size_t)tok * 512 + kt + c8;
                    float4 a0 = *(const float4*)pa, a1 = *(const float4*)(pa + 4);
                    oa.x = pkf(a0.x, a0.y); oa.y = pkf(a0.z, a0.w);
                    oa.z = pkf(a1.x, a1.y); oa.w = pkf(a1.z, a1.w);
                }
                *(uint4*)&Al[row][c8] = oa;
            } else {
                *(uint4*)&Al[row][c8] = *(const uint4*)&A[(size_t)(m0 + row) * K + kt + c8];
            }
            *(uint4*)&Bl[row][c8] = *(const uint4*)&B[(size_t)(n0 + row) * K + kt + c8];
        }
        __syncthreads();
        #pragma unroll
        for (int kk = 0; kk < 2; kk++) {
            v8s a[4], bfr[4];
            int ko = kk * 32 + (lane >> 4) * 8;
            #pragma unroll
            for (int mi = 0; mi < 4; mi++)
                a[mi] = *(const v8s*)&Al[wm * 64 + mi * 16 + (lane & 15)][ko];
            #pragma unroll
            for (int ni = 0; ni < 4; ni++)
                bfr[ni] = *(const v8s*)&Bl[wn * 64 + ni * 16 + (lane & 15)][ko];
            #pragma unroll
            for (int mi = 0; mi < 4; mi++)
                #pragma unroll
                for (int ni = 0; ni < 4; ni++)
                    acc[mi][ni] = __builtin_amdgcn_mfma_f32_16x16x32_bf16(a[mi], bfr[ni], acc[mi][ni], 0, 0, 0);
        }
    }
    int col = lane & 15, rbase = (lane >> 4) * 4;
    #pragma unroll
    for (int mi = 0; mi < 4; mi++)
        #pragma unroll
        for (int ni = 0; ni < 4; ni++)
            #pragma unroll
            for (int r = 0; r < 4; r++) {
                int m = m0 + wm * 64 + mi * 16 + rbase + r;
                int v = n0 + wn * 64 + ni * 16 + col;
                if (mode == 0)      imgEbf[(size_t)m * 512 + v] = f2bf(acc[mi][ni][r]);
                else if (mode == 1) proj[(size_t)m * 128 + v] = acc[mi][ni][r];
                else                embM[(size_t)m * 512 + v] = acc[mi][ni][r];
            }
}

__global__ __launch_bounds__(256) void k_gmean(const float* __restrict__ img,
                                               float* __restrict__ g) {
    int b = blockIdx.x;
    for (int d = threadIdx.x; d < 2048; d += 256) {
        float s = 0.f;
        for (int ss = 0; ss < 49; ss++) s += img[((size_t)(b * 49 + ss)) * 2048 + d];
        g[b * 2048 + d] = s * (1.f / 49.f);
    }
}

// grid 128: (b, m, rhalf) — one output row per thread
__global__ __launch_bounds__(256) void k_h0c0(const float* __restrict__ g,
        const float* __restrict__ Wh0, const float* __restrict__ bh0,
        const float* __restrict__ Wc0, const float* __restrict__ bc0,
        float* __restrict__ h0, float* __restrict__ c0) {
    int b = blockIdx.x >> 2, m = (blockIdx.x >> 1) & 1, rh = blockIdx.x & 1;
    __shared__ float gs[2048];
    for (int d = threadIdx.x; d < 2048; d += 256) gs[d] = g[b * 2048 + d];
    __syncthreads();
    const float* W = m ? Wc0 : Wh0;
    const float* bb = m ? bc0 : bh0;
    float* out = m ? c0 : h0;
    int r = rh * 256 + threadIdx.x;
    float acc = 0.f;
    const float* wr = W + (size_t)r * 2048;
    for (int d = 0; d < 2048; d += 4) {
        float4 w = *(const float4*)(wr + d);
        acc += w.x * gs[d] + w.y * gs[d + 1] + w.z * gs[d + 2] + w.w * gs[d + 3];
    }
    out[b * 512 + r] = ftanh(acc + bb[r]) * 0.5f;
}

// ---------------- persistent kernel: gates + attn + head roles ----------------

__device__ __forceinline__ void waitflags(unsigned* FLG, int base, int stride,
                                          int n, unsigned tgt) {
    if (threadIdx.x < 64) {
        bool done;
        do {
            unsigned v = tgt;
            if ((int)threadIdx.x < n)
                v = __hip_atomic_load(FLG + (base + (int)threadIdx.x * stride) * 16,
                                      __ATOMIC_RELAXED, __HIP_MEMORY_SCOPE_AGENT);
            done = __all((int)(v >= tgt));
            if (!done) __builtin_amdgcn_s_sleep(1);
        } while (!done);
    }
    __syncthreads();
}

template <int SLP>
__device__ __forceinline__ void waitgates(unsigned* FLG, unsigned tgt) {
    if (threadIdx.x < 64) {
        bool done;
        do {
            unsigned v0 = __hip_atomic_load(FLG + threadIdx.x * 16,
                            __ATOMIC_RELAXED, __HIP_MEMORY_SCOPE_AGENT);
            unsigned v1 = __hip_atomic_load(FLG + (threadIdx.x + 64) * 16,
                            __ATOMIC_RELAXED, __HIP_MEMORY_SCOPE_AGENT);
            done = __all((int)(v0 >= tgt && v1 >= tgt));
            if (!done) __builtin_amdgcn_s_sleep(SLP);
        } while (!done);
    }
    __syncthreads();
}

// wait until all 96 head blocks finished the in-kernel Wbf cast
__device__ __forceinline__ void waitcast(unsigned* FLG) {
    if (threadIdx.x == 0) {
        while (__hip_atomic_load(FLG + 12, __ATOMIC_RELAXED, __HIP_MEMORY_SCOPE_AGENT) < 96u)
            __builtin_amdgcn_s_sleep(4);
    }
    __syncthreads();
}

union SMem {
    struct {                       // gates role (blocks 0..127)
        ushort wh[64][520];
        ushort wi[64][520];
        ushort hsb[16][520];
        float gtmp[4][16][16];
        ushort h2s[16][8];
    } g;                           // ~154.1 KB
    struct {                       // attention role (blocks 128..159)
        float imgem[49][512];
        float projl[49][128];
        float hb[512];
        float ebs[512];
        float php[8][128];
        float ph[128];
        float scp[64][16];
        float wsm[64];
        float xps[2][512];
        float wred[8][2];
        float bc[2];
    } a;                           // ~142.5 KB
    struct {                       // head staging (any role post-loop, blocks 160+)
        ushort Al[256][72];
        ushort Bl[128][72];
    } h;                           // 55.3 KB
};

// one 256x128 head tile at (m0, n0); 1024 threads, 8 compute waves
__device__ __forceinline__ void head_tile(SMem& sm, const ushort* __restrict__ h2bf,
        const ushort* __restrict__ Wbf, float* __restrict__ out, int m0, int n0) {
    int tid = threadIdx.x, lane = tid & 63, wid = tid >> 6;
    int wm = wid >> 1, wn = wid & 1;
    v4f acc[4][4] = {};
    for (int kt = 0; kt < 512; kt += 64) {
        __syncthreads();
        #pragma unroll
        for (int i = 0; i < 2; i++) {   // A: 2048 uint4 over 1024 thr
            int idx = i * 1024 + tid;
            int row = idx >> 3, c8 = (idx & 7) * 8;
            const ull* p = (const ull*)&h2bf[(size_t)(m0 + row) * 512 + kt + c8];
            ull v0 = agld(p), v1 = agld(p + 1);
            *(ull*)&sm.h.Al[row][c8] = v0;
            *(ull*)&sm.h.Al[row][c8 + 4] = v1;
        }
        {   // B: 1024 uint4 over 1024 thr
            int row = tid >> 3, c8 = (tid & 7) * 8;
            *(uint4*)&sm.h.Bl[row][c8] = *(const uint4*)&Wbf[(size_t)(n0 + row) * 512 + kt + c8];
        }
        __syncthreads();
        if (wid < 8) {
            #pragma unroll
            for (int kk = 0; kk < 2; kk++) {
                v8s a[4], bfr[4];
                int ko = kk * 32 + (lane >> 4) * 8;
                #pragma unroll
                for (int mi = 0; mi < 4; mi++)
                    a[mi] = *(const v8s*)&sm.h.Al[wm * 64 + mi * 16 + (lane & 15)][ko];
                #pragma unroll
                for (int ni = 0; ni < 4; ni++)
                    bfr[ni] = *(const v8s*)&sm.h.Bl[wn * 64 + ni * 16 + (lane & 15)][ko];
                #pragma unroll
                for (int mi = 0; mi < 4; mi++)
                    #pragma unroll
                    for (int ni = 0; ni < 4; ni++)
                        acc[mi][ni] = __builtin_amdgcn_mfma_f32_16x16x32_bf16(a[mi], bfr[ni], acc[mi][ni], 0, 0, 0);
            }
        }
    }
    if (wid < 8) {
        int col = lane & 15, rbase = (lane >> 4) * 4;
        #pragma unroll
        for (int mi = 0; mi < 4; mi++)
            #pragma unroll
            for (int ni = 0; ni < 4; ni++)
                #pragma unroll
                for (int r = 0; r < 4; r++) {
                    int m = m0 + wm * 64 + mi * 16 + rbase + r;
                    int v = n0 + wn * 64 + ni * 16 + col;
                    int b = m & 31, t = m >> 5;
                    out[((size_t)(b * 64 + t)) * 32000 + v] = acc[mi][ni][r];
                }
    }
}

__global__ __launch_bounds__(1024, 1) void k_persist(
        const int* __restrict__ toks, const float* __restrict__ embed,
        const float* __restrict__ lng, const float* __restrict__ lnb,
        const float* __restrict__ bih, const float* __restrict__ bhh,
        const float* __restrict__ wsc, const ushort* __restrict__ whidbf,
        const ushort* __restrict__ whhbf, const ushort* __restrict__ wihbf,
        const float* __restrict__ proj, const float* __restrict__ imgEM,
        const float* __restrict__ embM, float* __restrict__ H,
        const float* __restrict__ C0, float* __restrict__ XN,
        unsigned* __restrict__ FLG, ushort* __restrict__ h2bf,
        const float* __restrict__ W_head, ushort* __restrict__ Wbf,
        float* __restrict__ out) {
    __shared__ SMem sm;
    __shared__ unsigned sh_w;
    int blk = blockIdx.x, tid = threadIdx.x;

    if (blk < 128) {
        // ---------------- gates role (R13-proven) ----------------
        int jc = blk >> 2, bg = blk & 3, b0 = bg * 8;
        int wid = tid >> 6, lane = tid & 63;
        int gate = wid & 3;
        for (int i = tid; i < 4096; i += 1024) {
            int rr = i >> 6, c8 = (i & 63) * 8;
            size_t R = (size_t)((rr >> 4) * 512 + jc * 16 + (rr & 15)) * 512 + c8;
            *(uint4*)&sm.g.wh[rr][c8] = *(const uint4*)&whhbf[R];
            *(uint4*)&sm.g.wi[rr][c8] = *(const uint4*)&wihbf[R];
        }
        for (int i = tid; i < 2080; i += 1024) ((ull*)sm.g.hsb)[i] = 0;
        float c_reg = 0.f, bs0 = 0.f, bs1 = 0.f, bs2 = 0.f, bs3 = 0.f;
        if (tid < 128) {
            int jl = tid >> 3, bb = tid & 7;
            int j = jc * 16 + jl;
            c_reg = C0[(b0 + bb) * 512 + j];
            bs0 = bih[j] + bhh[j];
            bs1 = bih[512 + j] + bhh[512 + j];
            bs2 = bih[1024 + j] + bhh[1024 + j];
            bs3 = bih[1536 + j] + bhh[1536 + j];
        }
        __syncthreads();

        for (int t = 0; t < NT; t++) {
            waitflags(FLG, bg, 4, 32, (unsigned)t);
            {   // stage h -> hsb bf16 (rows 0..7)
                const float* Hb = H + (t & 1) * 16384 + b0 * 512;
                if (tid < 512) {
                    int bb = tid >> 6, c8 = (tid & 63) * 8;
                    const ull* p = (const ull*)(Hb + bb * 512 + c8);
                    uint4 o = { pk2(agld(p)), pk2(agld(p + 1)),
                                pk2(agld(p + 2)), pk2(agld(p + 3)) };
                    *(uint4*)&sm.g.hsb[bb][c8] = o;
                }
            }
            __syncthreads();
            v4f acc = {};
            if (wid < 4) {
                #pragma unroll
                for (int ks = 0; ks < 16; ks++) {
                    int ko = ks * 32 + (lane >> 4) * 8;
                    v8s a = *(const v8s*)&sm.g.hsb[lane & 15][ko];
                    v8s b = *(const v8s*)&sm.g.wh[gate * 16 + (lane & 15)][ko];
                    acc = __builtin_amdgcn_mfma_f32_16x16x32_bf16(a, b, acc, 0, 0, 0);
                }
            }
            waitflags(FLG, 128 + b0, 1, 8, (unsigned)(t + 1));
            {   // stage xn -> hsb bf16
                const float* Xb = XN + b0 * 512;
                if (tid < 512) {
                    int bb = tid >> 6, c8 = (tid & 63) * 8;
                    const ull* p = (const ull*)(Xb + bb * 512 + c8);
                    uint4 o = { pk2(agld(p)), pk2(agld(p + 1)),
                                pk2(agld(p + 2)), pk2(agld(p + 3)) };
                    *(uint4*)&sm.g.hsb[bb][c8] = o;
                }
            }
            __syncthreads();
            if (wid < 4) {
                #pragma unroll
                for (int ks = 0; ks < 16; ks++) {
                    int ko = ks * 32 + (lane >> 4) * 8;
                    v8s a = *(const v8s*)&sm.g.hsb[lane & 15][ko];
                    v8s b = *(const v8s*)&sm.g.wi[gate * 16 + (lane & 15)][ko];
                    acc = __builtin_amdgcn_mfma_f32_16x16x32_bf16(a, b, acc, 0, 0, 0);
                }
                #pragma unroll
                for (int q = 0; q < 4; q++)
                    sm.g.gtmp[gate][lane & 15][(lane >> 4) * 4 + q] = acc[q];
            }
            __syncthreads();
            if (tid < 128) {
                int jl = tid >> 3, bb = tid & 7;
                float vi = sm.g.gtmp[0][jl][bb] + bs0;
                float vf = sm.g.gtmp[1][jl][bb] + bs1;
                float vg = sm.g.gtmp[2][jl][bb] + bs2;
                float vo = sm.g.gtmp[3][jl][bb] + bs3;
                float c2 = fsig(vf) * c_reg + fsig(vi) * ftanh(vg);
                float h2 = fsig(vo) * ftanh(c2);
                c_reg = c2;
                int bglob = b0 + bb, j = jc * 16 + jl;
                __hip_atomic_store((unsigned*)&H[((t + 1) & 1) * 16384 + bglob * 512 + j],
                                   __float_as_uint(h2), __ATOMIC_RELAXED, __HIP_MEMORY_SCOPE_AGENT);
                sm.g.h2s[jl][bb] = f2bf(h2);
            }
            __syncthreads();
            if (tid < 64) {
                int jlp = tid >> 3, bb = tid & 7;
                unsigned pk = (unsigned)sm.g.h2s[2 * jlp][bb]
                            | ((unsigned)sm.g.h2s[2 * jlp + 1][bb] << 16);
                int bglob = b0 + bb, j = jc * 16 + 2 * jlp;
                __hip_atomic_store((unsigned*)&h2bf[(size_t)(t * 32 + bglob) * 512 + j],
                                   pk, __ATOMIC_RELAXED, __HIP_MEMORY_SCOPE_AGENT);
            }
            __syncthreads();
            if (tid == 0)
                __hip_atomic_store(FLG + blk * 16, (unsigned)(t + 1),
                                   __ATOMIC_RELAXED, __HIP_MEMORY_SCOPE_AGENT);
        }
    } else if (blk < 160) {
        // ---------------- attention role (R13-proven) ----------------
        int b = blk - 128, bgb = b >> 3;
        for (int i = tid; i < 49 * 512; i += 1024)
            sm.a.imgem[i >> 9][i & 511] = imgEM[(size_t)b * 49 * 512 + i];
        for (int i = tid; i < 49 * 128; i += 1024)
            sm.a.projl[i >> 7][i & 127] = proj[(size_t)b * 49 * 128 + i];
        __syncthreads();
        for (int t = 0; t < NT; t++) {
            waitflags(FLG, bgb, 4, 32, (unsigned)t);
            int tok = toks[b * 64 + t];
            if (tid < 256) {
                ull v = agld((const ull*)(H + (t & 1) * 16384) + b * 256 + tid);
                *(ull*)&sm.a.hb[tid * 2] = v;
            } else if (tid < 768) {
                int k = tid - 256;
                sm.a.ebs[k] = (tok == 0) ? 0.f : embed[(size_t)tok * 512 + k];
            }
            __syncthreads();
            {   // ph partials (whid from L2, bf16)
                int a = tid & 127, kq = tid >> 7;
                const ushort* wr2 = whidbf + (size_t)a * 512 + kq * 64;
                const float* hp = sm.a.hb + kq * 64;
                float p = 0.f;
                #pragma unroll
                for (int k = 0; k < 64; k += 8) {
                    uint4 q = *(const uint4*)(wr2 + k);
                    float4 ha = *(const float4*)(hp + k);
                    float4 hb4 = *(const float4*)(hp + k + 4);
                    p += bf_lo(q.x)*ha.x + bf_hi(q.x)*ha.y + bf_lo(q.y)*ha.z + bf_hi(q.y)*ha.w
                       + bf_lo(q.z)*hb4.x + bf_hi(q.z)*hb4.y + bf_lo(q.w)*hb4.z + bf_hi(q.w)*hb4.w;
                }
                sm.a.php[kq][a] = p;
            }
            __syncthreads();
            if (tid < 128) {
                float p = 0.f;
                #pragma unroll
                for (int kq = 0; kq < 8; kq++) p += sm.a.php[kq][tid];
                sm.a.ph[tid] = p;
            }
            __syncthreads();
            {   // score partials (proj from LDS)
                int s = tid >> 4, aq = tid & 15;
                float p = 0.f;
                if (s < 49) {
                    const float* pr = &sm.a.projl[s][aq * 8];
                    #pragma unroll
                    for (int a = 0; a < 8; a++)
                        p += ftanh(pr[a] + sm.a.ph[aq * 8 + a]) * wsc[aq * 8 + a];
                }
                sm.a.scp[s][aq] = p;
            }
            __syncthreads();
            if (tid < 64) {
                float v = 0.f;
                #pragma unroll
                for (int q = 0; q < 16; q++) v += sm.a.scp[tid][q];
                if (tid >= 49) v = -1e30f;
                float m = v;
                for (int o = 32; o > 0; o >>= 1) m = fmaxf(m, __shfl_xor(m, o));
                float e = (tid < 49) ? __expf(v - m) : 0.f;
                float su = e;
                for (int o = 32; o > 0; o >>= 1) su += __shfl_xor(su, o);
                sm.a.wsm[tid] = e / su;
            }
            __syncthreads();
            {   // x = embM + sum_s w_s imgEM (imgem from LDS)
                int e = tid & 511, sh = tid >> 9;
                float xp = 0.f;
                if (sh == 0) xp = embM[(size_t)(t * 32 + b) * 512 + e];
                int s0 = sh * 25, s1 = sh ? 49 : 25;
                for (int s = s0; s < s1; s++)
                    xp += sm.a.wsm[s] * sm.a.imgem[s][e];
                sm.a.xps[sh][e] = xp;
            }
            __syncthreads();
            if (tid < 512) {
                float x = fmaxf(sm.a.xps[0][tid] + sm.a.xps[1][tid], 0.f);
                float s = x, s2 = x * x;
                for (int o = 32; o > 0; o >>= 1) { s += __shfl_xor(s, o); s2 += __shfl_xor(s2, o); }
                if ((tid & 63) == 0) { sm.a.wred[tid >> 6][0] = s; sm.a.wred[tid >> 6][1] = s2; }
            }
            __syncthreads();
            if (tid == 0) {
                float s = 0.f, s2 = 0.f;
                #pragma unroll
                for (int w = 0; w < 8; w++) { s += sm.a.wred[w][0]; s2 += sm.a.wred[w][1]; }
                float mu = s * (1.f / 512.f);
                float var = s2 * (1.f / 512.f) - mu * mu;
                sm.a.bc[0] = mu; sm.a.bc[1] = rsqrtf(var + 1e-5f);
            }
            __syncthreads();
            if (tid < 512) {
                float x = fmaxf(sm.a.xps[0][tid] + sm.a.xps[1][tid], 0.f);
                float xn = (x - sm.a.bc[0]) * sm.a.bc[1] * lng[tid] + lnb[tid] + sm.a.ebs[tid];
                __hip_atomic_store((unsigned*)&XN[b * 512 + tid], __float_as_uint(xn),
                                   __ATOMIC_RELAXED, __HIP_MEMORY_SCOPE_AGENT);
            }
            __syncthreads();
            if (tid == 0)
                __hip_atomic_store(FLG + (128 + b) * 16, (unsigned)(t + 1),
                                   __ATOMIC_RELAXED, __HIP_MEMORY_SCOPE_AGENT);
        }
    } else {
        // ---------------- head role (blocks 160..255) ----------------
        int hb = blk - 160;
        // in-kernel W_head -> Wbf cast (agent-scope stores; consumers wait counter)
        {
            ull* wq = (ull*)Wbf;
            for (size_t i = (size_t)hb * 1024 + tid; i < 4096000; i += 98304) {
                const float* p = W_head + i * 4;
                float4 a = *(const float4*)p;
                ull v = (ull)pkf(a.x, a.y) | ((ull)pkf(a.z, a.w) << 32);
                __hip_atomic_store(wq + i, v, __ATOMIC_RELAXED, __HIP_MEMORY_SCOPE_AGENT);
            }
            __syncthreads();
            if (tid == 0)
                __hip_atomic_fetch_add(FLG + 12, 1u, __ATOMIC_RELAXED,
                                       __HIP_MEMORY_SCOPE_AGENT);
        }
        waitcast(FLG);
        unsigned have = 0;
        for (int w = hb; w < 1750; w += 96) {
            int mt = w / 250, nt = w % 250;
            unsigned need = (unsigned)(mt * 8 + 8);
            if (have < need) { waitgates<8>(FLG, need); have = need; }
            head_tile(sm, h2bf, (const ushort*)Wbf, out, mt * 256, nt * 128);
        }
    }

    // ---------------- dynamic tail pool: mt=7 tiles on ALL blocks ----------------
    waitgates<2>(FLG, (unsigned)NT);
    waitcast(FLG);
    for (;;) {
        if (tid == 0)
            sh_w = __hip_atomic_fetch_add(FLG + 8, 1u, __ATOMIC_RELAXED,
                                          __HIP_MEMORY_SCOPE_AGENT);
        __syncthreads();
        unsigned w = sh_w;
        __syncthreads();
        if (w >= 250u) break;
        head_tile(sm, h2bf, (const ushort*)Wbf, out, 7 * 256, (int)w * 128);
    }
}

// ---------------- launch ----------------
extern "C" void kernel_launch(void* const* d_in, const int* in_sizes, int n_in,
                              void* d_out, int out_size, void* d_ws, size_t ws_size,
                              hipStream_t stream) {
    const float* img    = (const float*)d_in[0];
    const int*   toks   = (const int*)d_in[1];
    const float* embed  = (const float*)d_in[2];
    const float* W_ctx  = (const float*)d_in[3];
    const float* W_mix  = (const float*)d_in[4];
    const float* ln_g   = (const float*)d_in[5];
    const float* ln_b   = (const float*)d_in[6];
    const float* W_ih   = (const float*)d_in[7];
    const float* W_hh   = (const float*)d_in[8];
    const float* b_ih   = (const float*)d_in[9];
    const float* b_hh   = (const float*)d_in[10];
    const float* W_head = (const float*)d_in[11];
    const float* W_img  = (const float*)d_in[12];
    const float* W_hid  = (const float*)d_in[13];
    const float* w_sc   = (const float*)d_in[14];
    const float* W_h0   = (const float*)d_in[15];
    const float* b_h0   = (const float*)d_in[16];
    const float* W_c0   = (const float*)d_in[17];
    const float* b_c0   = (const float*)d_in[18];

    float* out = (float*)d_out;
    float* ws  = (float*)d_ws;
    ushort* Wbf    = (ushort*)(ws + WS_WBF);
    ushort* h2bf   = (ushort*)(ws + WS_H2BF);
    float*  imgEM  = ws + WS_IMGEM;
    float*  proj   = ws + WS_PROJ;
    float*  embM   = ws + WS_EMBM;
    ushort* whhbf  = (ushort*)(ws + WS_WHHBF);
    ushort* wihbf  = (ushort*)(ws + WS_WIHBF);
    ushort* whidbf = (ushort*)(ws + WS_WHIDBF);
    float*  H      = ws + WS_H;
    float*  XN     = ws + WS_XN;
    float*  C      = ws + WS_C;
    unsigned* flg  = (unsigned*)(ws + WS_FLAGS);
    float*  g      = ws + WS_G;
    // prep scratch (inside Wbf slot; dead before in-kernel Wbf cast)
    ushort* imgbf   = (ushort*)(ws + PS_IMGBF);
    ushort* wctxbf  = (ushort*)(ws + PS_WCTXBF);
    ushort* wimgbf  = (ushort*)(ws + PS_WIMGBF);
    ushort* wmixRbf = (ushort*)(ws + PS_WMIXRBF);
    ushort* wmixLbf = (ushort*)(ws + PS_WMIXLBF);
    ushort* imgEbf  = (ushort*)(ws + PS_IMGEBF);

    // prep 1: all casts (img + 7 weights) + flag/counter zeroing, one launch
    k_castall<<<3617, 256, 0, stream>>>(img, W_ctx, W_img, W_mix, W_hh, W_ih, W_hid,
                                        imgbf, wctxbf, wimgbf, wmixRbf, wmixLbf,
                                        whhbf, wihbf, whidbf, flg);
    // prep 2: fused triple GEMM
    k_gemm3<<<129, 256, 0, stream>>>(imgbf, wctxbf, wimgbf, embed, toks, wmixLbf,
                                     imgEbf, proj, embM);
    // prep 3: imgEM = imgEbf @ wmixR^T
    k_gemm<<<dim3(4, 13), 256, 0, stream>>>(imgEbf, wmixRbf, imgEM, 512, 512);
    // prep 4: init state
    k_gmean<<<32, 256, 0, stream>>>(img, g);
    k_h0c0<<<128, 256, 0, stream>>>(g, W_h0, b_h0, W_c0, b_c0, H, C);

    // fused recurrence + in-kernel W_head cast + streamed head GEMM + dynamic tail
    k_persist<<<NBLK, 1024, 0, stream>>>(toks, embed, ln_g, ln_b, b_ih, b_hh, w_sc,
                                         whidbf, whhbf, wihbf, proj, imgEM, embM,
                                         H, C, XN, flg, h2bf, W_head, Wbf, out);
}

// Round 18
// 834.755 us; speedup vs baseline: 1.6712x; 1.0862x over previous
//
#include <hip/hip_runtime.h>

#define NV 32000
#define NT 64
#define NBLK 256u

typedef unsigned long long ull;
typedef unsigned short ushort;
typedef __attribute__((ext_vector_type(8))) short v8s;
typedef __attribute__((ext_vector_type(4))) float v4f;

// persistent ws layout (float offsets; ushort regions = count/2 floats)
#define WS_WBF     0          // ushort [32000][512]           -> 8192000
#define WS_H2BF    8192000    // ushort [2048][512]  (524288)  -> 8716288
#define WS_IMGEM   8716288    // f32 [1664][512]     (851968)  -> 9568256
#define WS_PROJ    9568256    // f32 [1664][128]     (212992)  -> 9781248
#define WS_EMBM    9781248    // f32 [2048][512]     (1048576) -> 10829824
#define WS_WHHBF   10829824   // ushort [2048][512]  (524288)  -> 11354112
#define WS_WIHBF   11354112   // ushort [2048][512]  (524288)  -> 11878400
#define WS_WHIDBF  11878400   // ushort [128][512]   (32768)   -> 11911168
#define WS_H       11911168   // f32 [2][32][512]    (32768)   -> 11943936
#define WS_XN      11943936   // ushort [32][512]    (8192)    -> 11960320 (half used)
#define WS_C       11960320   // f32 [32][512]       (16384)   -> 11976704
#define WS_FLAGS   11976704   // 160 slots x 16 u32; slot0 word8 = tile ctr, word12 = cast ctr
#define WS_G       11979264   // f32 [32][2048]      (65536)   -> 12044800
// prep scratch (inside Wbf slot [0,8192000); dead before in-kernel Wbf cast)
#define PS_IMGBF   0          // ushort [1664][2048] (1703936) -> 1703936
#define PS_WCTXBF  1703936    // ushort [512][2048]  (524288)  -> 2228224
#define PS_WIMGBF  2228224    // ushort [128][2048]  (131072)  -> 2359296
#define PS_WMIXRBF 2359296    // ushort [512][512]   (131072)  -> 2490368
#define PS_WMIXLBF 2490368    // ushort [512][512]   (131072)  -> 2621440
#define PS_IMGEBF  3342336    // ushort [1664][512]  (425984)  -> 3768320
#define PS_WH0BF   3768320    // ushort [512][2048]  (524288)  -> 4292608
#define PS_WC0BF   4292608    // ushort [512][2048]  (524288)  -> 4816896

__device__ __forceinline__ float fsig(float x) {
    x = fminf(fmaxf(x, -30.f), 30.f);
    return 1.f / (1.f + __expf(-x));
}
__device__ __forceinline__ float ftanh(float x) {
    x = fminf(fmaxf(x, -15.f), 15.f);
    float e = __expf(2.f * x);
    return (e - 1.f) / (e + 1.f);
}
__device__ __forceinline__ unsigned short f2bf(float f) {
    union { float f; unsigned int u; } v; v.f = f;
    unsigned int u = v.u;
    return (unsigned short)((u + 0x7FFFu + ((u >> 16) & 1u)) >> 16);
}
__device__ __forceinline__ unsigned pkf(float x, float y) {
    return (unsigned)f2bf(x) | ((unsigned)f2bf(y) << 16);
}
__device__ __forceinline__ float bf_lo(unsigned u) { return __uint_as_float(u << 16); }
__device__ __forceinline__ float bf_hi(unsigned u) { return __uint_as_float(u & 0xffff0000u); }
__device__ __forceinline__ ull agld(const ull* p) {
    return __hip_atomic_load(p, __ATOMIC_RELAXED, __HIP_MEMORY_SCOPE_AGENT);
}
__device__ __forceinline__ unsigned pk2(ull v) {
    return (unsigned)f2bf(__uint_as_float((unsigned)v)) |
           ((unsigned)f2bf(__uint_as_float((unsigned)(v >> 32))) << 16);
}

// ---------------- prep kernels ----------------

__global__ __launch_bounds__(256) void k_castall(
        const float* __restrict__ img, const float* __restrict__ Wctx,
        const float* __restrict__ Wimg, const float* __restrict__ Wmix,
        const float* __restrict__ Whh, const float* __restrict__ Wih,
        const float* __restrict__ Whid, const float* __restrict__ Wh0,
        const float* __restrict__ Wc0,
        ushort* __restrict__ imgbf, ushort* __restrict__ wctxbf,
        ushort* __restrict__ wimgbf, ushort* __restrict__ wmixRbf,
        ushort* __restrict__ wmixLbf, ushort* __restrict__ whhbf,
        ushort* __restrict__ wihbf, ushort* __restrict__ whidbf,
        ushort* __restrict__ wh0bf, ushort* __restrict__ wc0bf,
        unsigned* __restrict__ flg) {
    int blk = blockIdx.x, tid = threadIdx.x;
    if (blk >= 4640) {                       // zero flag slots + counters
        for (int i = tid; i < 2560; i += 256) flg[i] = 0u;
        return;
    }
    const float* in; ushort* out; int R, K, ldi, off;
    if (blk < 1664)      { in = img;  out = imgbf;   R = 1568; K = 2048; ldi = 2048; off = 0; }
    else if (blk < 2176) { in = Wctx; out = wctxbf;  R = 512;  K = 2048; ldi = 2048; off = 0;   blk -= 1664; }
    else if (blk < 2304) { in = Wimg; out = wimgbf;  R = 128;  K = 2048; ldi = 2048; off = 0;   blk -= 2176; }
    else if (blk < 2432) { in = Wmix; out = wmixRbf; R = 512;  K = 512;  ldi = 1024; off = 512; blk -= 2304; }
    else if (blk < 2560) { in = Wmix; out = wmixLbf; R = 512;  K = 512;  ldi = 1024; off = 0;   blk -= 2432; }
    else if (blk < 3072) { in = Whh;  out = whhbf;   R = 2048; K = 512;  ldi = 512;  off = 0;   blk -= 2560; }
    else if (blk < 3584) { in = Wih;  out = wihbf;   R = 2048; K = 512;  ldi = 512;  off = 0;   blk -= 3072; }
    else if (blk < 3616) { in = Whid; out = whidbf;  R = 128;  K = 512;  ldi = 512;  off = 0;   blk -= 3584; }
    else if (blk < 4128) { in = Wh0;  out = wh0bf;   R = 512;  K = 2048; ldi = 2048; off = 0;   blk -= 3616; }
    else                 { in = Wc0;  out = wc0bf;   R = 512;  K = 2048; ldi = 2048; off = 0;   blk -= 4128; }
    size_t i = ((size_t)blk * 256 + tid) * 8;
    int r = (int)(i / K), k = (int)(i % K);
    uint4 o = {0, 0, 0, 0};
    if (r < R) {
        const float* p = in + (size_t)r * ldi + off + k;
        float4 a = *(const float4*)(p);
        float4 b = *(const float4*)(p + 4);
        o.x = pkf(a.x, a.y); o.y = pkf(a.z, a.w);
        o.z = pkf(b.x, b.y); o.w = pkf(b.z, b.w);
    }
    *(uint4*)(out + i) = o;
}

// generic bf16 GEMM, fp32 out
__global__ __launch_bounds__(256) void k_gemm(const ushort* __restrict__ A,
        const ushort* __restrict__ B, float* __restrict__ C, int N, int K) {
    __shared__ ushort Al[128][72];
    __shared__ ushort Bl[128][72];
    int n0 = blockIdx.x * 128, m0 = blockIdx.y * 128;
    int tid = threadIdx.x, lane = tid & 63, wid = tid >> 6;
    int wm = wid >> 1, wn = wid & 1;
    v4f acc[4][4] = {};
    for (int kt = 0; kt < K; kt += 64) {
        __syncthreads();
        #pragma unroll
        for (int i = 0; i < 4; i++) {
            int idx = i * 256 + tid;
            int row = idx >> 3, c8 = (idx & 7) * 8;
            *(uint4*)&Al[row][c8] = *(const uint4*)&A[(size_t)(m0 + row) * K + kt + c8];
            *(uint4*)&Bl[row][c8] = *(const uint4*)&B[(size_t)(n0 + row) * K + kt + c8];
        }
        __syncthreads();
        #pragma unroll
        for (int kk = 0; kk < 2; kk++) {
            v8s a[4], bfr[4];
            int ko = kk * 32 + (lane >> 4) * 8;
            #pragma unroll
            for (int mi = 0; mi < 4; mi++)
                a[mi] = *(const v8s*)&Al[wm * 64 + mi * 16 + (lane & 15)][ko];
            #pragma unroll
            for (int ni = 0; ni < 4; ni++)
                bfr[ni] = *(const v8s*)&Bl[wn * 64 + ni * 16 + (lane & 15)][ko];
            #pragma unroll
            for (int mi = 0; mi < 4; mi++)
                #pragma unroll
                for (int ni = 0; ni < 4; ni++)
                    acc[mi][ni] = __builtin_amdgcn_mfma_f32_16x16x32_bf16(a[mi], bfr[ni], acc[mi][ni], 0, 0, 0);
        }
    }
    int col = lane & 15, rbase = (lane >> 4) * 4;
    #pragma unroll
    for (int mi = 0; mi < 4; mi++)
        #pragma unroll
        for (int ni = 0; ni < 4; ni++)
            #pragma unroll
            for (int r = 0; r < 4; r++) {
                int m = m0 + wm * 64 + mi * 16 + rbase + r;
                int v = n0 + wn * 64 + ni * 16 + col;
                C[(size_t)m * N + v] = acc[mi][ni][r];
            }
}

// fused 5-way GEMM in one launch:
//  [0,52):    imgEbf = bf16(imgbf @ wctxbf^T)        K=2048, bf16 out
//  [52,65):   proj   = imgbf @ wimgbf^T              K=2048, fp32 out
//  [65,129):  embM   = gather(embed,toks) @ wmixL^T  K=512,  fp32 out
//  [129,133): h0 = tanh(g @ Wh0^T + b_h0)*0.5 -> H   K=2048
//  [133,137): c0 = tanh(g @ Wc0^T + b_c0)*0.5 -> C   K=2048
__global__ __launch_bounds__(256) void k_gemm3(
        const ushort* __restrict__ imgbf, const ushort* __restrict__ wctxbf,
        const ushort* __restrict__ wimgbf, const float* __restrict__ embed,
        const int* __restrict__ toks, const ushort* __restrict__ wmixLbf,
        const ushort* __restrict__ wh0bf, const ushort* __restrict__ wc0bf,
        const float* __restrict__ g, const float* __restrict__ bh0,
        const float* __restrict__ bc0,
        ushort* __restrict__ imgEbf, float* __restrict__ proj,
        float* __restrict__ embM, float* __restrict__ Hout,
        float* __restrict__ Cout) {
    __shared__ ushort Al[128][72];
    __shared__ ushort Bl[128][72];
    int bid = blockIdx.x;
    const ushort* A; const ushort* B; int mode, K, N, n0, m0;
    if (bid < 52)       { mode = 0; A = imgbf; B = wctxbf;  K = 2048; N = 512; n0 = (bid & 3) * 128; m0 = (bid >> 2) * 128; }
    else if (bid < 65)  { mode = 1; A = imgbf; B = wimgbf;  K = 2048; N = 128; n0 = 0;               m0 = (bid - 52) * 128; }
    else if (bid < 129) { int e = bid - 65;  mode = 2; A = nullptr; B = wmixLbf; K = 512;  N = 512; n0 = (e & 3) * 128; m0 = (e >> 2) * 128; }
    else if (bid < 133) { mode = 3; A = nullptr; B = wh0bf; K = 2048; N = 512; n0 = (bid - 129) * 128; m0 = 0; }
    else                { mode = 4; A = nullptr; B = wc0bf; K = 2048; N = 512; n0 = (bid - 133) * 128; m0 = 0; }
    int tid = threadIdx.x, lane = tid & 63, wid = tid >> 6;
    int wm = wid >> 1, wn = wid & 1;
    v4f acc[4][4] = {};
    for (int kt = 0; kt < K; kt += 64) {
        __syncthreads();
        #pragma unroll
        for (int i = 0; i < 4; i++) {
            int idx = i * 256 + tid;
            int row = idx >> 3, c8 = (idx & 7) * 8;
            if (mode == 2) {
                int rowg = m0 + row;
                int tok = toks[(rowg & 31) * 64 + (rowg >> 5)];
                uint4 oa = {0, 0, 0, 0};
                if (tok != 0) {
                    const float* pa = embed + (size_t)tok * 512 + kt + c8;
                    float4 a0 = *(const float4*)pa, a1 = *(const float4*)(pa + 4);
                    oa.x = pkf(a0.x, a0.y); oa.y = pkf(a0.z, a0.w);
                    oa.z = pkf(a1.x, a1.y); oa.w = pkf(a1.z, a1.w);
                }
                *(uint4*)&Al[row][c8] = oa;
            } else if (mode >= 3) {
                int rowg = m0 + row;
                uint4 oa = {0, 0, 0, 0};
                if (rowg < 32) {
                    const float* pa = g + (size_t)rowg * 2048 + kt + c8;
                    float4 a0 = *(const float4*)pa, a1 = *(const float4*)(pa + 4);
                    oa.x = pkf(a0.x, a0.y); oa.y = pkf(a0.z, a0.w);
                    oa.z = pkf(a1.x, a1.y); oa.w = pkf(a1.z, a1.w);
                }
                *(uint4*)&Al[row][c8] = oa;
            } else {
                *(uint4*)&Al[row][c8] = *(const uint4*)&A[(size_t)(m0 + row) * K + kt + c8];
            }
            *(uint4*)&Bl[row][c8] = *(const uint4*)&B[(size_t)(n0 + row) * K + kt + c8];
        }
        __syncthreads();
        #pragma unroll
        for (int kk = 0; kk < 2; kk++) {
            v8s a[4], bfr[4];
            int ko = kk * 32 + (lane >> 4) * 8;
            #pragma unroll
            for (int mi = 0; mi < 4; mi++)
                a[mi] = *(const v8s*)&Al[wm * 64 + mi * 16 + (lane & 15)][ko];
            #pragma unroll
            for (int ni = 0; ni < 4; ni++)
                bfr[ni] = *(const v8s*)&Bl[wn * 64 + ni * 16 + (lane & 15)][ko];
            #pragma unroll
            for (int mi = 0; mi < 4; mi++)
                #pragma unroll
                for (int ni = 0; ni < 4; ni++)
                    acc[mi][ni] = __builtin_amdgcn_mfma_f32_16x16x32_bf16(a[mi], bfr[ni], acc[mi][ni], 0, 0, 0);
        }
    }
    int col = lane & 15, rbase = (lane >> 4) * 4;
    #pragma unroll
    for (int mi = 0; mi < 4; mi++)
        #pragma unroll
        for (int ni = 0; ni < 4; ni++)
            #pragma unroll
            for (int r = 0; r < 4; r++) {
                int m = m0 + wm * 64 + mi * 16 + rbase + r;
                int v = n0 + wn * 64 + ni * 16 + col;
                if (mode == 0)      imgEbf[(size_t)m * 512 + v] = f2bf(acc[mi][ni][r]);
                else if (mode == 1) proj[(size_t)m * 128 + v] = acc[mi][ni][r];
                else if (mode == 2) embM[(size_t)m * 512 + v] = acc[mi][ni][r];
                else if (m < 32) {
                    float pre = acc[mi][ni][r] + ((mode == 3) ? bh0[v] : bc0[v]);
                    float val = ftanh(pre) * 0.5f;
                    if (mode == 3) Hout[m * 512 + v] = val;
                    else           Cout[m * 512 + v] = val;
                }
            }
}

__global__ __launch_bounds__(256) void k_gmean(const float* __restrict__ img,
                                               float* __restrict__ g) {
    int b = blockIdx.x;
    for (int d = threadIdx.x; d < 2048; d += 256) {
        float s = 0.f;
        for (int ss = 0; ss < 49; ss++) s += img[((size_t)(b * 49 + ss)) * 2048 + d];
        g[b * 2048 + d] = s * (1.f / 49.f);
    }
}

// ---------------- persistent kernel: gates + attn + head roles ----------------

__device__ __forceinline__ void waitflags(unsigned* FLG, int base, int stride,
                                          int n, unsigned tgt) {
    if (threadIdx.x < 64) {
        bool done;
        do {
            unsigned v = tgt;
            if ((int)threadIdx.x < n)
                v = __hip_atomic_load(FLG + (base + (int)threadIdx.x * stride) * 16,
                                      __ATOMIC_RELAXED, __HIP_MEMORY_SCOPE_AGENT);
            done = __all((int)(v >= tgt));
            if (!done) __builtin_amdgcn_s_sleep(1);
        } while (!done);
    }
    __syncthreads();
}

template <int SLP>
__device__ __forceinline__ void waitgates(unsigned* FLG, unsigned tgt) {
    if (threadIdx.x < 64) {
        bool done;
        do {
            unsigned v0 = __hip_atomic_load(FLG + threadIdx.x * 16,
                            __ATOMIC_RELAXED, __HIP_MEMORY_SCOPE_AGENT);
            unsigned v1 = __hip_atomic_load(FLG + (threadIdx.x + 64) * 16,
                            __ATOMIC_RELAXED, __HIP_MEMORY_SCOPE_AGENT);
            done = __all((int)(v0 >= tgt && v1 >= tgt));
            if (!done) __builtin_amdgcn_s_sleep(SLP);
        } while (!done);
    }
    __syncthreads();
}

__device__ __forceinline__ void waitcast(unsigned* FLG) {
    if (threadIdx.x == 0) {
        while (__hip_atomic_load(FLG + 12, __ATOMIC_RELAXED, __HIP_MEMORY_SCOPE_AGENT) < 96u)
            __builtin_amdgcn_s_sleep(4);
    }
    __syncthreads();
}

union SMem {
    struct {                       // gates role (blocks 0..127)
        ushort wh[64][520];
        ushort wi[64][520];
        ushort hsb[16][520];
        float gtmp[4][16][16];
        ushort h2s[16][8];
    } g;                           // ~154.1 KB
    struct {                       // attention role (blocks 128..159)
        float imgem[49][512];
        float projl[49][128];
        float hb[512];
        float ebs[512];
        float php[8][128];
        float ph[128];
        float scp[64][16];
        float wsm[64];
        float xps[2][512];
        float wred[8][2];
        float bc[2];
    } a;                           // ~142.5 KB
    struct {                       // head staging (any role post-loop, blocks 160+)
        ushort Al[256][72];
        ushort Bl[128][72];
    } h;                           // 55.3 KB
};

// one 256x128 head tile at (m0, n0); 1024 threads, 8 compute waves
__device__ __forceinline__ void head_tile(SMem& sm, const ushort* __restrict__ h2bf,
        const ushort* __restrict__ Wbf, float* __restrict__ out, int m0, int n0) {
    int tid = threadIdx.x, lane = tid & 63, wid = tid >> 6;
    int wm = wid >> 1, wn = wid & 1;
    v4f acc[4][4] = {};
    for (int kt = 0; kt < 512; kt += 64) {
        __syncthreads();
        #pragma unroll
        for (int i = 0; i < 2; i++) {   // A: 2048 uint4 over 1024 thr
            int idx = i * 1024 + tid;
            int row = idx >> 3, c8 = (idx & 7) * 8;
            const ull* p = (const ull*)&h2bf[(size_t)(m0 + row) * 512 + kt + c8];
            ull v0 = agld(p), v1 = agld(p + 1);
            *(ull*)&sm.h.Al[row][c8] = v0;
            *(ull*)&sm.h.Al[row][c8 + 4] = v1;
        }
        {   // B: 1024 uint4 over 1024 thr
            int row = tid >> 3, c8 = (tid & 7) * 8;
            *(uint4*)&sm.h.Bl[row][c8] = *(const uint4*)&Wbf[(size_t)(n0 + row) * 512 + kt + c8];
        }
        __syncthreads();
        if (wid < 8) {
            #pragma unroll
            for (int kk = 0; kk < 2; kk++) {
                v8s a[4], bfr[4];
                int ko = kk * 32 + (lane >> 4) * 8;
                #pragma unroll
                for (int mi = 0; mi < 4; mi++)
                    a[mi] = *(const v8s*)&sm.h.Al[wm * 64 + mi * 16 + (lane & 15)][ko];
                #pragma unroll
                for (int ni = 0; ni < 4; ni++)
                    bfr[ni] = *(const v8s*)&sm.h.Bl[wn * 64 + ni * 16 + (lane & 15)][ko];
                #pragma unroll
                for (int mi = 0; mi < 4; mi++)
                    #pragma unroll
                    for (int ni = 0; ni < 4; ni++)
                        acc[mi][ni] = __builtin_amdgcn_mfma_f32_16x16x32_bf16(a[mi], bfr[ni], acc[mi][ni], 0, 0, 0);
            }
        }
    }
    if (wid < 8) {
        int col = lane & 15, rbase = (lane >> 4) * 4;
        #pragma unroll
        for (int mi = 0; mi < 4; mi++)
            #pragma unroll
            for (int ni = 0; ni < 4; ni++)
                #pragma unroll
                for (int r = 0; r < 4; r++) {
                    int m = m0 + wm * 64 + mi * 16 + rbase + r;
                    int v = n0 + wn * 64 + ni * 16 + col;
                    int b = m & 31, t = m >> 5;
                    out[((size_t)(b * 64 + t)) * 32000 + v] = acc[mi][ni][r];
                }
    }
}

__global__ __launch_bounds__(1024, 1) void k_persist(
        const int* __restrict__ toks, const float* __restrict__ embed,
        const float* __restrict__ lng, const float* __restrict__ lnb,
        const float* __restrict__ bih, const float* __restrict__ bhh,
        const float* __restrict__ wsc, const ushort* __restrict__ whidbf,
        const ushort* __restrict__ whhbf, const ushort* __restrict__ wihbf,
        const float* __restrict__ proj, const float* __restrict__ imgEM,
        const float* __restrict__ embM, float* __restrict__ H,
        const float* __restrict__ C0, ushort* __restrict__ XNh,
        unsigned* __restrict__ FLG, ushort* __restrict__ h2bf,
        const float* __restrict__ W_head, ushort* __restrict__ Wbf,
        float* __restrict__ out) {
    __shared__ SMem sm;
    __shared__ unsigned sh_w;
    int blk = blockIdx.x, tid = threadIdx.x;

    if (blk < 128) {
        // ---------------- gates role ----------------
        int jc = blk >> 2, bg = blk & 3, b0 = bg * 8;
        int wid = tid >> 6, lane = tid & 63;
        int gate = wid & 3;
        for (int i = tid; i < 4096; i += 1024) {
            int rr = i >> 6, c8 = (i & 63) * 8;
            size_t R = (size_t)((rr >> 4) * 512 + jc * 16 + (rr & 15)) * 512 + c8;
            *(uint4*)&sm.g.wh[rr][c8] = *(const uint4*)&whhbf[R];
            *(uint4*)&sm.g.wi[rr][c8] = *(const uint4*)&wihbf[R];
        }
        for (int i = tid; i < 2080; i += 1024) ((ull*)sm.g.hsb)[i] = 0;
        float c_reg = 0.f, bs0 = 0.f, bs1 = 0.f, bs2 = 0.f, bs3 = 0.f;
        if (tid < 128) {
            int jl = tid >> 3, bb = tid & 7;
            int j = jc * 16 + jl;
            c_reg = C0[(b0 + bb) * 512 + j];
            bs0 = bih[j] + bhh[j];
            bs1 = bih[512 + j] + bhh[512 + j];
            bs2 = bih[1024 + j] + bhh[1024 + j];
            bs3 = bih[1536 + j] + bhh[1536 + j];
        }
        __syncthreads();

        for (int t = 0; t < NT; t++) {
            waitflags(FLG, bg, 4, 32, (unsigned)t);
            {   // stage h -> hsb bf16 (rows 0..7)
                const float* Hb = H + (t & 1) * 16384 + b0 * 512;
                if (tid < 512) {
                    int bb = tid >> 6, c8 = (tid & 63) * 8;
                    const ull* p = (const ull*)(Hb + bb * 512 + c8);
                    uint4 o = { pk2(agld(p)), pk2(agld(p + 1)),
                                pk2(agld(p + 2)), pk2(agld(p + 3)) };
                    *(uint4*)&sm.g.hsb[bb][c8] = o;
                }
            }
            __syncthreads();
            v4f acc = {};
            if (wid < 4) {
                #pragma unroll
                for (int ks = 0; ks < 16; ks++) {
                    int ko = ks * 32 + (lane >> 4) * 8;
                    v8s a = *(const v8s*)&sm.g.hsb[lane & 15][ko];
                    v8s b = *(const v8s*)&sm.g.wh[gate * 16 + (lane & 15)][ko];
                    acc = __builtin_amdgcn_mfma_f32_16x16x32_bf16(a, b, acc, 0, 0, 0);
                }
            }
            waitflags(FLG, 128 + b0, 1, 8, (unsigned)(t + 1));
            {   // stage xn (already bf16-packed) -> hsb
                const ushort* Xh = XNh + b0 * 512;
                if (tid < 512) {
                    int bb = tid >> 6, c8 = (tid & 63) * 8;
                    const ull* p = (const ull*)(Xh + bb * 512 + c8);
                    ull v0 = agld(p), v1 = agld(p + 1);
                    *(ull*)&sm.g.hsb[bb][c8] = v0;
                    *(ull*)&sm.g.hsb[bb][c8 + 4] = v1;
                }
            }
            __syncthreads();
            if (wid < 4) {
                #pragma unroll
                for (int ks = 0; ks < 16; ks++) {
                    int ko = ks * 32 + (lane >> 4) * 8;
                    v8s a = *(const v8s*)&sm.g.hsb[lane & 15][ko];
                    v8s b = *(const v8s*)&sm.g.wi[gate * 16 + (lane & 15)][ko];
                    acc = __builtin_amdgcn_mfma_f32_16x16x32_bf16(a, b, acc, 0, 0, 0);
                }
                #pragma unroll
                for (int q = 0; q < 4; q++)
                    sm.g.gtmp[gate][lane & 15][(lane >> 4) * 4 + q] = acc[q];
            }
            __syncthreads();
            if (tid < 128) {
                int jl = tid >> 3, bb = tid & 7;
                float vi = sm.g.gtmp[0][jl][bb] + bs0;
                float vf = sm.g.gtmp[1][jl][bb] + bs1;
                float vg = sm.g.gtmp[2][jl][bb] + bs2;
                float vo = sm.g.gtmp[3][jl][bb] + bs3;
                float c2 = fsig(vf) * c_reg + fsig(vi) * ftanh(vg);
                float h2 = fsig(vo) * ftanh(c2);
                c_reg = c2;
                int bglob = b0 + bb, j = jc * 16 + jl;
                __hip_atomic_store((unsigned*)&H[((t + 1) & 1) * 16384 + bglob * 512 + j],
                                   __float_as_uint(h2), __ATOMIC_RELAXED, __HIP_MEMORY_SCOPE_AGENT);
                sm.g.h2s[jl][bb] = f2bf(h2);
            }
            __syncthreads();
            if (tid < 64) {
                int jlp = tid >> 3, bb = tid & 7;
                unsigned pk = (unsigned)sm.g.h2s[2 * jlp][bb]
                            | ((unsigned)sm.g.h2s[2 * jlp + 1][bb] << 16);
                int bglob = b0 + bb, j = jc * 16 + 2 * jlp;
                __hip_atomic_store((unsigned*)&h2bf[(size_t)(t * 32 + bglob) * 512 + j],
                                   pk, __ATOMIC_RELAXED, __HIP_MEMORY_SCOPE_AGENT);
            }
            __syncthreads();
            if (tid == 0)
                __hip_atomic_store(FLG + blk * 16, (unsigned)(t + 1),
                                   __ATOMIC_RELAXED, __HIP_MEMORY_SCOPE_AGENT);
        }
    } else if (blk < 160) {
        // ---------------- attention role ----------------
        int b = blk - 128, bgb = b >> 3;
        for (int i = tid; i < 49 * 512; i += 1024)
            sm.a.imgem[i >> 9][i & 511] = imgEM[(size_t)b * 49 * 512 + i];
        for (int i = tid; i < 49 * 128; i += 1024)
            sm.a.projl[i >> 7][i & 127] = proj[(size_t)b * 49 * 128 + i];
        __syncthreads();
        for (int t = 0; t < NT; t++) {
            waitflags(FLG, bgb, 4, 32, (unsigned)t);
            int tok = toks[b * 64 + t];
            if (tid < 256) {
                ull v = agld((const ull*)(H + (t & 1) * 16384) + b * 256 + tid);
                *(ull*)&sm.a.hb[tid * 2] = v;
            } else if (tid < 768) {
                int k = tid - 256;
                sm.a.ebs[k] = (tok == 0) ? 0.f : embed[(size_t)tok * 512 + k];
            }
            __syncthreads();
            {   // ph partials (whid from L2, bf16)
                int a = tid & 127, kq = tid >> 7;
                const ushort* wr2 = whidbf + (size_t)a * 512 + kq * 64;
                const float* hp = sm.a.hb + kq * 64;
                float p = 0.f;
                #pragma unroll
                for (int k = 0; k < 64; k += 8) {
                    uint4 q = *(const uint4*)(wr2 + k);
                    float4 ha = *(const float4*)(hp + k);
                    float4 hb4 = *(const float4*)(hp + k + 4);
                    p += bf_lo(q.x)*ha.x + bf_hi(q.x)*ha.y + bf_lo(q.y)*ha.z + bf_hi(q.y)*ha.w
                       + bf_lo(q.z)*hb4.x + bf_hi(q.z)*hb4.y + bf_lo(q.w)*hb4.z + bf_hi(q.w)*hb4.w;
                }
                sm.a.php[kq][a] = p;
            }
            __syncthreads();
            if (tid < 128) {
                float p = 0.f;
                #pragma unroll
                for (int kq = 0; kq < 8; kq++) p += sm.a.php[kq][tid];
                sm.a.ph[tid] = p;
            }
            __syncthreads();
            {   // score partials (proj from LDS)
                int s = tid >> 4, aq = tid & 15;
                float p = 0.f;
                if (s < 49) {
                    const float* pr = &sm.a.projl[s][aq * 8];
                    #pragma unroll
                    for (int a = 0; a < 8; a++)
                        p += ftanh(pr[a] + sm.a.ph[aq * 8 + a]) * wsc[aq * 8 + a];
                }
                sm.a.scp[s][aq] = p;
            }
            __syncthreads();
            if (tid < 64) {
                float v = 0.f;
                #pragma unroll
                for (int q = 0; q < 16; q++) v += sm.a.scp[tid][q];
                if (tid >= 49) v = -1e30f;
                float m = v;
                for (int o = 32; o > 0; o >>= 1) m = fmaxf(m, __shfl_xor(m, o));
                float e = (tid < 49) ? __expf(v - m) : 0.f;
                float su = e;
                for (int o = 32; o > 0; o >>= 1) su += __shfl_xor(su, o);
                sm.a.wsm[tid] = e / su;
            }
            __syncthreads();
            {   // x = embM + sum_s w_s imgEM (imgem from LDS)
                int e = tid & 511, sh = tid >> 9;
                float xp = 0.f;
                if (sh == 0) xp = embM[(size_t)(t * 32 + b) * 512 + e];
                int s0 = sh * 25, s1 = sh ? 49 : 25;
                for (int s = s0; s < s1; s++)
                    xp += sm.a.wsm[s] * sm.a.imgem[s][e];
                sm.a.xps[sh][e] = xp;
            }
            __syncthreads();
            if (tid < 512) {
                float x = fmaxf(sm.a.xps[0][tid] + sm.a.xps[1][tid], 0.f);
                float s = x, s2 = x * x;
                for (int o = 32; o > 0; o >>= 1) { s += __shfl_xor(s, o); s2 += __shfl_xor(s2, o); }
                if ((tid & 63) == 0) { sm.a.wred[tid >> 6][0] = s; sm.a.wred[tid >> 6][1] = s2; }
            }
            __syncthreads();
            if (tid == 0) {
                float s = 0.f, s2 = 0.f;
                #pragma unroll
                for (int w = 0; w < 8; w++) { s += sm.a.wred[w][0]; s2 += sm.a.wred[w][1]; }
                float mu = s * (1.f / 512.f);
                float var = s2 * (1.f / 512.f) - mu * mu;
                sm.a.bc[0] = mu; sm.a.bc[1] = rsqrtf(var + 1e-5f);
            }
            __syncthreads();
            if (tid < 512) {
                float x = fmaxf(sm.a.xps[0][tid] + sm.a.xps[1][tid], 0.f);
                float xn = (x - sm.a.bc[0]) * sm.a.bc[1] * lng[tid] + lnb[tid] + sm.a.ebs[tid];
                float xnn = __shfl_xor(xn, 1);
                if (!(tid & 1)) {
                    unsigned pkv = pkf(xn, xnn);   // bf16 pair, same rounding as gates' pk2
                    __hip_atomic_store((unsigned*)&XNh[b * 512 + tid], pkv,
                                       __ATOMIC_RELAXED, __HIP_MEMORY_SCOPE_AGENT);
                }
            }
            __syncthreads();
            if (tid == 0)
                __hip_atomic_store(FLG + (128 + b) * 16, (unsigned)(t + 1),
                                   __ATOMIC_RELAXED, __HIP_MEMORY_SCOPE_AGENT);
        }
    } else {
        // ---------------- head role (blocks 160..255) ----------------
        int hb = blk - 160;
        // in-kernel W_head -> Wbf cast (agent-scope stores; consumers wait counter)
        {
            ull* wq = (ull*)Wbf;
            for (size_t i = (size_t)hb * 1024 + tid; i < 4096000; i += 98304) {
                const float* p = W_head + i * 4;
                float4 a = *(const float4*)p;
                ull v = (ull)pkf(a.x, a.y) | ((ull)pkf(a.z, a.w) << 32);
                __hip_atomic_store(wq + i, v, __ATOMIC_RELAXED, __HIP_MEMORY_SCOPE_AGENT);
            }
            __syncthreads();
            if (tid == 0)
                __hip_atomic_fetch_add(FLG + 12, 1u, __ATOMIC_RELAXED,
                                       __HIP_MEMORY_SCOPE_AGENT);
        }
        waitcast(FLG);
        unsigned have = 0;
        for (int w = hb; w < 1750; w += 96) {
            int mt = w / 250, nt = w % 250;
            unsigned need = (unsigned)(mt * 8 + 8);
            if (have < need) { waitgates<8>(FLG, need); have = need; }
            head_tile(sm, h2bf, (const ushort*)Wbf, out, mt * 256, nt * 128);
        }
    }

    // ---------------- dynamic tail pool: mt=7 tiles on ALL blocks ----------------
    waitgates<2>(FLG, (unsigned)NT);
    waitcast(FLG);
    for (;;) {
        if (tid == 0)
            sh_w = __hip_atomic_fetch_add(FLG + 8, 1u, __ATOMIC_RELAXED,
                                          __HIP_MEMORY_SCOPE_AGENT);
        __syncthreads();
        unsigned w = sh_w;
        __syncthreads();
        if (w >= 250u) break;
        head_tile(sm, h2bf, (const ushort*)Wbf, out, 7 * 256, (int)w * 128);
    }
}

// ---------------- launch ----------------
extern "C" void kernel_launch(void* const* d_in, const int* in_sizes, int n_in,
                              void* d_out, int out_size, void* d_ws, size_t ws_size,
                              hipStream_t stream) {
    const float* img    = (const float*)d_in[0];
    const int*   toks   = (const int*)d_in[1];
    const float* embed  = (const float*)d_in[2];
    const float* W_ctx  = (const float*)d_in[3];
    const float* W_mix  = (const float*)d_in[4];
    const float* ln_g   = (const float*)d_in[5];
    const float* ln_b   = (const float*)d_in[6];
    const float* W_ih   = (const float*)d_in[7];
    const float* W_hh   = (const float*)d_in[8];
    const float* b_ih   = (const float*)d_in[9];
    const float* b_hh   = (const float*)d_in[10];
    const float* W_head = (const float*)d_in[11];
    const float* W_img  = (const float*)d_in[12];
    const float* W_hid  = (const float*)d_in[13];
    const float* w_sc   = (const float*)d_in[14];
    const float* W_h0   = (const float*)d_in[15];
    const float* b_h0   = (const float*)d_in[16];
    const float* W_c0   = (const float*)d_in[17];
    const float* b_c0   = (const float*)d_in[18];

    float* out = (float*)d_out;
    float* ws  = (float*)d_ws;
    ushort* Wbf    = (ushort*)(ws + WS_WBF);
    ushort* h2bf   = (ushort*)(ws + WS_H2BF);
    float*  imgEM  = ws + WS_IMGEM;
    float*  proj   = ws + WS_PROJ;
    float*  embM   = ws + WS_EMBM;
    ushort* whhbf  = (ushort*)(ws + WS_WHHBF);
    ushort* wihbf  = (ushort*)(ws + WS_WIHBF);
    ushort* whidbf = (ushort*)(ws + WS_WHIDBF);
    float*  H      = ws + WS_H;
    ushort* XNh    = (ushort*)(ws + WS_XN);
    float*  C      = ws + WS_C;
    unsigned* flg  = (unsigned*)(ws + WS_FLAGS);
    float*  g      = ws + WS_G;
    // prep scratch (inside Wbf slot; dead before in-kernel Wbf cast)
    ushort* imgbf   = (ushort*)(ws + PS_IMGBF);
    ushort* wctxbf  = (ushort*)(ws + PS_WCTXBF);
    ushort* wimgbf  = (ushort*)(ws + PS_WIMGBF);
    ushort* wmixRbf = (ushort*)(ws + PS_WMIXRBF);
    ushort* wmixLbf = (ushort*)(ws + PS_WMIXLBF);
    ushort* imgEbf  = (ushort*)(ws + PS_IMGEBF);
    ushort* wh0bf   = (ushort*)(ws + PS_WH0BF);
    ushort* wc0bf   = (ushort*)(ws + PS_WC0BF);

    // prep 1: all casts (img + 9 weights) + flag/counter zeroing, one launch
    k_castall<<<4641, 256, 0, stream>>>(img, W_ctx, W_img, W_mix, W_hh, W_ih, W_hid,
                                        W_h0, W_c0,
                                        imgbf, wctxbf, wimgbf, wmixRbf, wmixLbf,
                                        whhbf, wihbf, whidbf, wh0bf, wc0bf, flg);
    // prep 2: g = mean_s img
    k_gmean<<<32, 256, 0, stream>>>(img, g);
    // prep 3: fused 5-way GEMM (imgEbf, proj, embM, h0 -> H, c0 -> C)
    k_gemm3<<<137, 256, 0, stream>>>(imgbf, wctxbf, wimgbf, embed, toks, wmixLbf,
                                     wh0bf, wc0bf, g, b_h0, b_c0,
                                     imgEbf, proj, embM, H, C);
    // prep 4: imgEM = imgEbf @ wmixR^T
    k_gemm<<<dim3(4, 13), 256, 0, stream>>>(imgEbf, wmixRbf, imgEM, 512, 512);

    // fused recurrence + in-kernel W_head cast + streamed head GEMM + dynamic tail
    k_persist<<<NBLK, 1024, 0, stream>>>(toks, embed, ln_g, ln_b, b_ih, b_hh, w_sc,
                                         whidbf, whhbf, wihbf, proj, imgEM, embM,
                                         H, C, XNh, flg, h2bf, W_head, Wbf, out);
}